// Round 9
// baseline (1728.201 us; speedup 1.0000x reference)
//
#include <hip/hip_runtime.h>

#define N_NODES 200000
#define N_EDGES 800000
#define NODE_IN 133
#define EDGE_IN 14
#define HID 128
#define NUM_GRAPHS 4096

#define SCAN_CHUNK 2048
#define SCAN_NBLK ((N_NODES + SCAN_CHUNK - 1) / SCAN_CHUNK)  // 98

#define MT 64  // M tile rows per block for MFMA GEMMs

// K geometry per GEMM (padded K, LDS/WT row stride in elements)
#define K1_PAD 160
#define K1_STRIDE 168
#define K2_PAD 128
#define K2_STRIDE 136
#define K3_PAD 288
#define K3_STRIDE 296

typedef unsigned short u16;
typedef unsigned char u8;
typedef short bf16x8 __attribute__((ext_vector_type(8)));
typedef float f32x4 __attribute__((ext_vector_type(4)));

__device__ __forceinline__ float bu2f(unsigned s) {
    return __uint_as_float(s << 16);
}
__device__ __forceinline__ u16 f2bu(float f) {
    unsigned u = __float_as_uint(f);
    return (u16)((u + 0x7FFFu + ((u >> 16) & 1u)) >> 16);  // RNE
}
// ---------------- fp8 e4m3 (OCP), non-negative post-ReLU values -----------
__device__ __forceinline__ float e42f(unsigned b) {
    unsigned E = (b >> 4) & 0xF, M = b & 7u;
    if (E == 0) return (float)M * 0.001953125f;  // M * 2^-9
    return __uint_as_float(((E - 7u + 127u) << 23) | (M << 20));
}
__device__ __forceinline__ u8 f2e4(float f) {
    if (!(f > 0.f)) return 0;
    if (f >= 448.f) return 0x7E;
    unsigned u = __float_as_uint(f);
    int e = (int)((u >> 23) & 0xFF) - 127;
    if (e < -6) {
        int q = (int)rintf(f * 512.f);  // q in [0,8]; 8 == 0x08 == 2^-6 (valid)
        return (u8)q;
    }
    unsigned m = u & 0x7FFFFF;
    unsigned keep = m >> 20, rem = m & 0xFFFFF;
    keep += (rem > 0x80000u || (rem == 0x80000u && (keep & 1u))) ? 1u : 0u;
    unsigned E = (unsigned)(e + 7);
    if (keep == 8u) { keep = 0u; E++; }
    return (u8)((E << 4) | keep);
}
__device__ __forceinline__ int clampi(int v, int hi) {
    return v < 0 ? 0 : (v >= hi ? hi - 1 : v);
}

// ---------------------------------------------------------------------------
// Weight prep: WT[n][k] = bf16(W[k][n]), k < K else 0.
// ---------------------------------------------------------------------------
__global__ __launch_bounds__(256) void k_prep(const float* __restrict__ W,
                                              u16* __restrict__ WT, int K,
                                              int stride) {
    const int idx = blockIdx.x * 256 + threadIdx.x;
    if (idx >= HID * stride) return;
    const int n = idx / stride, k = idx % stride;
    WT[idx] = (k < K) ? f2bu(W[k * HID + n]) : (u16)0;
}

// ---------------------------------------------------------------------------
// CSR build: histogram -> exclusive scan -> atomic-cursor placement
// ---------------------------------------------------------------------------
__global__ __launch_bounds__(256) void k_hist(const int* __restrict__ dst,
                                              int* __restrict__ cnt) {
    const int e = blockIdx.x * 256 + threadIdx.x;
    if (e < N_EDGES) atomicAdd(&cnt[clampi(dst[e], N_NODES)], 1);
}

__global__ __launch_bounds__(256) void k_scan1(const int* __restrict__ cnt,
                                               int* __restrict__ local,
                                               int* __restrict__ partial) {
    __shared__ int tsum[256];
    const int b = blockIdx.x, t = threadIdx.x;
    const int base = b * SCAN_CHUNK + t * 8;
    int v[8];
    int s = 0;
#pragma unroll
    for (int i = 0; i < 8; i++) {
        const int idx = base + i;
        v[i] = (idx < N_NODES) ? cnt[idx] : 0;
        s += v[i];
    }
    tsum[t] = s;
    __syncthreads();
    for (int ofs = 1; ofs < 256; ofs <<= 1) {
        const int add = (t >= ofs) ? tsum[t - ofs] : 0;
        __syncthreads();
        tsum[t] += add;
        __syncthreads();
    }
    int excl = (t == 0) ? 0 : tsum[t - 1];
    if (t == 255) partial[b] = tsum[255];
#pragma unroll
    for (int i = 0; i < 8; i++) {
        const int idx = base + i;
        if (idx < N_NODES) local[idx] = excl;
        excl += v[i];
    }
}

__global__ __launch_bounds__(256) void k_scan2(int* __restrict__ partial) {
    __shared__ int s[256];
    const int t = threadIdx.x;
    s[t] = (t < SCAN_NBLK) ? partial[t] : 0;
    __syncthreads();
    for (int ofs = 1; ofs < 256; ofs <<= 1) {
        const int add = (t >= ofs) ? s[t - ofs] : 0;
        __syncthreads();
        s[t] += add;
        __syncthreads();
    }
    if (t < SCAN_NBLK) partial[t] = (t == 0) ? 0 : s[t - 1];
}

__global__ __launch_bounds__(256) void k_scan3(const int* __restrict__ local,
                                               const int* __restrict__ partial,
                                               int* __restrict__ row_ptr,
                                               int* __restrict__ cursor) {
    const int idx = blockIdx.x * 256 + threadIdx.x;
    if (idx <= N_NODES) {
        const int v = (idx == N_NODES) ? N_EDGES
                                       : local[idx] + partial[idx / SCAN_CHUNK];
        row_ptr[idx] = v;
        if (idx < N_NODES) cursor[idx] = v;
    }
}

__global__ __launch_bounds__(256) void k_place(const int* __restrict__ dst,
                                               int* __restrict__ cursor,
                                               int* __restrict__ eidx) {
    const int e = blockIdx.x * 256 + threadIdx.x;
    if (e < N_EDGES) {
        const int slot = atomicAdd(&cursor[clampi(dst[e], N_NODES)], 1);
        eidx[slot] = e;
    }
}

// ---------------------------------------------------------------------------
// K2 (CSR gather): node_sum[n] = sum_{e in csr[n]} h[e]  (fp8 in, fp32 acc,
// bf16 out). 32 threads per node, 4 channels each.
// ---------------------------------------------------------------------------
__global__ __launch_bounds__(256) void k_gather(const u8* __restrict__ h,
                                                const int* __restrict__ row_ptr,
                                                const int* __restrict__ eidx,
                                                u16* __restrict__ node_sum) {
    const long long idx = (long long)blockIdx.x * 256 + threadIdx.x;
    const int n = (int)(idx >> 5);
    if (n >= N_NODES) return;
    const int c4 = (int)(idx & 31) << 2;
    const int beg = row_ptr[n], end = row_ptr[n + 1];
    float a0 = 0.f, a1 = 0.f, a2 = 0.f, a3 = 0.f;
    for (int j = beg; j < end; j++) {
        const int e = eidx[j];
        const uchar4 v = *reinterpret_cast<const uchar4*>(h + (long long)e * HID + c4);
        a0 += e42f(v.x); a1 += e42f(v.y); a2 += e42f(v.z); a3 += e42f(v.w);
    }
    ushort4 o;
    o.x = f2bu(a0); o.y = f2bu(a1); o.z = f2bu(a2); o.w = f2bu(a3);
    *reinterpret_cast<ushort4*>(node_sum + (long long)n * HID + c4) = o;
}

// ---------------------------------------------------------------------------
// MFMA geometry (64x128 tile, 4 waves: 2 in M x 2 in N)
// a-frag: lane holds A[lane&15][(lane>>4)*8 + i]; b-frag: B[(lane>>4)*8+i][lane&15]
// with B[k][n] = WT[n][k].  C/D: col = lane&15, row = (lane>>4)*4 + reg.
// ---------------------------------------------------------------------------

// K1a: xw[n] = x[n] @ W1x  (per-NODE GEMM; A cols 133..159 zeroed so the
// ea-part of WT1 multiplies zeros). No bias/relu here.
__global__ __launch_bounds__(256) void k_xw(const float* __restrict__ x,
                                            const u16* __restrict__ WT1,
                                            u16* __restrict__ xw) {
    __shared__ u16 A[MT * K1_STRIDE];
    const int n0 = blockIdx.x * MT;
    const int t = threadIdx.x;
    const int lane = t & 63, wv = t >> 6;
    for (int rr = 0; rr < 16; rr++) {
        const int row = wv * 16 + rr;
        const int n = n0 + row;
        const float* xr = x + (size_t)n * NODE_IN;
        u16* dstr = &A[row * K1_STRIDE];
        dstr[lane] = f2bu(xr[lane]);                 // k 0..63
        dstr[64 + lane] = f2bu(xr[64 + lane]);       // k 64..127
        if (lane < 5) dstr[128 + lane] = f2bu(xr[128 + lane]);  // 128..132
        if (lane < K1_PAD - NODE_IN) dstr[NODE_IN + lane] = 0;  // 133..159
    }
    __syncthreads();

    const int wm = wv & 1, wn = wv >> 1;
    const int lr = lane & 15, lk = (lane >> 4) * 8;
    f32x4 acc[2][4];
#pragma unroll
    for (int m = 0; m < 2; m++)
#pragma unroll
        for (int n = 0; n < 4; n++) acc[m][n] = (f32x4){0.f, 0.f, 0.f, 0.f};

    const int ar0 = (wm * 32 + lr) * K1_STRIDE + lk;
#pragma unroll
    for (int ks = 0; ks < K1_PAD / 32; ks++) {
        const int kk = ks * 32;
        const bf16x8 a0 = *(const bf16x8*)&A[ar0 + kk];
        const bf16x8 a1 = *(const bf16x8*)&A[ar0 + 16 * K1_STRIDE + kk];
#pragma unroll
        for (int n = 0; n < 4; n++) {
            const bf16x8 b = *(const bf16x8*)&WT1[(size_t)(wn * 64 + n * 16 + lr) * K1_STRIDE + kk + lk];
            acc[0][n] = __builtin_amdgcn_mfma_f32_16x16x32_bf16(a0, b, acc[0][n], 0, 0, 0);
            acc[1][n] = __builtin_amdgcn_mfma_f32_16x16x32_bf16(a1, b, acc[1][n], 0, 0, 0);
        }
    }

    const int lr4 = lane >> 4;
#pragma unroll
    for (int n = 0; n < 4; n++) {
        const int col = wn * 64 + n * 16 + lr;
#pragma unroll
        for (int m = 0; m < 2; m++)
#pragma unroll
            for (int j = 0; j < 4; j++) {
                const int nd = n0 + wm * 32 + m * 16 + lr4 * 4 + j;
                xw[(size_t)nd * HID + col] = f2bu(acc[m][n][j]);
            }
    }
}

// K1b: h0[e] = relu(xw[src[e]] + ea[e]@W1e + b1) -> fp8.  Elementwise + tiny
// K=14 per-edge matvec from LDS-staged W1e. 32 lanes/edge, 4 channels each.
__global__ __launch_bounds__(256) void k_init2(const u16* __restrict__ xw,
                                               const float* __restrict__ ea,
                                               const float* __restrict__ W1,
                                               const float* __restrict__ b1,
                                               const int* __restrict__ src,
                                               u8* __restrict__ h0) {
    __shared__ float w1e[EDGE_IN * HID];  // 7 KB
    __shared__ float b1s[HID];
    const int t = threadIdx.x;
    for (int i = t; i < EDGE_IN * HID; i += 256)
        w1e[i] = W1[(NODE_IN + i / HID) * HID + (i % HID)];
    if (t < HID) b1s[t] = b1[t];
    __syncthreads();

    const int e = blockIdx.x * 8 + (t >> 5);
    const int c4 = (t & 31) << 2;
    const int s = clampi(src[e], N_NODES);
    const ushort4 xv = *(const ushort4*)(xw + (size_t)s * HID + c4);
    float a0 = bu2f(xv.x) + b1s[c4];
    float a1 = bu2f(xv.y) + b1s[c4 + 1];
    float a2 = bu2f(xv.z) + b1s[c4 + 2];
    float a3 = bu2f(xv.w) + b1s[c4 + 3];
    const float* er = ea + (size_t)e * EDGE_IN;
#pragma unroll
    for (int k = 0; k < EDGE_IN; k++) {
        const float ev = er[k];
        const float4 w = *(const float4*)&w1e[k * HID + c4];
        a0 = fmaf(ev, w.x, a0);
        a1 = fmaf(ev, w.y, a1);
        a2 = fmaf(ev, w.z, a2);
        a3 = fmaf(ev, w.w, a3);
    }
    uchar4 o;
    o.x = f2e4(a0); o.y = f2e4(a1); o.z = f2e4(a2); o.w = f2e4(a3);
    *(uchar4*)(h0 + (size_t)e * HID + c4) = o;
}

// K3: hn = relu(h0 + (node_sum[src] - h[rev]) @ W2 + b2)  (fp8 states)
__global__ __launch_bounds__(256) void k_msg_mfma(const u16* __restrict__ ns,
                                                  const u8* __restrict__ h,
                                                  const u8* __restrict__ h0g,
                                                  const u16* __restrict__ WT2,
                                                  const float* __restrict__ b2,
                                                  const int* __restrict__ src,
                                                  const int* __restrict__ rev,
                                                  u8* __restrict__ hn) {
    __shared__ u16 A[MT * K2_STRIDE];
    const int e0 = blockIdx.x * MT;
    const int t = threadIdx.x;
    {   // builder: 4 threads/row, 32 channels each (vector loads; random rows)
        const int le = t >> 2, j = t & 3;
        const int e = e0 + le;
        const int s = clampi(src[e], N_NODES);
        const int r = clampi(rev[e], N_EDGES);
        const u16* nsr = ns + (size_t)s * HID + j * 32;
        const u8* hr = h + (size_t)r * HID + j * 32;
        u16* dstr = &A[le * K2_STRIDE + j * 32];
#pragma unroll
        for (int q = 0; q < 4; q++) {
            const uint4 nv = *(const uint4*)(nsr + q * 8);  // 8 bf16
            const uint2 hv = *(const uint2*)(hr + q * 8);   // 8 fp8
            union { bf16x8 v; u16 s[8]; } o;
            o.s[0] = f2bu(bu2f(nv.x & 0xFFFFu) - e42f(hv.x & 0xFFu));
            o.s[1] = f2bu(bu2f(nv.x >> 16)     - e42f((hv.x >> 8) & 0xFFu));
            o.s[2] = f2bu(bu2f(nv.y & 0xFFFFu) - e42f((hv.x >> 16) & 0xFFu));
            o.s[3] = f2bu(bu2f(nv.y >> 16)     - e42f(hv.x >> 24));
            o.s[4] = f2bu(bu2f(nv.z & 0xFFFFu) - e42f(hv.y & 0xFFu));
            o.s[5] = f2bu(bu2f(nv.z >> 16)     - e42f((hv.y >> 8) & 0xFFu));
            o.s[6] = f2bu(bu2f(nv.w & 0xFFFFu) - e42f((hv.y >> 16) & 0xFFu));
            o.s[7] = f2bu(bu2f(nv.w >> 16)     - e42f(hv.y >> 24));
            *(bf16x8*)(dstr + q * 8) = o.v;
        }
    }
    __syncthreads();

    const int lane = t & 63, wid = t >> 6;
    const int wm = wid & 1, wn = wid >> 1;
    const int lr = lane & 15, lk = (lane >> 4) * 8;
    f32x4 acc[2][4];
#pragma unroll
    for (int m = 0; m < 2; m++)
#pragma unroll
        for (int n = 0; n < 4; n++) acc[m][n] = (f32x4){0.f, 0.f, 0.f, 0.f};

    const int ar0 = (wm * 32 + lr) * K2_STRIDE + lk;
#pragma unroll
    for (int ks = 0; ks < K2_PAD / 32; ks++) {
        const int kk = ks * 32;
        const bf16x8 a0 = *(const bf16x8*)&A[ar0 + kk];
        const bf16x8 a1 = *(const bf16x8*)&A[ar0 + 16 * K2_STRIDE + kk];
#pragma unroll
        for (int n = 0; n < 4; n++) {
            const bf16x8 b = *(const bf16x8*)&WT2[(size_t)(wn * 64 + n * 16 + lr) * K2_STRIDE + kk + lk];
            acc[0][n] = __builtin_amdgcn_mfma_f32_16x16x32_bf16(a0, b, acc[0][n], 0, 0, 0);
            acc[1][n] = __builtin_amdgcn_mfma_f32_16x16x32_bf16(a1, b, acc[1][n], 0, 0, 0);
        }
    }

    const int lr4 = lane >> 4;
#pragma unroll
    for (int n = 0; n < 4; n++) {
        const int col = wn * 64 + n * 16 + lr;
        const float bias = b2[col];
#pragma unroll
        for (int m = 0; m < 2; m++)
#pragma unroll
            for (int j = 0; j < 4; j++) {
                const long long e = e0 + wm * 32 + m * 16 + lr4 * 4 + j;
                const size_t idx = (size_t)e * HID + col;
                float v = e42f(h0g[idx]) + acc[m][n][j] + bias;
                hn[idx] = f2e4(v);
            }
    }
}

// K5: node_attr[n] = relu(concat(x[n], vmsg[n]) @ W3 + b3)  (fp32 out)
__global__ __launch_bounds__(256) void k_node_mfma(const float* __restrict__ x,
                                                   const u16* __restrict__ vmsg,
                                                   const u16* __restrict__ WT3,
                                                   const float* __restrict__ b3,
                                                   float* __restrict__ node_attr) {
    __shared__ u16 A[MT * K3_STRIDE];
    const int n0 = blockIdx.x * MT;
    const int t = threadIdx.x;
    const int lane = t & 63, wv = t >> 6;
    {   // coalesced builder: wave wv handles rows wv*16 .. wv*16+15
        for (int rr = 0; rr < 16; rr++) {
            const int row = wv * 16 + rr;
            const int n = n0 + row;
            const float* xr = x + (size_t)n * NODE_IN;
            const unsigned* vr = (const unsigned*)(vmsg + (size_t)n * HID);
            u16* dstr = &A[row * K3_STRIDE];
            dstr[lane] = f2bu(xr[lane]);                 // k 0..63
            dstr[64 + lane] = f2bu(xr[64 + lane]);       // k 64..127
            if (lane < 5) dstr[128 + lane] = f2bu(xr[128 + lane]);  // 128..132
            const unsigned v = vr[lane];                 // 2 bf16
            dstr[NODE_IN + 2 * lane] = (u16)(v & 0xFFFFu);
            dstr[NODE_IN + 2 * lane + 1] = (u16)(v >> 16);
            if (lane < K3_PAD - (NODE_IN + HID))         // 261..287
                dstr[NODE_IN + HID + lane] = 0;
        }
    }
    __syncthreads();

    const int wm = wv & 1, wn = wv >> 1;
    const int lr = lane & 15, lk = (lane >> 4) * 8;
    f32x4 acc[2][4];
#pragma unroll
    for (int m = 0; m < 2; m++)
#pragma unroll
        for (int n = 0; n < 4; n++) acc[m][n] = (f32x4){0.f, 0.f, 0.f, 0.f};

    const int ar0 = (wm * 32 + lr) * K3_STRIDE + lk;
#pragma unroll
    for (int ks = 0; ks < K3_PAD / 32; ks++) {
        const int kk = ks * 32;
        const bf16x8 a0 = *(const bf16x8*)&A[ar0 + kk];
        const bf16x8 a1 = *(const bf16x8*)&A[ar0 + 16 * K3_STRIDE + kk];
#pragma unroll
        for (int n = 0; n < 4; n++) {
            const bf16x8 b = *(const bf16x8*)&WT3[(size_t)(wn * 64 + n * 16 + lr) * K3_STRIDE + kk + lk];
            acc[0][n] = __builtin_amdgcn_mfma_f32_16x16x32_bf16(a0, b, acc[0][n], 0, 0, 0);
            acc[1][n] = __builtin_amdgcn_mfma_f32_16x16x32_bf16(a1, b, acc[1][n], 0, 0, 0);
        }
    }

    const int lr4 = lane >> 4;
#pragma unroll
    for (int n = 0; n < 4; n++) {
        const int col = wn * 64 + n * 16 + lr;
        const float bias = b3[col];
#pragma unroll
        for (int m = 0; m < 2; m++)
#pragma unroll
            for (int j = 0; j < 4; j++) {
                const int nd = n0 + wm * 32 + m * 16 + lr4 * 4 + j;
                float v = acc[m][n][j] + bias;
                node_attr[(size_t)nd * HID + col] = v > 0.f ? v : 0.f;
            }
    }
}

// ---------------------------------------------------------------------------
// K6: out[g] = mean over the graph's (sorted, contiguous) node range.
// ---------------------------------------------------------------------------
__global__ __launch_bounds__(128) void k_pool2(const float* __restrict__ node_attr,
                                               const int* __restrict__ batch,
                                               float* __restrict__ out) {
    const int g = blockIdx.x;
    __shared__ int lo_s, hi_s;
    if (threadIdx.x == 0) {
        int lo = 0, hi = N_NODES;
        while (lo < hi) { int mid = (lo + hi) >> 1; if (batch[mid] < g) lo = mid + 1; else hi = mid; }
        lo_s = lo;
        int lo2 = lo, hi2 = N_NODES;
        while (lo2 < hi2) { int mid = (lo2 + hi2) >> 1; if (batch[mid] <= g) lo2 = mid + 1; else hi2 = mid; }
        hi_s = lo2;
    }
    __syncthreads();
    const int lo = lo_s, hi = hi_s;
    float acc = 0.f;
    for (int n = lo; n < hi; n++) acc += node_attr[(size_t)n * HID + threadIdx.x];
    const float cnt = (hi > lo) ? (float)(hi - lo) : 1.f;
    out[(size_t)g * HID + threadIdx.x] = acc / cnt;
}

// ---------------------------------------------------------------------------
extern "C" void kernel_launch(void* const* d_in, const int* in_sizes, int n_in,
                              void* d_out, int out_size, void* d_ws, size_t ws_size,
                              hipStream_t stream) {
    const float* x   = (const float*)d_in[0];
    const float* ea  = (const float*)d_in[1];
    const float* W1  = (const float*)d_in[2];
    const float* b1  = (const float*)d_in[3];
    const float* W2  = (const float*)d_in[4];
    const float* b2  = (const float*)d_in[5];
    const float* W3  = (const float*)d_in[6];
    const float* b3  = (const float*)d_in[7];
    const int*   ei  = (const int*)d_in[8];
    const int*   src = ei;
    const int*   dst = ei + N_EDGES;
    const int*   rev = (const int*)d_in[9];
    const int*   bat = (const int*)d_in[10];

    char* ws = (char*)d_ws;
    size_t off = 0;
    auto alloc = [&](size_t bytes) -> void* {
        void* p = ws + off;
        off += (bytes + 255) & ~(size_t)255;
        return p;
    };
    const size_t hbytes = (size_t)N_EDGES * HID;                 // 102.4 MB fp8
    u8* h0 = (u8*)alloc(hbytes);
    u8* hA = (u8*)alloc(hbytes);
    u8* hB = (u8*)alloc(hbytes);
    u16* node_sum = (u16*)alloc((size_t)N_NODES * HID * sizeof(u16));  // 51.2 MB
    int* row_ptr = (int*)alloc((size_t)(N_NODES + 1) * sizeof(int));
    int* eidx = (int*)alloc((size_t)N_EDGES * sizeof(int));
    u16* WT1 = (u16*)alloc((size_t)HID * K1_STRIDE * sizeof(u16));
    u16* WT2 = (u16*)alloc((size_t)HID * K2_STRIDE * sizeof(u16));
    u16* WT3 = (u16*)alloc((size_t)HID * K3_STRIDE * sizeof(u16));
    // Aliases (footprint unchanged, ~363 MB < proven 415.7 MB floor):
    //  - xw (bf16, 51.2 MB) lives in hA: dead before the first k_msg writes hA.
    //  - node_attr (fp32, 102.4 MB) lives in h0: dead after last k_msg read.
    u16* xw = (u16*)hA;
    float* node_attr = (float*)h0;

    if (ws_size < off) return;  // diagnostic: leave d_out untouched

    // weight transpose+pad to bf16
    k_prep<<<(HID * K1_STRIDE + 255) / 256, 256, 0, stream>>>(W1, WT1, NODE_IN + EDGE_IN, K1_STRIDE);
    k_prep<<<(HID * K2_STRIDE + 255) / 256, 256, 0, stream>>>(W2, WT2, HID, K2_STRIDE);
    k_prep<<<(HID * K3_STRIDE + 255) / 256, 256, 0, stream>>>(W3, WT3, NODE_IN + HID, K3_STRIDE);

    // CSR build (transients overlay node_sum, not live yet; 9.6 MB < 51.2 MB)
    {
        int* cnt = (int*)node_sum;
        int* local = cnt + N_NODES;
        int* cursor = local + N_NODES;
        int* partial = cursor + N_NODES;
        hipMemsetAsync(cnt, 0, (size_t)N_NODES * sizeof(int), stream);
        k_hist<<<(N_EDGES + 255) / 256, 256, 0, stream>>>(dst, cnt);
        k_scan1<<<SCAN_NBLK, 256, 0, stream>>>(cnt, local, partial);
        k_scan2<<<1, 256, 0, stream>>>(partial);
        k_scan3<<<(N_NODES + 256) / 256, 256, 0, stream>>>(local, partial, row_ptr, cursor);
        k_place<<<(N_EDGES + 255) / 256, 256, 0, stream>>>(dst, cursor, eidx);
    }

    // h0 = relu(x[src]@W1x + ea@W1e + b1), split per-node GEMM + fused epilogue
    k_xw<<<N_NODES / MT, 256, 0, stream>>>(x, WT1, xw);
    k_init2<<<N_EDGES / 8, 256, 0, stream>>>(xw, ea, W1, b1, src, h0);

    const u8* h = h0;
    u8* bufs[2] = {hA, hB};
    const int agg_blocks = (int)(((long long)N_NODES * 32 + 255) / 256);
    for (int it = 0; it < 3; it++) {
        k_gather<<<agg_blocks, 256, 0, stream>>>(h, row_ptr, eidx, node_sum);
        u8* hn = bufs[it & 1];   // it=0 writes hA (xw already consumed)
        k_msg_mfma<<<N_EDGES / MT, 256, 0, stream>>>(node_sum, h, h0, WT2, b2, src, rev, hn);
        h = hn;
    }
    k_gather<<<agg_blocks, 256, 0, stream>>>(h, row_ptr, eidx, node_sum);

    // h0 is dead from here; node_attr reuses its storage.
    k_node_mfma<<<N_NODES / MT, 256, 0, stream>>>(x, node_sum, WT3, b3, node_attr);
    k_pool2<<<NUM_GRAPHS, 128, 0, stream>>>(node_attr, bat, (float*)d_out);
}

// Round 10
// 1219.726 us; speedup vs baseline: 1.4169x; 1.4169x over previous
//
#include <hip/hip_runtime.h>

#define N_NODES 200000
#define N_EDGES 800000
#define NODE_IN 133
#define EDGE_IN 14
#define HID 128
#define NUM_GRAPHS 4096

#define SCAN_CHUNK 2048
#define SCAN_NBLK ((N_NODES + SCAN_CHUNK - 1) / SCAN_CHUNK)  // 98

#define MT 64  // M tile rows per block for MFMA GEMMs

// K geometry per GEMM (padded K, LDS/WT row stride in elements)
#define K1_PAD 160
#define K1_STRIDE 168
#define K2_PAD 128
#define K2_STRIDE 136
#define K3_PAD 288
#define K3_STRIDE 296

typedef unsigned short u16;
typedef unsigned char u8;
typedef short bf16x8 __attribute__((ext_vector_type(8)));
typedef float f32x4 __attribute__((ext_vector_type(4)));

__device__ __forceinline__ float bu2f(unsigned s) {
    return __uint_as_float(s << 16);
}
__device__ __forceinline__ u16 f2bu(float f) {
    unsigned u = __float_as_uint(f);
    return (u16)((u + 0x7FFFu + ((u >> 16) & 1u)) >> 16);  // RNE
}
// ---------------- fp8 e4m3 (OCP), non-negative post-ReLU values -----------
__device__ __forceinline__ float e42f(unsigned b) {
    unsigned E = (b >> 4) & 0xF, M = b & 7u;
    if (E == 0) return (float)M * 0.001953125f;  // M * 2^-9
    return __uint_as_float(((E - 7u + 127u) << 23) | (M << 20));
}
__device__ __forceinline__ u8 f2e4(float f) {
    if (!(f > 0.f)) return 0;
    if (f >= 448.f) return 0x7E;
    unsigned u = __float_as_uint(f);
    int e = (int)((u >> 23) & 0xFF) - 127;
    if (e < -6) {
        int q = (int)rintf(f * 512.f);
        return (u8)q;
    }
    unsigned m = u & 0x7FFFFF;
    unsigned keep = m >> 20, rem = m & 0xFFFFF;
    keep += (rem > 0x80000u || (rem == 0x80000u && (keep & 1u))) ? 1u : 0u;
    unsigned E = (unsigned)(e + 7);
    if (keep == 8u) { keep = 0u; E++; }
    return (u8)((E << 4) | keep);
}

// ---------------- HW fp8 convert (gfx950 OCP) with software fallback -------
#if defined(__has_builtin)
#if __has_builtin(__builtin_amdgcn_cvt_f32_fp8) && __has_builtin(__builtin_amdgcn_cvt_pk_fp8_f32)
#define HW_FP8 1
#endif
#endif

#if defined(HW_FP8)
// sel must be a compile-time constant
#define FP8_DEC(dw, s) __builtin_amdgcn_cvt_f32_fp8((int)(dw), (s))
__device__ __forceinline__ unsigned fp8_pk(float a, float b) {
    a = fminf(fmaxf(a, 0.f), 448.f);  // ReLU + sat (matches sw path)
    b = fminf(fmaxf(b, 0.f), 448.f);
    return (unsigned)__builtin_amdgcn_cvt_pk_fp8_f32(a, b, 0, false) & 0xFFFFu;
}
#else
#define FP8_DEC(dw, s) e42f(((dw) >> (8 * (s))) & 0xFFu)
__device__ __forceinline__ unsigned fp8_pk(float a, float b) {
    return (unsigned)f2e4(a) | ((unsigned)f2e4(b) << 8);
}
#endif

__device__ __forceinline__ int clampi(int v, int hi) {
    return v < 0 ? 0 : (v >= hi ? hi - 1 : v);
}

// ---------------------------------------------------------------------------
// Weight prep: WT[n][k] = bf16(W[k][n]), k < K else 0.
// ---------------------------------------------------------------------------
__global__ __launch_bounds__(256) void k_prep(const float* __restrict__ W,
                                              u16* __restrict__ WT, int K,
                                              int stride) {
    const int idx = blockIdx.x * 256 + threadIdx.x;
    if (idx >= HID * stride) return;
    const int n = idx / stride, k = idx % stride;
    WT[idx] = (k < K) ? f2bu(W[k * HID + n]) : (u16)0;
}

// ---------------------------------------------------------------------------
// CSR build: histogram -> exclusive scan -> atomic-cursor placement
// ---------------------------------------------------------------------------
__global__ __launch_bounds__(256) void k_hist(const int* __restrict__ dst,
                                              int* __restrict__ cnt) {
    const int e = blockIdx.x * 256 + threadIdx.x;
    if (e < N_EDGES) atomicAdd(&cnt[clampi(dst[e], N_NODES)], 1);
}

__global__ __launch_bounds__(256) void k_scan1(const int* __restrict__ cnt,
                                               int* __restrict__ local,
                                               int* __restrict__ partial) {
    __shared__ int tsum[256];
    const int b = blockIdx.x, t = threadIdx.x;
    const int base = b * SCAN_CHUNK + t * 8;
    int v[8];
    int s = 0;
#pragma unroll
    for (int i = 0; i < 8; i++) {
        const int idx = base + i;
        v[i] = (idx < N_NODES) ? cnt[idx] : 0;
        s += v[i];
    }
    tsum[t] = s;
    __syncthreads();
    for (int ofs = 1; ofs < 256; ofs <<= 1) {
        const int add = (t >= ofs) ? tsum[t - ofs] : 0;
        __syncthreads();
        tsum[t] += add;
        __syncthreads();
    }
    int excl = (t == 0) ? 0 : tsum[t - 1];
    if (t == 255) partial[b] = tsum[255];
#pragma unroll
    for (int i = 0; i < 8; i++) {
        const int idx = base + i;
        if (idx < N_NODES) local[idx] = excl;
        excl += v[i];
    }
}

__global__ __launch_bounds__(256) void k_scan2(int* __restrict__ partial) {
    __shared__ int s[256];
    const int t = threadIdx.x;
    s[t] = (t < SCAN_NBLK) ? partial[t] : 0;
    __syncthreads();
    for (int ofs = 1; ofs < 256; ofs <<= 1) {
        const int add = (t >= ofs) ? s[t - ofs] : 0;
        __syncthreads();
        s[t] += add;
        __syncthreads();
    }
    if (t < SCAN_NBLK) partial[t] = (t == 0) ? 0 : s[t - 1];
}

__global__ __launch_bounds__(256) void k_scan3(const int* __restrict__ local,
                                               const int* __restrict__ partial,
                                               int* __restrict__ row_ptr,
                                               int* __restrict__ cursor) {
    const int idx = blockIdx.x * 256 + threadIdx.x;
    if (idx <= N_NODES) {
        const int v = (idx == N_NODES) ? N_EDGES
                                       : local[idx] + partial[idx / SCAN_CHUNK];
        row_ptr[idx] = v;
        if (idx < N_NODES) cursor[idx] = v;
    }
}

__global__ __launch_bounds__(256) void k_place(const int* __restrict__ dst,
                                               int* __restrict__ cursor,
                                               int* __restrict__ eidx) {
    const int e = blockIdx.x * 256 + threadIdx.x;
    if (e < N_EDGES) {
        const int slot = atomicAdd(&cursor[clampi(dst[e], N_NODES)], 1);
        eidx[slot] = e;
    }
}

// ---------------------------------------------------------------------------
// K2 (CSR gather): node_sum[n] = sum_{e in csr[n]} h[e]  (fp8 in, fp32 acc,
// bf16 out). 32 threads per node, 4 channels each.
// ---------------------------------------------------------------------------
__global__ __launch_bounds__(256) void k_gather(const u8* __restrict__ h,
                                                const int* __restrict__ row_ptr,
                                                const int* __restrict__ eidx,
                                                u16* __restrict__ node_sum) {
    const long long idx = (long long)blockIdx.x * 256 + threadIdx.x;
    const int n = (int)(idx >> 5);
    if (n >= N_NODES) return;
    const int c4 = (int)(idx & 31) << 2;
    const int beg = row_ptr[n], end = row_ptr[n + 1];
    float a0 = 0.f, a1 = 0.f, a2 = 0.f, a3 = 0.f;
    for (int j = beg; j < end; j++) {
        const int e = eidx[j];
        const unsigned v = *reinterpret_cast<const unsigned*>(h + (long long)e * HID + c4);
        a0 += FP8_DEC(v, 0); a1 += FP8_DEC(v, 1);
        a2 += FP8_DEC(v, 2); a3 += FP8_DEC(v, 3);
    }
    ushort4 o;
    o.x = f2bu(a0); o.y = f2bu(a1); o.z = f2bu(a2); o.w = f2bu(a3);
    *reinterpret_cast<ushort4*>(node_sum + (long long)n * HID + c4) = o;
}

// ---------------------------------------------------------------------------
// MFMA geometry (64x128 tile, 4 waves: 2 in M x 2 in N)
// a-frag: lane holds A[lane&15][(lane>>4)*8 + i]; b-frag: B[(lane>>4)*8+i][lane&15]
// with B[k][n] = WT[n][k].  C/D: col = lane&15, row = (lane>>4)*4 + reg.
// ---------------------------------------------------------------------------

// K1a: xw[n] = x[n] @ W1x  (per-NODE GEMM; A cols 133..159 zeroed)
__global__ __launch_bounds__(256) void k_xw(const float* __restrict__ x,
                                            const u16* __restrict__ WT1,
                                            u16* __restrict__ xw) {
    __shared__ u16 A[MT * K1_STRIDE];
    const int n0 = blockIdx.x * MT;
    const int t = threadIdx.x;
    const int lane = t & 63, wv = t >> 6;
    for (int rr = 0; rr < 16; rr++) {
        const int row = wv * 16 + rr;
        const int n = n0 + row;
        const float* xr = x + (size_t)n * NODE_IN;
        u16* dstr = &A[row * K1_STRIDE];
        dstr[lane] = f2bu(xr[lane]);                 // k 0..63
        dstr[64 + lane] = f2bu(xr[64 + lane]);       // k 64..127
        if (lane < 5) dstr[128 + lane] = f2bu(xr[128 + lane]);  // 128..132
        if (lane < K1_PAD - NODE_IN) dstr[NODE_IN + lane] = 0;  // 133..159
    }
    __syncthreads();

    const int wm = wv & 1, wn = wv >> 1;
    const int lr = lane & 15, lk = (lane >> 4) * 8;
    f32x4 acc[2][4];
#pragma unroll
    for (int m = 0; m < 2; m++)
#pragma unroll
        for (int n = 0; n < 4; n++) acc[m][n] = (f32x4){0.f, 0.f, 0.f, 0.f};

    const int ar0 = (wm * 32 + lr) * K1_STRIDE + lk;
#pragma unroll
    for (int ks = 0; ks < K1_PAD / 32; ks++) {
        const int kk = ks * 32;
        const bf16x8 a0 = *(const bf16x8*)&A[ar0 + kk];
        const bf16x8 a1 = *(const bf16x8*)&A[ar0 + 16 * K1_STRIDE + kk];
#pragma unroll
        for (int n = 0; n < 4; n++) {
            const bf16x8 b = *(const bf16x8*)&WT1[(size_t)(wn * 64 + n * 16 + lr) * K1_STRIDE + kk + lk];
            acc[0][n] = __builtin_amdgcn_mfma_f32_16x16x32_bf16(a0, b, acc[0][n], 0, 0, 0);
            acc[1][n] = __builtin_amdgcn_mfma_f32_16x16x32_bf16(a1, b, acc[1][n], 0, 0, 0);
        }
    }

    const int lr4 = lane >> 4;
#pragma unroll
    for (int n = 0; n < 4; n++) {
        const int col = wn * 64 + n * 16 + lr;
#pragma unroll
        for (int m = 0; m < 2; m++)
#pragma unroll
            for (int j = 0; j < 4; j++) {
                const int nd = n0 + wm * 32 + m * 16 + lr4 * 4 + j;
                xw[(size_t)nd * HID + col] = f2bu(acc[m][n][j]);
            }
    }
}

// K1b: h0[e] = relu(xw[src[e]] + ea[e]@W1e + b1) -> fp8.
// 16 edges/block, 32 lanes/edge, 4 ch/lane, 2 edges per thread (ILP).
__global__ __launch_bounds__(256) void k_init2(const u16* __restrict__ xw,
                                               const float* __restrict__ ea,
                                               const float* __restrict__ W1,
                                               const float* __restrict__ b1,
                                               const int* __restrict__ src,
                                               u8* __restrict__ h0) {
    __shared__ float w1e[EDGE_IN * HID];  // 7 KB
    __shared__ float b1s[HID];
    const int t = threadIdx.x;
    for (int i = t; i < EDGE_IN * HID; i += 256)
        w1e[i] = W1[(NODE_IN + i / HID) * HID + (i % HID)];
    if (t < HID) b1s[t] = b1[t];
    __syncthreads();

    const int g = t >> 5;                 // 0..7
    const int c4 = (t & 31) << 2;
    const int e1 = blockIdx.x * 16 + g;
    const int e2 = e1 + 8;
    const int s1 = clampi(src[e1], N_NODES);
    const int s2 = clampi(src[e2], N_NODES);
    const ushort4 xv1 = *(const ushort4*)(xw + (size_t)s1 * HID + c4);
    const ushort4 xv2 = *(const ushort4*)(xw + (size_t)s2 * HID + c4);
    const float4 bb = *(const float4*)&b1s[c4];
    float a0 = bu2f(xv1.x) + bb.x, a1 = bu2f(xv1.y) + bb.y;
    float a2 = bu2f(xv1.z) + bb.z, a3 = bu2f(xv1.w) + bb.w;
    float d0 = bu2f(xv2.x) + bb.x, d1 = bu2f(xv2.y) + bb.y;
    float d2 = bu2f(xv2.z) + bb.z, d3 = bu2f(xv2.w) + bb.w;
    const float* er1 = ea + (size_t)e1 * EDGE_IN;
    const float* er2 = ea + (size_t)e2 * EDGE_IN;
#pragma unroll
    for (int k = 0; k < EDGE_IN; k++) {
        const float4 w = *(const float4*)&w1e[k * HID + c4];
        const float ev1 = er1[k], ev2 = er2[k];
        a0 = fmaf(ev1, w.x, a0); a1 = fmaf(ev1, w.y, a1);
        a2 = fmaf(ev1, w.z, a2); a3 = fmaf(ev1, w.w, a3);
        d0 = fmaf(ev2, w.x, d0); d1 = fmaf(ev2, w.y, d1);
        d2 = fmaf(ev2, w.z, d2); d3 = fmaf(ev2, w.w, d3);
    }
    const unsigned p1 = fp8_pk(a0, a1) | (fp8_pk(a2, a3) << 16);
    const unsigned p2 = fp8_pk(d0, d1) | (fp8_pk(d2, d3) << 16);
    *(unsigned*)(h0 + (size_t)e1 * HID + c4) = p1;
    *(unsigned*)(h0 + (size_t)e2 * HID + c4) = p2;
}

// K3: hn = relu(h0 + (node_sum[src] - h[rev]) @ W2 + b2)  (fp8 states)
__global__ __launch_bounds__(256) void k_msg_mfma(const u16* __restrict__ ns,
                                                  const u8* __restrict__ h,
                                                  const u8* __restrict__ h0g,
                                                  const u16* __restrict__ WT2,
                                                  const float* __restrict__ b2,
                                                  const int* __restrict__ src,
                                                  const int* __restrict__ rev,
                                                  u8* __restrict__ hn) {
    __shared__ u16 A[MT * K2_STRIDE];
    const int e0 = blockIdx.x * MT;
    const int t = threadIdx.x;
    {   // builder: 4 threads/row, 32 channels each (vector loads; random rows)
        const int le = t >> 2, j = t & 3;
        const int e = e0 + le;
        const int s = clampi(src[e], N_NODES);
        const int r = clampi(rev[e], N_EDGES);
        const u16* nsr = ns + (size_t)s * HID + j * 32;
        const u8* hr = h + (size_t)r * HID + j * 32;
        u16* dstr = &A[le * K2_STRIDE + j * 32];
#pragma unroll
        for (int q = 0; q < 4; q++) {
            const uint4 nv = *(const uint4*)(nsr + q * 8);  // 8 bf16
            const uint2 hv = *(const uint2*)(hr + q * 8);   // 8 fp8
            union { bf16x8 v; u16 s[8]; } o;
            o.s[0] = f2bu(bu2f(nv.x & 0xFFFFu) - FP8_DEC(hv.x, 0));
            o.s[1] = f2bu(bu2f(nv.x >> 16)     - FP8_DEC(hv.x, 1));
            o.s[2] = f2bu(bu2f(nv.y & 0xFFFFu) - FP8_DEC(hv.x, 2));
            o.s[3] = f2bu(bu2f(nv.y >> 16)     - FP8_DEC(hv.x, 3));
            o.s[4] = f2bu(bu2f(nv.z & 0xFFFFu) - FP8_DEC(hv.y, 0));
            o.s[5] = f2bu(bu2f(nv.z >> 16)     - FP8_DEC(hv.y, 1));
            o.s[6] = f2bu(bu2f(nv.w & 0xFFFFu) - FP8_DEC(hv.y, 2));
            o.s[7] = f2bu(bu2f(nv.w >> 16)     - FP8_DEC(hv.y, 3));
            *(bf16x8*)(dstr + q * 8) = o.v;
        }
    }
    __syncthreads();

    const int lane = t & 63, wid = t >> 6;
    const int wm = wid & 1, wn = wid >> 1;
    const int lr = lane & 15, lk = (lane >> 4) * 8;
    f32x4 acc[2][4];
#pragma unroll
    for (int m = 0; m < 2; m++)
#pragma unroll
        for (int n = 0; n < 4; n++) acc[m][n] = (f32x4){0.f, 0.f, 0.f, 0.f};

    const int ar0 = (wm * 32 + lr) * K2_STRIDE + lk;
#pragma unroll
    for (int ks = 0; ks < K2_PAD / 32; ks++) {
        const int kk = ks * 32;
        const bf16x8 a0 = *(const bf16x8*)&A[ar0 + kk];
        const bf16x8 a1 = *(const bf16x8*)&A[ar0 + 16 * K2_STRIDE + kk];
#pragma unroll
        for (int n = 0; n < 4; n++) {
            const bf16x8 b = *(const bf16x8*)&WT2[(size_t)(wn * 64 + n * 16 + lr) * K2_STRIDE + kk + lk];
            acc[0][n] = __builtin_amdgcn_mfma_f32_16x16x32_bf16(a0, b, acc[0][n], 0, 0, 0);
            acc[1][n] = __builtin_amdgcn_mfma_f32_16x16x32_bf16(a1, b, acc[1][n], 0, 0, 0);
        }
    }

    const int lr4 = lane >> 4;
#pragma unroll
    for (int n = 0; n < 4; n++) {
        const int col = wn * 64 + n * 16 + lr;
        const float bias = b2[col];
#pragma unroll
        for (int m = 0; m < 2; m++) {
            const long long eb = e0 + wm * 32 + m * 16 + lr4 * 4;
            const size_t i0 = (size_t)eb * HID + col;
            float v0 = FP8_DEC((unsigned)h0g[i0], 0)            + acc[m][n][0] + bias;
            float v1 = FP8_DEC((unsigned)h0g[i0 + HID], 0)      + acc[m][n][1] + bias;
            float v2 = FP8_DEC((unsigned)h0g[i0 + 2 * HID], 0)  + acc[m][n][2] + bias;
            float v3 = FP8_DEC((unsigned)h0g[i0 + 3 * HID], 0)  + acc[m][n][3] + bias;
            const unsigned pa = fp8_pk(v0, v1);
            const unsigned pb = fp8_pk(v2, v3);
            hn[i0] = (u8)pa;           hn[i0 + HID] = (u8)(pa >> 8);
            hn[i0 + 2 * HID] = (u8)pb; hn[i0 + 3 * HID] = (u8)(pb >> 8);
        }
    }
}

// K5: node_attr[n] = relu(concat(x[n], vmsg[n]) @ W3 + b3)  (fp32 out)
__global__ __launch_bounds__(256) void k_node_mfma(const float* __restrict__ x,
                                                   const u16* __restrict__ vmsg,
                                                   const u16* __restrict__ WT3,
                                                   const float* __restrict__ b3,
                                                   float* __restrict__ node_attr) {
    __shared__ u16 A[MT * K3_STRIDE];
    const int n0 = blockIdx.x * MT;
    const int t = threadIdx.x;
    const int lane = t & 63, wv = t >> 6;
    {   // coalesced builder: wave wv handles rows wv*16 .. wv*16+15
        for (int rr = 0; rr < 16; rr++) {
            const int row = wv * 16 + rr;
            const int n = n0 + row;
            const float* xr = x + (size_t)n * NODE_IN;
            const unsigned* vr = (const unsigned*)(vmsg + (size_t)n * HID);
            u16* dstr = &A[row * K3_STRIDE];
            dstr[lane] = f2bu(xr[lane]);                 // k 0..63
            dstr[64 + lane] = f2bu(xr[64 + lane]);       // k 64..127
            if (lane < 5) dstr[128 + lane] = f2bu(xr[128 + lane]);  // 128..132
            const unsigned v = vr[lane];                 // 2 bf16
            dstr[NODE_IN + 2 * lane] = (u16)(v & 0xFFFFu);
            dstr[NODE_IN + 2 * lane + 1] = (u16)(v >> 16);
            if (lane < K3_PAD - (NODE_IN + HID))         // 261..287
                dstr[NODE_IN + HID + lane] = 0;
        }
    }
    __syncthreads();

    const int wm = wv & 1, wn = wv >> 1;
    const int lr = lane & 15, lk = (lane >> 4) * 8;
    f32x4 acc[2][4];
#pragma unroll
    for (int m = 0; m < 2; m++)
#pragma unroll
        for (int n = 0; n < 4; n++) acc[m][n] = (f32x4){0.f, 0.f, 0.f, 0.f};

    const int ar0 = (wm * 32 + lr) * K3_STRIDE + lk;
#pragma unroll
    for (int ks = 0; ks < K3_PAD / 32; ks++) {
        const int kk = ks * 32;
        const bf16x8 a0 = *(const bf16x8*)&A[ar0 + kk];
        const bf16x8 a1 = *(const bf16x8*)&A[ar0 + 16 * K3_STRIDE + kk];
#pragma unroll
        for (int n = 0; n < 4; n++) {
            const bf16x8 b = *(const bf16x8*)&WT3[(size_t)(wn * 64 + n * 16 + lr) * K3_STRIDE + kk + lk];
            acc[0][n] = __builtin_amdgcn_mfma_f32_16x16x32_bf16(a0, b, acc[0][n], 0, 0, 0);
            acc[1][n] = __builtin_amdgcn_mfma_f32_16x16x32_bf16(a1, b, acc[1][n], 0, 0, 0);
        }
    }

    const int lr4 = lane >> 4;
#pragma unroll
    for (int n = 0; n < 4; n++) {
        const int col = wn * 64 + n * 16 + lr;
        const float bias = b3[col];
#pragma unroll
        for (int m = 0; m < 2; m++)
#pragma unroll
            for (int j = 0; j < 4; j++) {
                const int nd = n0 + wm * 32 + m * 16 + lr4 * 4 + j;
                float v = acc[m][n][j] + bias;
                node_attr[(size_t)nd * HID + col] = v > 0.f ? v : 0.f;
            }
    }
}

// ---------------------------------------------------------------------------
// K6: out[g] = mean over the graph's (sorted, contiguous) node range.
// ---------------------------------------------------------------------------
__global__ __launch_bounds__(128) void k_pool2(const float* __restrict__ node_attr,
                                               const int* __restrict__ batch,
                                               float* __restrict__ out) {
    const int g = blockIdx.x;
    __shared__ int lo_s, hi_s;
    if (threadIdx.x == 0) {
        int lo = 0, hi = N_NODES;
        while (lo < hi) { int mid = (lo + hi) >> 1; if (batch[mid] < g) lo = mid + 1; else hi = mid; }
        lo_s = lo;
        int lo2 = lo, hi2 = N_NODES;
        while (lo2 < hi2) { int mid = (lo2 + hi2) >> 1; if (batch[mid] <= g) lo2 = mid + 1; else hi2 = mid; }
        hi_s = lo2;
    }
    __syncthreads();
    const int lo = lo_s, hi = hi_s;
    float acc = 0.f;
    for (int n = lo; n < hi; n++) acc += node_attr[(size_t)n * HID + threadIdx.x];
    const float cnt = (hi > lo) ? (float)(hi - lo) : 1.f;
    out[(size_t)g * HID + threadIdx.x] = acc / cnt;
}

// ---------------------------------------------------------------------------
extern "C" void kernel_launch(void* const* d_in, const int* in_sizes, int n_in,
                              void* d_out, int out_size, void* d_ws, size_t ws_size,
                              hipStream_t stream) {
    const float* x   = (const float*)d_in[0];
    const float* ea  = (const float*)d_in[1];
    const float* W1  = (const float*)d_in[2];
    const float* b1  = (const float*)d_in[3];
    const float* W2  = (const float*)d_in[4];
    const float* b2  = (const float*)d_in[5];
    const float* W3  = (const float*)d_in[6];
    const float* b3  = (const float*)d_in[7];
    const int*   ei  = (const int*)d_in[8];
    const int*   src = ei;
    const int*   dst = ei + N_EDGES;
    const int*   rev = (const int*)d_in[9];
    const int*   bat = (const int*)d_in[10];

    char* ws = (char*)d_ws;
    size_t off = 0;
    auto alloc = [&](size_t bytes) -> void* {
        void* p = ws + off;
        off += (bytes + 255) & ~(size_t)255;
        return p;
    };
    const size_t hbytes = (size_t)N_EDGES * HID;                 // 102.4 MB fp8
    u8* h0 = (u8*)alloc(hbytes);
    u8* hA = (u8*)alloc(hbytes);
    u8* hB = (u8*)alloc(hbytes);
    u16* node_sum = (u16*)alloc((size_t)N_NODES * HID * sizeof(u16));  // 51.2 MB
    int* row_ptr = (int*)alloc((size_t)(N_NODES + 1) * sizeof(int));
    int* eidx = (int*)alloc((size_t)N_EDGES * sizeof(int));
    u16* WT1 = (u16*)alloc((size_t)HID * K1_STRIDE * sizeof(u16));
    u16* WT2 = (u16*)alloc((size_t)HID * K2_STRIDE * sizeof(u16));
    u16* WT3 = (u16*)alloc((size_t)HID * K3_STRIDE * sizeof(u16));
    // Aliases (footprint unchanged, ~363 MB < proven 415.7 MB floor):
    //  - xw (bf16, 51.2 MB) lives in hA: dead before the first k_msg writes hA.
    //  - node_attr (fp32, 102.4 MB) lives in h0: dead after last k_msg read.
    u16* xw = (u16*)hA;
    float* node_attr = (float*)h0;

    if (ws_size < off) return;  // diagnostic: leave d_out untouched

    // weight transpose+pad to bf16
    k_prep<<<(HID * K1_STRIDE + 255) / 256, 256, 0, stream>>>(W1, WT1, NODE_IN + EDGE_IN, K1_STRIDE);
    k_prep<<<(HID * K2_STRIDE + 255) / 256, 256, 0, stream>>>(W2, WT2, HID, K2_STRIDE);
    k_prep<<<(HID * K3_STRIDE + 255) / 256, 256, 0, stream>>>(W3, WT3, NODE_IN + HID, K3_STRIDE);

    // CSR build (transients overlay node_sum, not live yet; 9.6 MB < 51.2 MB)
    {
        int* cnt = (int*)node_sum;
        int* local = cnt + N_NODES;
        int* cursor = local + N_NODES;
        int* partial = cursor + N_NODES;
        hipMemsetAsync(cnt, 0, (size_t)N_NODES * sizeof(int), stream);
        k_hist<<<(N_EDGES + 255) / 256, 256, 0, stream>>>(dst, cnt);
        k_scan1<<<SCAN_NBLK, 256, 0, stream>>>(cnt, local, partial);
        k_scan2<<<1, 256, 0, stream>>>(partial);
        k_scan3<<<(N_NODES + 256) / 256, 256, 0, stream>>>(local, partial, row_ptr, cursor);
        k_place<<<(N_EDGES + 255) / 256, 256, 0, stream>>>(dst, cursor, eidx);
    }

    // h0 = relu(x[src]@W1x + ea@W1e + b1), split per-node GEMM + fused epilogue
    k_xw<<<N_NODES / MT, 256, 0, stream>>>(x, WT1, xw);
    k_init2<<<N_EDGES / 16, 256, 0, stream>>>(xw, ea, W1, b1, src, h0);

    const u8* h = h0;
    u8* bufs[2] = {hA, hB};
    const int agg_blocks = (int)(((long long)N_NODES * 32 + 255) / 256);
    for (int it = 0; it < 3; it++) {
        k_gather<<<agg_blocks, 256, 0, stream>>>(h, row_ptr, eidx, node_sum);
        u8* hn = bufs[it & 1];   // it=0 writes hA (xw already consumed)
        k_msg_mfma<<<N_EDGES / MT, 256, 0, stream>>>(node_sum, h, h0, WT2, b2, src, rev, hn);
        h = hn;
    }
    k_gather<<<agg_blocks, 256, 0, stream>>>(h, row_ptr, eidx, node_sum);

    // h0 is dead from here; node_attr reuses its storage.
    k_node_mfma<<<N_NODES / MT, 256, 0, stream>>>(x, node_sum, WT3, b3, node_attr);
    k_pool2<<<NUM_GRAPHS, 128, 0, stream>>>(node_attr, bat, (float*)d_out);
}

// Round 11
// 1061.754 us; speedup vs baseline: 1.6277x; 1.1488x over previous
//
#include <hip/hip_runtime.h>

#define N_NODES 200000
#define N_EDGES 800000
#define NODE_IN 133
#define EDGE_IN 14
#define HID 128
#define NUM_GRAPHS 4096

#define SCAN_CHUNK 2048
#define SCAN_NBLK ((N_NODES + SCAN_CHUNK - 1) / SCAN_CHUNK)  // 98

#define MT 64  // M tile rows per block for MFMA GEMMs

// K geometry per GEMM (padded K, LDS/WT row stride in elements)
#define K1_PAD 160
#define K1_STRIDE 168
#define K2_PAD 128
#define K2_STRIDE 136
#define K3_PAD 288
#define K3_STRIDE 296

typedef unsigned short u16;
typedef unsigned char u8;
typedef short bf16x8 __attribute__((ext_vector_type(8)));
typedef float f32x4 __attribute__((ext_vector_type(4)));

__device__ __forceinline__ float bu2f(unsigned s) {
    return __uint_as_float(s << 16);
}
__device__ __forceinline__ u16 f2bu(float f) {
    unsigned u = __float_as_uint(f);
    return (u16)((u + 0x7FFFu + ((u >> 16) & 1u)) >> 16);  // RNE
}
// ---------------- fp8 e4m3 (OCP), non-negative post-ReLU values -----------
__device__ __forceinline__ float e42f(unsigned b) {
    unsigned E = (b >> 4) & 0xF, M = b & 7u;
    if (E == 0) return (float)M * 0.001953125f;  // M * 2^-9
    return __uint_as_float(((E - 7u + 127u) << 23) | (M << 20));
}
__device__ __forceinline__ u8 f2e4(float f) {
    if (!(f > 0.f)) return 0;
    if (f >= 448.f) return 0x7E;
    unsigned u = __float_as_uint(f);
    int e = (int)((u >> 23) & 0xFF) - 127;
    if (e < -6) {
        int q = (int)rintf(f * 512.f);
        return (u8)q;
    }
    unsigned m = u & 0x7FFFFF;
    unsigned keep = m >> 20, rem = m & 0xFFFFF;
    keep += (rem > 0x80000u || (rem == 0x80000u && (keep & 1u))) ? 1u : 0u;
    unsigned E = (unsigned)(e + 7);
    if (keep == 8u) { keep = 0u; E++; }
    return (u8)((E << 4) | keep);
}

// ---------------- HW fp8 convert (gfx950 OCP) with software fallback -------
#if defined(__has_builtin)
#if __has_builtin(__builtin_amdgcn_cvt_f32_fp8) && __has_builtin(__builtin_amdgcn_cvt_pk_fp8_f32)
#define HW_FP8 1
#endif
#endif

#if defined(HW_FP8)
// sel must be a compile-time constant
#define FP8_DEC(dw, s) __builtin_amdgcn_cvt_f32_fp8((int)(dw), (s))
__device__ __forceinline__ unsigned fp8_pk(float a, float b) {
    a = fminf(fmaxf(a, 0.f), 448.f);  // ReLU + sat (matches sw path)
    b = fminf(fmaxf(b, 0.f), 448.f);
    return (unsigned)__builtin_amdgcn_cvt_pk_fp8_f32(a, b, 0, false) & 0xFFFFu;
}
#else
#define FP8_DEC(dw, s) e42f(((dw) >> (8 * (s))) & 0xFFu)
__device__ __forceinline__ unsigned fp8_pk(float a, float b) {
    return (unsigned)f2e4(a) | ((unsigned)f2e4(b) << 8);
}
#endif

__device__ __forceinline__ int clampi(int v, int hi) {
    return v < 0 ? 0 : (v >= hi ? hi - 1 : v);
}

// ---------------------------------------------------------------------------
// Weight prep: WT[n][k] = bf16(W[k][n]), k < K else 0.
// ---------------------------------------------------------------------------
__global__ __launch_bounds__(256) void k_prep(const float* __restrict__ W,
                                              u16* __restrict__ WT, int K,
                                              int stride) {
    const int idx = blockIdx.x * 256 + threadIdx.x;
    if (idx >= HID * stride) return;
    const int n = idx / stride, k = idx % stride;
    WT[idx] = (k < K) ? f2bu(W[k * HID + n]) : (u16)0;
}

// ---------------------------------------------------------------------------
// CSR build: histogram -> exclusive scan -> atomic-cursor placement
// ---------------------------------------------------------------------------
__global__ __launch_bounds__(256) void k_hist(const int* __restrict__ dst,
                                              int* __restrict__ cnt) {
    const int e = blockIdx.x * 256 + threadIdx.x;
    if (e < N_EDGES) atomicAdd(&cnt[clampi(dst[e], N_NODES)], 1);
}

__global__ __launch_bounds__(256) void k_scan1(const int* __restrict__ cnt,
                                               int* __restrict__ local,
                                               int* __restrict__ partial) {
    __shared__ int tsum[256];
    const int b = blockIdx.x, t = threadIdx.x;
    const int base = b * SCAN_CHUNK + t * 8;
    int v[8];
    int s = 0;
#pragma unroll
    for (int i = 0; i < 8; i++) {
        const int idx = base + i;
        v[i] = (idx < N_NODES) ? cnt[idx] : 0;
        s += v[i];
    }
    tsum[t] = s;
    __syncthreads();
    for (int ofs = 1; ofs < 256; ofs <<= 1) {
        const int add = (t >= ofs) ? tsum[t - ofs] : 0;
        __syncthreads();
        tsum[t] += add;
        __syncthreads();
    }
    int excl = (t == 0) ? 0 : tsum[t - 1];
    if (t == 255) partial[b] = tsum[255];
#pragma unroll
    for (int i = 0; i < 8; i++) {
        const int idx = base + i;
        if (idx < N_NODES) local[idx] = excl;
        excl += v[i];
    }
}

__global__ __launch_bounds__(256) void k_scan2(int* __restrict__ partial) {
    __shared__ int s[256];
    const int t = threadIdx.x;
    s[t] = (t < SCAN_NBLK) ? partial[t] : 0;
    __syncthreads();
    for (int ofs = 1; ofs < 256; ofs <<= 1) {
        const int add = (t >= ofs) ? s[t - ofs] : 0;
        __syncthreads();
        s[t] += add;
        __syncthreads();
    }
    if (t < SCAN_NBLK) partial[t] = (t == 0) ? 0 : s[t - 1];
}

__global__ __launch_bounds__(256) void k_scan3(const int* __restrict__ local,
                                               const int* __restrict__ partial,
                                               int* __restrict__ row_ptr,
                                               int* __restrict__ cursor) {
    const int idx = blockIdx.x * 256 + threadIdx.x;
    if (idx <= N_NODES) {
        const int v = (idx == N_NODES) ? N_EDGES
                                       : local[idx] + partial[idx / SCAN_CHUNK];
        row_ptr[idx] = v;
        if (idx < N_NODES) cursor[idx] = v;
    }
}

__global__ __launch_bounds__(256) void k_place(const int* __restrict__ dst,
                                               int* __restrict__ cursor,
                                               int* __restrict__ eidx) {
    const int e = blockIdx.x * 256 + threadIdx.x;
    if (e < N_EDGES) {
        const int slot = atomicAdd(&cursor[clampi(dst[e], N_NODES)], 1);
        eidx[slot] = e;
    }
}

// ---------------------------------------------------------------------------
// K2 (CSR gather): node_sum[n] = sum_{e in csr[n]} h[e]  (fp8 in, fp32 acc,
// bf16 out). 16 threads per node, 8 channels each (uint2 loads).
// ---------------------------------------------------------------------------
__global__ __launch_bounds__(256) void k_gather(const u8* __restrict__ h,
                                                const int* __restrict__ row_ptr,
                                                const int* __restrict__ eidx,
                                                u16* __restrict__ node_sum) {
    const long long idx = (long long)blockIdx.x * 256 + threadIdx.x;
    const int n = (int)(idx >> 4);
    if (n >= N_NODES) return;
    const int c8 = (int)(idx & 15) << 3;
    const int beg = row_ptr[n], end = row_ptr[n + 1];
    float a0 = 0.f, a1 = 0.f, a2 = 0.f, a3 = 0.f;
    float a4 = 0.f, a5 = 0.f, a6 = 0.f, a7 = 0.f;
    for (int j = beg; j < end; j++) {
        const int e = eidx[j];
        const uint2 v = *reinterpret_cast<const uint2*>(h + (long long)e * HID + c8);
        a0 += FP8_DEC(v.x, 0); a1 += FP8_DEC(v.x, 1);
        a2 += FP8_DEC(v.x, 2); a3 += FP8_DEC(v.x, 3);
        a4 += FP8_DEC(v.y, 0); a5 += FP8_DEC(v.y, 1);
        a6 += FP8_DEC(v.y, 2); a7 += FP8_DEC(v.y, 3);
    }
    ushort4 o1, o2;
    o1.x = f2bu(a0); o1.y = f2bu(a1); o1.z = f2bu(a2); o1.w = f2bu(a3);
    o2.x = f2bu(a4); o2.y = f2bu(a5); o2.z = f2bu(a6); o2.w = f2bu(a7);
    *reinterpret_cast<ushort4*>(node_sum + (long long)n * HID + c8) = o1;
    *reinterpret_cast<ushort4*>(node_sum + (long long)n * HID + c8 + 4) = o2;
}

// ---------------------------------------------------------------------------
// MFMA geometry (64x128 tile, 4 waves: 2 in M x 2 in N)
// a-frag: lane holds A[lane&15][(lane>>4)*8 + i]; b-frag: B[(lane>>4)*8+i][lane&15]
// with B[k][n] = WT[n][k].  C/D: col = lane&15, row = (lane>>4)*4 + reg.
// ---------------------------------------------------------------------------

// K1a: xw[n] = x[n] @ W1x  (per-NODE GEMM; A cols 133..159 zeroed)
__global__ __launch_bounds__(256) void k_xw(const float* __restrict__ x,
                                            const u16* __restrict__ WT1,
                                            u16* __restrict__ xw) {
    __shared__ u16 A[MT * K1_STRIDE];
    const int n0 = blockIdx.x * MT;
    const int t = threadIdx.x;
    const int lane = t & 63, wv = t >> 6;
    for (int rr = 0; rr < 16; rr++) {
        const int row = wv * 16 + rr;
        const int n = n0 + row;
        const float* xr = x + (size_t)n * NODE_IN;
        u16* dstr = &A[row * K1_STRIDE];
        dstr[lane] = f2bu(xr[lane]);                 // k 0..63
        dstr[64 + lane] = f2bu(xr[64 + lane]);       // k 64..127
        if (lane < 5) dstr[128 + lane] = f2bu(xr[128 + lane]);  // 128..132
        if (lane < K1_PAD - NODE_IN) dstr[NODE_IN + lane] = 0;  // 133..159
    }
    __syncthreads();

    const int wm = wv & 1, wn = wv >> 1;
    const int lr = lane & 15, lk = (lane >> 4) * 8;
    f32x4 acc[2][4];
#pragma unroll
    for (int m = 0; m < 2; m++)
#pragma unroll
        for (int n = 0; n < 4; n++) acc[m][n] = (f32x4){0.f, 0.f, 0.f, 0.f};

    const int ar0 = (wm * 32 + lr) * K1_STRIDE + lk;
#pragma unroll
    for (int ks = 0; ks < K1_PAD / 32; ks++) {
        const int kk = ks * 32;
        const bf16x8 a0 = *(const bf16x8*)&A[ar0 + kk];
        const bf16x8 a1 = *(const bf16x8*)&A[ar0 + 16 * K1_STRIDE + kk];
#pragma unroll
        for (int n = 0; n < 4; n++) {
            const bf16x8 b = *(const bf16x8*)&WT1[(size_t)(wn * 64 + n * 16 + lr) * K1_STRIDE + kk + lk];
            acc[0][n] = __builtin_amdgcn_mfma_f32_16x16x32_bf16(a0, b, acc[0][n], 0, 0, 0);
            acc[1][n] = __builtin_amdgcn_mfma_f32_16x16x32_bf16(a1, b, acc[1][n], 0, 0, 0);
        }
    }

    const int lr4 = lane >> 4;
#pragma unroll
    for (int n = 0; n < 4; n++) {
        const int col = wn * 64 + n * 16 + lr;
#pragma unroll
        for (int m = 0; m < 2; m++)
#pragma unroll
            for (int j = 0; j < 4; j++) {
                const int nd = n0 + wm * 32 + m * 16 + lr4 * 4 + j;
                xw[(size_t)nd * HID + col] = f2bu(acc[m][n][j]);
            }
    }
}

// K1b: h0[e] = relu(xw[src[e]] + ea[e]@W1e + b1) -> fp8.
// 16 edges/block, 32 lanes/edge, 4 ch/lane, 2 edges per thread (ILP).
__global__ __launch_bounds__(256) void k_init2(const u16* __restrict__ xw,
                                               const float* __restrict__ ea,
                                               const float* __restrict__ W1,
                                               const float* __restrict__ b1,
                                               const int* __restrict__ src,
                                               u8* __restrict__ h0) {
    __shared__ float w1e[EDGE_IN * HID];  // 7 KB
    __shared__ float b1s[HID];
    const int t = threadIdx.x;
    for (int i = t; i < EDGE_IN * HID; i += 256)
        w1e[i] = W1[(NODE_IN + i / HID) * HID + (i % HID)];
    if (t < HID) b1s[t] = b1[t];
    __syncthreads();

    const int g = t >> 5;                 // 0..7
    const int c4 = (t & 31) << 2;
    const int e1 = blockIdx.x * 16 + g;
    const int e2 = e1 + 8;
    const int s1 = clampi(src[e1], N_NODES);
    const int s2 = clampi(src[e2], N_NODES);
    const ushort4 xv1 = *(const ushort4*)(xw + (size_t)s1 * HID + c4);
    const ushort4 xv2 = *(const ushort4*)(xw + (size_t)s2 * HID + c4);
    const float4 bb = *(const float4*)&b1s[c4];
    float a0 = bu2f(xv1.x) + bb.x, a1 = bu2f(xv1.y) + bb.y;
    float a2 = bu2f(xv1.z) + bb.z, a3 = bu2f(xv1.w) + bb.w;
    float d0 = bu2f(xv2.x) + bb.x, d1 = bu2f(xv2.y) + bb.y;
    float d2 = bu2f(xv2.z) + bb.z, d3 = bu2f(xv2.w) + bb.w;
    // preload ea rows as float2 (56B rows are 8B-aligned)
    const float2* er1 = (const float2*)(ea + (size_t)e1 * EDGE_IN);
    const float2* er2 = (const float2*)(ea + (size_t)e2 * EDGE_IN);
    float ev1[EDGE_IN], ev2[EDGE_IN];
#pragma unroll
    for (int k = 0; k < EDGE_IN / 2; k++) {
        const float2 u1 = er1[k], u2 = er2[k];
        ev1[2 * k] = u1.x; ev1[2 * k + 1] = u1.y;
        ev2[2 * k] = u2.x; ev2[2 * k + 1] = u2.y;
    }
#pragma unroll
    for (int k = 0; k < EDGE_IN; k++) {
        const float4 w = *(const float4*)&w1e[k * HID + c4];
        a0 = fmaf(ev1[k], w.x, a0); a1 = fmaf(ev1[k], w.y, a1);
        a2 = fmaf(ev1[k], w.z, a2); a3 = fmaf(ev1[k], w.w, a3);
        d0 = fmaf(ev2[k], w.x, d0); d1 = fmaf(ev2[k], w.y, d1);
        d2 = fmaf(ev2[k], w.z, d2); d3 = fmaf(ev2[k], w.w, d3);
    }
    const unsigned p1 = fp8_pk(a0, a1) | (fp8_pk(a2, a3) << 16);
    const unsigned p2 = fp8_pk(d0, d1) | (fp8_pk(d2, d3) << 16);
    *(unsigned*)(h0 + (size_t)e1 * HID + c4) = p1;
    *(unsigned*)(h0 + (size_t)e2 * HID + c4) = p2;
}

// K3: hn = relu(h0 + (node_sum[src] - h[rev]) @ W2 + b2)  (fp8 states)
// Epilogue: acc staged to LDS as bf16, then coalesced uint2 RMW phase.
__global__ __launch_bounds__(256) void k_msg_mfma(const u16* __restrict__ ns,
                                                  const u8* __restrict__ h,
                                                  const u8* __restrict__ h0g,
                                                  const u16* __restrict__ WT2,
                                                  const float* __restrict__ b2,
                                                  const int* __restrict__ src,
                                                  const int* __restrict__ rev,
                                                  u8* __restrict__ hn) {
    __shared__ u16 A[MT * K2_STRIDE];
    __shared__ float b2s[HID];
    const int e0 = blockIdx.x * MT;
    const int t = threadIdx.x;
    if (t < HID) b2s[t] = b2[t];
    {   // builder: 4 threads/row, 32 channels each (vector loads; random rows)
        const int le = t >> 2, j = t & 3;
        const int e = e0 + le;
        const int s = clampi(src[e], N_NODES);
        const int r = clampi(rev[e], N_EDGES);
        const u16* nsr = ns + (size_t)s * HID + j * 32;
        const u8* hr = h + (size_t)r * HID + j * 32;
        u16* dstr = &A[le * K2_STRIDE + j * 32];
#pragma unroll
        for (int q = 0; q < 4; q++) {
            const uint4 nv = *(const uint4*)(nsr + q * 8);  // 8 bf16
            const uint2 hv = *(const uint2*)(hr + q * 8);   // 8 fp8
            union { bf16x8 v; u16 s[8]; } o;
            o.s[0] = f2bu(bu2f(nv.x & 0xFFFFu) - FP8_DEC(hv.x, 0));
            o.s[1] = f2bu(bu2f(nv.x >> 16)     - FP8_DEC(hv.x, 1));
            o.s[2] = f2bu(bu2f(nv.y & 0xFFFFu) - FP8_DEC(hv.x, 2));
            o.s[3] = f2bu(bu2f(nv.y >> 16)     - FP8_DEC(hv.x, 3));
            o.s[4] = f2bu(bu2f(nv.z & 0xFFFFu) - FP8_DEC(hv.y, 0));
            o.s[5] = f2bu(bu2f(nv.z >> 16)     - FP8_DEC(hv.y, 1));
            o.s[6] = f2bu(bu2f(nv.w & 0xFFFFu) - FP8_DEC(hv.y, 2));
            o.s[7] = f2bu(bu2f(nv.w >> 16)     - FP8_DEC(hv.y, 3));
            *(bf16x8*)(dstr + q * 8) = o.v;
        }
    }
    __syncthreads();

    const int lane = t & 63, wid = t >> 6;
    const int wm = wid & 1, wn = wid >> 1;
    const int lr = lane & 15, lk = (lane >> 4) * 8;
    f32x4 acc[2][4];
#pragma unroll
    for (int m = 0; m < 2; m++)
#pragma unroll
        for (int n = 0; n < 4; n++) acc[m][n] = (f32x4){0.f, 0.f, 0.f, 0.f};

    const int ar0 = (wm * 32 + lr) * K2_STRIDE + lk;
#pragma unroll
    for (int ks = 0; ks < K2_PAD / 32; ks++) {
        const int kk = ks * 32;
        const bf16x8 a0 = *(const bf16x8*)&A[ar0 + kk];
        const bf16x8 a1 = *(const bf16x8*)&A[ar0 + 16 * K2_STRIDE + kk];
#pragma unroll
        for (int n = 0; n < 4; n++) {
            const bf16x8 b = *(const bf16x8*)&WT2[(size_t)(wn * 64 + n * 16 + lr) * K2_STRIDE + kk + lk];
            acc[0][n] = __builtin_amdgcn_mfma_f32_16x16x32_bf16(a0, b, acc[0][n], 0, 0, 0);
            acc[1][n] = __builtin_amdgcn_mfma_f32_16x16x32_bf16(a1, b, acc[1][n], 0, 0, 0);
        }
    }

    __syncthreads();  // A's builder data fully consumed; safe to overwrite
    // stage product (bf16) into A at [row][col], stride K2_STRIDE
    const int lr4 = lane >> 4;
#pragma unroll
    for (int n = 0; n < 4; n++) {
        const int col = wn * 64 + n * 16 + lr;
#pragma unroll
        for (int m = 0; m < 2; m++)
#pragma unroll
            for (int j = 0; j < 4; j++) {
                const int row = wm * 32 + m * 16 + lr4 * 4 + j;
                A[row * K2_STRIDE + col] = f2bu(acc[m][n][j]);
            }
    }
    __syncthreads();

    // phase 2: coalesced RMW, thread = (row, 32-ch chunk), uint2 (8 fp8) IO
    const int prow = t >> 2, pj = t & 3;
    const long long e = e0 + prow;
#pragma unroll
    for (int q = 0; q < 4; q++) {
        const int c8 = pj * 32 + q * 8;
        const uint4 sv = *(const uint4*)&A[prow * K2_STRIDE + c8];  // 8 bf16
        const uint2 hv = *(const uint2*)(h0g + e * HID + c8);       // 8 fp8
        const float4 ba = *(const float4*)&b2s[c8];
        const float4 bbv = *(const float4*)&b2s[c8 + 4];
        const float v0 = bu2f(sv.x & 0xFFFFu) + FP8_DEC(hv.x, 0) + ba.x;
        const float v1 = bu2f(sv.x >> 16)     + FP8_DEC(hv.x, 1) + ba.y;
        const float v2 = bu2f(sv.y & 0xFFFFu) + FP8_DEC(hv.x, 2) + ba.z;
        const float v3 = bu2f(sv.y >> 16)     + FP8_DEC(hv.x, 3) + ba.w;
        const float v4 = bu2f(sv.z & 0xFFFFu) + FP8_DEC(hv.y, 0) + bbv.x;
        const float v5 = bu2f(sv.z >> 16)     + FP8_DEC(hv.y, 1) + bbv.y;
        const float v6 = bu2f(sv.w & 0xFFFFu) + FP8_DEC(hv.y, 2) + bbv.z;
        const float v7 = bu2f(sv.w >> 16)     + FP8_DEC(hv.y, 3) + bbv.w;
        uint2 o;
        o.x = fp8_pk(v0, v1) | (fp8_pk(v2, v3) << 16);
        o.y = fp8_pk(v4, v5) | (fp8_pk(v6, v7) << 16);
        *(uint2*)(hn + e * HID + c8) = o;
    }
}

// K5: node_attr[n] = relu(concat(x[n], vmsg[n]) @ W3 + b3)  (fp32 out)
__global__ __launch_bounds__(256) void k_node_mfma(const float* __restrict__ x,
                                                   const u16* __restrict__ vmsg,
                                                   const u16* __restrict__ WT3,
                                                   const float* __restrict__ b3,
                                                   float* __restrict__ node_attr) {
    __shared__ u16 A[MT * K3_STRIDE];
    const int n0 = blockIdx.x * MT;
    const int t = threadIdx.x;
    const int lane = t & 63, wv = t >> 6;
    {   // coalesced builder: wave wv handles rows wv*16 .. wv*16+15
        for (int rr = 0; rr < 16; rr++) {
            const int row = wv * 16 + rr;
            const int n = n0 + row;
            const float* xr = x + (size_t)n * NODE_IN;
            const unsigned* vr = (const unsigned*)(vmsg + (size_t)n * HID);
            u16* dstr = &A[row * K3_STRIDE];
            dstr[lane] = f2bu(xr[lane]);                 // k 0..63
            dstr[64 + lane] = f2bu(xr[64 + lane]);       // k 64..127
            if (lane < 5) dstr[128 + lane] = f2bu(xr[128 + lane]);  // 128..132
            const unsigned v = vr[lane];                 // 2 bf16
            dstr[NODE_IN + 2 * lane] = (u16)(v & 0xFFFFu);
            dstr[NODE_IN + 2 * lane + 1] = (u16)(v >> 16);
            if (lane < K3_PAD - (NODE_IN + HID))         // 261..287
                dstr[NODE_IN + HID + lane] = 0;
        }
    }
    __syncthreads();

    const int wm = wv & 1, wn = wv >> 1;
    const int lr = lane & 15, lk = (lane >> 4) * 8;
    f32x4 acc[2][4];
#pragma unroll
    for (int m = 0; m < 2; m++)
#pragma unroll
        for (int n = 0; n < 4; n++) acc[m][n] = (f32x4){0.f, 0.f, 0.f, 0.f};

    const int ar0 = (wm * 32 + lr) * K3_STRIDE + lk;
#pragma unroll
    for (int ks = 0; ks < K3_PAD / 32; ks++) {
        const int kk = ks * 32;
        const bf16x8 a0 = *(const bf16x8*)&A[ar0 + kk];
        const bf16x8 a1 = *(const bf16x8*)&A[ar0 + 16 * K3_STRIDE + kk];
#pragma unroll
        for (int n = 0; n < 4; n++) {
            const bf16x8 b = *(const bf16x8*)&WT3[(size_t)(wn * 64 + n * 16 + lr) * K3_STRIDE + kk + lk];
            acc[0][n] = __builtin_amdgcn_mfma_f32_16x16x32_bf16(a0, b, acc[0][n], 0, 0, 0);
            acc[1][n] = __builtin_amdgcn_mfma_f32_16x16x32_bf16(a1, b, acc[1][n], 0, 0, 0);
        }
    }

    const int lr4 = lane >> 4;
#pragma unroll
    for (int n = 0; n < 4; n++) {
        const int col = wn * 64 + n * 16 + lr;
        const float bias = b3[col];
#pragma unroll
        for (int m = 0; m < 2; m++)
#pragma unroll
            for (int j = 0; j < 4; j++) {
                const int nd = n0 + wm * 32 + m * 16 + lr4 * 4 + j;
                float v = acc[m][n][j] + bias;
                node_attr[(size_t)nd * HID + col] = v > 0.f ? v : 0.f;
            }
    }
}

// ---------------------------------------------------------------------------
// K6: out[g] = mean over the graph's (sorted, contiguous) node range.
// ---------------------------------------------------------------------------
__global__ __launch_bounds__(128) void k_pool2(const float* __restrict__ node_attr,
                                               const int* __restrict__ batch,
                                               float* __restrict__ out) {
    const int g = blockIdx.x;
    __shared__ int lo_s, hi_s;
    if (threadIdx.x == 0) {
        int lo = 0, hi = N_NODES;
        while (lo < hi) { int mid = (lo + hi) >> 1; if (batch[mid] < g) lo = mid + 1; else hi = mid; }
        lo_s = lo;
        int lo2 = lo, hi2 = N_NODES;
        while (lo2 < hi2) { int mid = (lo2 + hi2) >> 1; if (batch[mid] <= g) lo2 = mid + 1; else hi2 = mid; }
        hi_s = lo2;
    }
    __syncthreads();
    const int lo = lo_s, hi = hi_s;
    float acc = 0.f;
    for (int n = lo; n < hi; n++) acc += node_attr[(size_t)n * HID + threadIdx.x];
    const float cnt = (hi > lo) ? (float)(hi - lo) : 1.f;
    out[(size_t)g * HID + threadIdx.x] = acc / cnt;
}

// ---------------------------------------------------------------------------
extern "C" void kernel_launch(void* const* d_in, const int* in_sizes, int n_in,
                              void* d_out, int out_size, void* d_ws, size_t ws_size,
                              hipStream_t stream) {
    const float* x   = (const float*)d_in[0];
    const float* ea  = (const float*)d_in[1];
    const float* W1  = (const float*)d_in[2];
    const float* b1  = (const float*)d_in[3];
    const float* W2  = (const float*)d_in[4];
    const float* b2  = (const float*)d_in[5];
    const float* W3  = (const float*)d_in[6];
    const float* b3  = (const float*)d_in[7];
    const int*   ei  = (const int*)d_in[8];
    const int*   src = ei;
    const int*   dst = ei + N_EDGES;
    const int*   rev = (const int*)d_in[9];
    const int*   bat = (const int*)d_in[10];

    char* ws = (char*)d_ws;
    size_t off = 0;
    auto alloc = [&](size_t bytes) -> void* {
        void* p = ws + off;
        off += (bytes + 255) & ~(size_t)255;
        return p;
    };
    const size_t hbytes = (size_t)N_EDGES * HID;                 // 102.4 MB fp8
    u8* h0 = (u8*)alloc(hbytes);
    u8* hA = (u8*)alloc(hbytes);
    u8* hB = (u8*)alloc(hbytes);
    u16* node_sum = (u16*)alloc((size_t)N_NODES * HID * sizeof(u16));  // 51.2 MB
    int* row_ptr = (int*)alloc((size_t)(N_NODES + 1) * sizeof(int));
    int* eidx = (int*)alloc((size_t)N_EDGES * sizeof(int));
    u16* WT1 = (u16*)alloc((size_t)HID * K1_STRIDE * sizeof(u16));
    u16* WT2 = (u16*)alloc((size_t)HID * K2_STRIDE * sizeof(u16));
    u16* WT3 = (u16*)alloc((size_t)HID * K3_STRIDE * sizeof(u16));
    // Aliases (footprint unchanged, ~363 MB < proven 415.7 MB floor):
    //  - xw (bf16, 51.2 MB) lives in hA: dead before the first k_msg writes hA.
    //  - node_attr (fp32, 102.4 MB) lives in h0: dead after last k_msg read.
    u16* xw = (u16*)hA;
    float* node_attr = (float*)h0;

    if (ws_size < off) return;  // diagnostic: leave d_out untouched

    // weight transpose+pad to bf16
    k_prep<<<(HID * K1_STRIDE + 255) / 256, 256, 0, stream>>>(W1, WT1, NODE_IN + EDGE_IN, K1_STRIDE);
    k_prep<<<(HID * K2_STRIDE + 255) / 256, 256, 0, stream>>>(W2, WT2, HID, K2_STRIDE);
    k_prep<<<(HID * K3_STRIDE + 255) / 256, 256, 0, stream>>>(W3, WT3, NODE_IN + HID, K3_STRIDE);

    // CSR build (transients overlay node_sum, not live yet; 9.6 MB < 51.2 MB)
    {
        int* cnt = (int*)node_sum;
        int* local = cnt + N_NODES;
        int* cursor = local + N_NODES;
        int* partial = cursor + N_NODES;
        hipMemsetAsync(cnt, 0, (size_t)N_NODES * sizeof(int), stream);
        k_hist<<<(N_EDGES + 255) / 256, 256, 0, stream>>>(dst, cnt);
        k_scan1<<<SCAN_NBLK, 256, 0, stream>>>(cnt, local, partial);
        k_scan2<<<1, 256, 0, stream>>>(partial);
        k_scan3<<<(N_NODES + 256) / 256, 256, 0, stream>>>(local, partial, row_ptr, cursor);
        k_place<<<(N_EDGES + 255) / 256, 256, 0, stream>>>(dst, cursor, eidx);
    }

    // h0 = relu(x[src]@W1x + ea@W1e + b1), split per-node GEMM + fused epilogue
    k_xw<<<N_NODES / MT, 256, 0, stream>>>(x, WT1, xw);
    k_init2<<<N_EDGES / 16, 256, 0, stream>>>(xw, ea, W1, b1, src, h0);

    const u8* h = h0;
    u8* bufs[2] = {hA, hB};
    const int agg_blocks = (int)(((long long)N_NODES * 16 + 255) / 256);
    for (int it = 0; it < 3; it++) {
        k_gather<<<agg_blocks, 256, 0, stream>>>(h, row_ptr, eidx, node_sum);
        u8* hn = bufs[it & 1];   // it=0 writes hA (xw already consumed)
        k_msg_mfma<<<N_EDGES / MT, 256, 0, stream>>>(node_sum, h, h0, WT2, b2, src, rev, hn);
        h = hn;
    }
    k_gather<<<agg_blocks, 256, 0, stream>>>(h, row_ptr, eidx, node_sum);

    // h0 is dead from here; node_attr reuses its storage.
    k_node_mfma<<<N_NODES / MT, 256, 0, stream>>>(x, node_sum, WT3, b3, node_attr);
    k_pool2<<<NUM_GRAPHS, 128, 0, stream>>>(node_attr, bat, (float*)d_out);
}

// Round 12
// 1039.287 us; speedup vs baseline: 1.6629x; 1.0216x over previous
//
#include <hip/hip_runtime.h>

#define N_NODES 200000
#define N_EDGES 800000
#define NODE_IN 133
#define EDGE_IN 14
#define HID 128
#define NUM_GRAPHS 4096

#define SCAN_CHUNK 2048
#define SCAN_NBLK ((N_NODES + SCAN_CHUNK - 1) / SCAN_CHUNK)  // 98

#define MT 64  // M tile rows per block for MFMA GEMMs

// K geometry per GEMM (padded K, LDS/WT row stride in elements)
#define K1_PAD 160
#define K1_STRIDE 168
#define K2_PAD 128
#define K2_STRIDE 136
#define K3_PAD 288
#define K3_STRIDE 296

typedef unsigned short u16;
typedef unsigned char u8;
typedef short bf16x8 __attribute__((ext_vector_type(8)));
typedef float f32x4 __attribute__((ext_vector_type(4)));

__device__ __forceinline__ float bu2f(unsigned s) {
    return __uint_as_float(s << 16);
}
__device__ __forceinline__ u16 f2bu(float f) {
    unsigned u = __float_as_uint(f);
    return (u16)((u + 0x7FFFu + ((u >> 16) & 1u)) >> 16);  // RNE
}
// ---------------- fp8 e4m3 (OCP), non-negative post-ReLU values -----------
__device__ __forceinline__ float e42f(unsigned b) {
    unsigned E = (b >> 4) & 0xF, M = b & 7u;
    if (E == 0) return (float)M * 0.001953125f;  // M * 2^-9
    return __uint_as_float(((E - 7u + 127u) << 23) | (M << 20));
}
__device__ __forceinline__ u8 f2e4(float f) {
    if (!(f > 0.f)) return 0;
    if (f >= 448.f) return 0x7E;
    unsigned u = __float_as_uint(f);
    int e = (int)((u >> 23) & 0xFF) - 127;
    if (e < -6) {
        int q = (int)rintf(f * 512.f);
        return (u8)q;
    }
    unsigned m = u & 0x7FFFFF;
    unsigned keep = m >> 20, rem = m & 0xFFFFF;
    keep += (rem > 0x80000u || (rem == 0x80000u && (keep & 1u))) ? 1u : 0u;
    unsigned E = (unsigned)(e + 7);
    if (keep == 8u) { keep = 0u; E++; }
    return (u8)((E << 4) | keep);
}

// ---------------- HW fp8 convert (gfx950 OCP) with software fallback -------
#if defined(__has_builtin)
#if __has_builtin(__builtin_amdgcn_cvt_f32_fp8) && __has_builtin(__builtin_amdgcn_cvt_pk_fp8_f32)
#define HW_FP8 1
#endif
#endif

#if defined(HW_FP8)
// sel must be a compile-time constant
#define FP8_DEC(dw, s) __builtin_amdgcn_cvt_f32_fp8((int)(dw), (s))
__device__ __forceinline__ unsigned fp8_pk(float a, float b) {
    a = fminf(fmaxf(a, 0.f), 448.f);  // ReLU + sat (matches sw path)
    b = fminf(fmaxf(b, 0.f), 448.f);
    return (unsigned)__builtin_amdgcn_cvt_pk_fp8_f32(a, b, 0, false) & 0xFFFFu;
}
#else
#define FP8_DEC(dw, s) e42f(((dw) >> (8 * (s))) & 0xFFu)
__device__ __forceinline__ unsigned fp8_pk(float a, float b) {
    return (unsigned)f2e4(a) | ((unsigned)f2e4(b) << 8);
}
#endif

__device__ __forceinline__ int clampi(int v, int hi) {
    return v < 0 ? 0 : (v >= hi ? hi - 1 : v);
}

// ---------------------------------------------------------------------------
// Weight prep: WT[n][k] = bf16(W[k][n]), k < K else 0.
// ---------------------------------------------------------------------------
__global__ __launch_bounds__(256) void k_prep(const float* __restrict__ W,
                                              u16* __restrict__ WT, int K,
                                              int stride) {
    const int idx = blockIdx.x * 256 + threadIdx.x;
    if (idx >= HID * stride) return;
    const int n = idx / stride, k = idx % stride;
    WT[idx] = (k < K) ? f2bu(W[k * HID + n]) : (u16)0;
}

// ---------------------------------------------------------------------------
// CSR build: histogram -> exclusive scan -> atomic-cursor placement.
// The whole edge state space is then RELABELED into dst-sorted order:
// sorted position j <-> original edge eidx[j].
// ---------------------------------------------------------------------------
__global__ __launch_bounds__(256) void k_hist(const int* __restrict__ dst,
                                              int* __restrict__ cnt) {
    const int e = blockIdx.x * 256 + threadIdx.x;
    if (e < N_EDGES) atomicAdd(&cnt[clampi(dst[e], N_NODES)], 1);
}

__global__ __launch_bounds__(256) void k_scan1(const int* __restrict__ cnt,
                                               int* __restrict__ local,
                                               int* __restrict__ partial) {
    __shared__ int tsum[256];
    const int b = blockIdx.x, t = threadIdx.x;
    const int base = b * SCAN_CHUNK + t * 8;
    int v[8];
    int s = 0;
#pragma unroll
    for (int i = 0; i < 8; i++) {
        const int idx = base + i;
        v[i] = (idx < N_NODES) ? cnt[idx] : 0;
        s += v[i];
    }
    tsum[t] = s;
    __syncthreads();
    for (int ofs = 1; ofs < 256; ofs <<= 1) {
        const int add = (t >= ofs) ? tsum[t - ofs] : 0;
        __syncthreads();
        tsum[t] += add;
        __syncthreads();
    }
    int excl = (t == 0) ? 0 : tsum[t - 1];
    if (t == 255) partial[b] = tsum[255];
#pragma unroll
    for (int i = 0; i < 8; i++) {
        const int idx = base + i;
        if (idx < N_NODES) local[idx] = excl;
        excl += v[i];
    }
}

__global__ __launch_bounds__(256) void k_scan2(int* __restrict__ partial) {
    __shared__ int s[256];
    const int t = threadIdx.x;
    s[t] = (t < SCAN_NBLK) ? partial[t] : 0;
    __syncthreads();
    for (int ofs = 1; ofs < 256; ofs <<= 1) {
        const int add = (t >= ofs) ? s[t - ofs] : 0;
        __syncthreads();
        s[t] += add;
        __syncthreads();
    }
    if (t < SCAN_NBLK) partial[t] = (t == 0) ? 0 : s[t - 1];
}

__global__ __launch_bounds__(256) void k_scan3(const int* __restrict__ local,
                                               const int* __restrict__ partial,
                                               int* __restrict__ row_ptr,
                                               int* __restrict__ cursor) {
    const int idx = blockIdx.x * 256 + threadIdx.x;
    if (idx <= N_NODES) {
        const int v = (idx == N_NODES) ? N_EDGES
                                       : local[idx] + partial[idx / SCAN_CHUNK];
        row_ptr[idx] = v;
        if (idx < N_NODES) cursor[idx] = v;
    }
}

__global__ __launch_bounds__(256) void k_place(const int* __restrict__ dst,
                                               int* __restrict__ cursor,
                                               int* __restrict__ eidx) {
    const int e = blockIdx.x * 256 + threadIdx.x;
    if (e < N_EDGES) {
        const int slot = atomicAdd(&cursor[clampi(dst[e], N_NODES)], 1);
        eidx[slot] = e;
    }
}

// inv[eidx[j]] = j  (eidx is a permutation -> inv fully written)
__global__ __launch_bounds__(256) void k_inv(const int* __restrict__ eidx,
                                             int* __restrict__ inv) {
    const int j = blockIdx.x * 256 + threadIdx.x;
    if (j < N_EDGES) inv[clampi(eidx[j], N_EDGES)] = j;
}

// src_d[j] = src[eidx[j]];  rev_d[j] = inv[rev[eidx[j]]]  (sorted space)
__global__ __launch_bounds__(256) void k_remap(const int* __restrict__ eidx,
                                               const int* __restrict__ src,
                                               const int* __restrict__ rev,
                                               const int* __restrict__ inv,
                                               int* __restrict__ src_d,
                                               int* __restrict__ rev_d) {
    const int j = blockIdx.x * 256 + threadIdx.x;
    if (j < N_EDGES) {
        const int e = clampi(eidx[j], N_EDGES);
        src_d[j] = src[e];
        rev_d[j] = inv[clampi(rev[e], N_EDGES)];
    }
}

// ea_d[j] = bf16-packed ea[eidx[j]] (16 u16 = 32 B rows; last 2 zero)
__global__ __launch_bounds__(256) void k_ea(const int* __restrict__ eidx,
                                            const float* __restrict__ ea,
                                            u16* __restrict__ ea_d) {
    const int j = blockIdx.x * 256 + threadIdx.x;
    if (j >= N_EDGES) return;
    const int e = clampi(eidx[j], N_EDGES);
    const float2* er = (const float2*)(ea + (size_t)e * EDGE_IN);
    u16 v[16];
#pragma unroll
    for (int k = 0; k < 7; k++) {
        const float2 u = er[k];
        v[2 * k] = f2bu(u.x);
        v[2 * k + 1] = f2bu(u.y);
    }
    v[14] = 0; v[15] = 0;
    uint4 o1, o2;
    o1.x = (unsigned)v[0] | ((unsigned)v[1] << 16);
    o1.y = (unsigned)v[2] | ((unsigned)v[3] << 16);
    o1.z = (unsigned)v[4] | ((unsigned)v[5] << 16);
    o1.w = (unsigned)v[6] | ((unsigned)v[7] << 16);
    o2.x = (unsigned)v[8] | ((unsigned)v[9] << 16);
    o2.y = (unsigned)v[10] | ((unsigned)v[11] << 16);
    o2.z = (unsigned)v[12] | ((unsigned)v[13] << 16);
    o2.w = 0;
    uint4* dstp = (uint4*)(ea_d + (size_t)j * 16);
    dstp[0] = o1;
    dstp[1] = o2;
}

// ---------------------------------------------------------------------------
// K2 (streaming gather): node_sum[n] = sum_{j in [row_ptr[n],row_ptr[n+1])}
// h[j] — NO indirection; h rows are dst-sorted. 16 threads/node, 8 ch each.
// ---------------------------------------------------------------------------
__global__ __launch_bounds__(256) void k_gather(const u8* __restrict__ h,
                                                const int* __restrict__ row_ptr,
                                                u16* __restrict__ node_sum) {
    const long long idx = (long long)blockIdx.x * 256 + threadIdx.x;
    const int n = (int)(idx >> 4);
    if (n >= N_NODES) return;
    const int c8 = (int)(idx & 15) << 3;
    const int beg = row_ptr[n], end = row_ptr[n + 1];
    float a0 = 0.f, a1 = 0.f, a2 = 0.f, a3 = 0.f;
    float a4 = 0.f, a5 = 0.f, a6 = 0.f, a7 = 0.f;
    for (int j = beg; j < end; j++) {
        const uint2 v = *reinterpret_cast<const uint2*>(h + (long long)j * HID + c8);
        a0 += FP8_DEC(v.x, 0); a1 += FP8_DEC(v.x, 1);
        a2 += FP8_DEC(v.x, 2); a3 += FP8_DEC(v.x, 3);
        a4 += FP8_DEC(v.y, 0); a5 += FP8_DEC(v.y, 1);
        a6 += FP8_DEC(v.y, 2); a7 += FP8_DEC(v.y, 3);
    }
    ushort4 o1, o2;
    o1.x = f2bu(a0); o1.y = f2bu(a1); o1.z = f2bu(a2); o1.w = f2bu(a3);
    o2.x = f2bu(a4); o2.y = f2bu(a5); o2.z = f2bu(a6); o2.w = f2bu(a7);
    *reinterpret_cast<ushort4*>(node_sum + (long long)n * HID + c8) = o1;
    *reinterpret_cast<ushort4*>(node_sum + (long long)n * HID + c8 + 4) = o2;
}

// ---------------------------------------------------------------------------
// MFMA geometry (64x128 tile, 4 waves: 2 in M x 2 in N)
// a-frag: lane holds A[lane&15][(lane>>4)*8 + i]; b-frag: B[(lane>>4)*8+i][lane&15]
// with B[k][n] = WT[n][k].  C/D: col = lane&15, row = (lane>>4)*4 + reg.
// ---------------------------------------------------------------------------

// K1a: xw[n] = x[n] @ W1x  (per-NODE GEMM; A cols 133..159 zeroed)
__global__ __launch_bounds__(256) void k_xw(const float* __restrict__ x,
                                            const u16* __restrict__ WT1,
                                            u16* __restrict__ xw) {
    __shared__ u16 A[MT * K1_STRIDE];
    const int n0 = blockIdx.x * MT;
    const int t = threadIdx.x;
    const int lane = t & 63, wv = t >> 6;
    for (int rr = 0; rr < 16; rr++) {
        const int row = wv * 16 + rr;
        const int n = n0 + row;
        const float* xr = x + (size_t)n * NODE_IN;
        u16* dstr = &A[row * K1_STRIDE];
        dstr[lane] = f2bu(xr[lane]);                 // k 0..63
        dstr[64 + lane] = f2bu(xr[64 + lane]);       // k 64..127
        if (lane < 5) dstr[128 + lane] = f2bu(xr[128 + lane]);  // 128..132
        if (lane < K1_PAD - NODE_IN) dstr[NODE_IN + lane] = 0;  // 133..159
    }
    __syncthreads();

    const int wm = wv & 1, wn = wv >> 1;
    const int lr = lane & 15, lk = (lane >> 4) * 8;
    f32x4 acc[2][4];
#pragma unroll
    for (int m = 0; m < 2; m++)
#pragma unroll
        for (int n = 0; n < 4; n++) acc[m][n] = (f32x4){0.f, 0.f, 0.f, 0.f};

    const int ar0 = (wm * 32 + lr) * K1_STRIDE + lk;
#pragma unroll
    for (int ks = 0; ks < K1_PAD / 32; ks++) {
        const int kk = ks * 32;
        const bf16x8 a0 = *(const bf16x8*)&A[ar0 + kk];
        const bf16x8 a1 = *(const bf16x8*)&A[ar0 + 16 * K1_STRIDE + kk];
#pragma unroll
        for (int n = 0; n < 4; n++) {
            const bf16x8 b = *(const bf16x8*)&WT1[(size_t)(wn * 64 + n * 16 + lr) * K1_STRIDE + kk + lk];
            acc[0][n] = __builtin_amdgcn_mfma_f32_16x16x32_bf16(a0, b, acc[0][n], 0, 0, 0);
            acc[1][n] = __builtin_amdgcn_mfma_f32_16x16x32_bf16(a1, b, acc[1][n], 0, 0, 0);
        }
    }

    const int lr4 = lane >> 4;
#pragma unroll
    for (int n = 0; n < 4; n++) {
        const int col = wn * 64 + n * 16 + lr;
#pragma unroll
        for (int m = 0; m < 2; m++)
#pragma unroll
            for (int j = 0; j < 4; j++) {
                const int nd = n0 + wm * 32 + m * 16 + lr4 * 4 + j;
                xw[(size_t)nd * HID + col] = f2bu(acc[m][n][j]);
            }
    }
}

// K1b: h0[j] = relu(xw[src_d[j]] + ea_d[j]@W1e + b1) -> fp8 (sorted space).
// 16 edges/block, 32 lanes/edge, 4 ch/lane, 2 edges per thread (ILP).
__global__ __launch_bounds__(256) void k_init2(const u16* __restrict__ xw,
                                               const u16* __restrict__ ea_d,
                                               const float* __restrict__ W1,
                                               const float* __restrict__ b1,
                                               const int* __restrict__ src_d,
                                               u8* __restrict__ h0) {
    __shared__ float w1e[EDGE_IN * HID];  // 7 KB
    __shared__ float b1s[HID];
    const int t = threadIdx.x;
    for (int i = t; i < EDGE_IN * HID; i += 256)
        w1e[i] = W1[(NODE_IN + i / HID) * HID + (i % HID)];
    if (t < HID) b1s[t] = b1[t];
    __syncthreads();

    const int g = t >> 5;                 // 0..7
    const int c4 = (t & 31) << 2;
    const int e1 = blockIdx.x * 16 + g;
    const int e2 = e1 + 8;
    const int s1 = clampi(src_d[e1], N_NODES);
    const int s2 = clampi(src_d[e2], N_NODES);
    const ushort4 xv1 = *(const ushort4*)(xw + (size_t)s1 * HID + c4);
    const ushort4 xv2 = *(const ushort4*)(xw + (size_t)s2 * HID + c4);
    const float4 bb = *(const float4*)&b1s[c4];
    float a0 = bu2f(xv1.x) + bb.x, a1 = bu2f(xv1.y) + bb.y;
    float a2 = bu2f(xv1.z) + bb.z, a3 = bu2f(xv1.w) + bb.w;
    float d0 = bu2f(xv2.x) + bb.x, d1 = bu2f(xv2.y) + bb.y;
    float d2 = bu2f(xv2.z) + bb.z, d3 = bu2f(xv2.w) + bb.w;
    // ea rows: bf16-packed, 32 B, sequential in sorted space
    const uint4* r1 = (const uint4*)(ea_d + (size_t)e1 * 16);
    const uint4* r2 = (const uint4*)(ea_d + (size_t)e2 * 16);
    const uint4 u1a = r1[0], u1b = r1[1];
    const uint4 u2a = r2[0], u2b = r2[1];
    float ev1[EDGE_IN], ev2[EDGE_IN];
    ev1[0] = bu2f(u1a.x & 0xFFFFu); ev1[1] = bu2f(u1a.x >> 16);
    ev1[2] = bu2f(u1a.y & 0xFFFFu); ev1[3] = bu2f(u1a.y >> 16);
    ev1[4] = bu2f(u1a.z & 0xFFFFu); ev1[5] = bu2f(u1a.z >> 16);
    ev1[6] = bu2f(u1a.w & 0xFFFFu); ev1[7] = bu2f(u1a.w >> 16);
    ev1[8] = bu2f(u1b.x & 0xFFFFu); ev1[9] = bu2f(u1b.x >> 16);
    ev1[10] = bu2f(u1b.y & 0xFFFFu); ev1[11] = bu2f(u1b.y >> 16);
    ev1[12] = bu2f(u1b.z & 0xFFFFu); ev1[13] = bu2f(u1b.z >> 16);
    ev2[0] = bu2f(u2a.x & 0xFFFFu); ev2[1] = bu2f(u2a.x >> 16);
    ev2[2] = bu2f(u2a.y & 0xFFFFu); ev2[3] = bu2f(u2a.y >> 16);
    ev2[4] = bu2f(u2a.z & 0xFFFFu); ev2[5] = bu2f(u2a.z >> 16);
    ev2[6] = bu2f(u2a.w & 0xFFFFu); ev2[7] = bu2f(u2a.w >> 16);
    ev2[8] = bu2f(u2b.x & 0xFFFFu); ev2[9] = bu2f(u2b.x >> 16);
    ev2[10] = bu2f(u2b.y & 0xFFFFu); ev2[11] = bu2f(u2b.y >> 16);
    ev2[12] = bu2f(u2b.z & 0xFFFFu); ev2[13] = bu2f(u2b.z >> 16);
#pragma unroll
    for (int k = 0; k < EDGE_IN; k++) {
        const float4 w = *(const float4*)&w1e[k * HID + c4];
        a0 = fmaf(ev1[k], w.x, a0); a1 = fmaf(ev1[k], w.y, a1);
        a2 = fmaf(ev1[k], w.z, a2); a3 = fmaf(ev1[k], w.w, a3);
        d0 = fmaf(ev2[k], w.x, d0); d1 = fmaf(ev2[k], w.y, d1);
        d2 = fmaf(ev2[k], w.z, d2); d3 = fmaf(ev2[k], w.w, d3);
    }
    const unsigned p1 = fp8_pk(a0, a1) | (fp8_pk(a2, a3) << 16);
    const unsigned p2 = fp8_pk(d0, d1) | (fp8_pk(d2, d3) << 16);
    *(unsigned*)(h0 + (size_t)e1 * HID + c4) = p1;
    *(unsigned*)(h0 + (size_t)e2 * HID + c4) = p2;
}

// K3: hn[j] = relu(h0[j] + (node_sum[src_d[j]] - h[rev_d[j]]) @ W2 + b2)
// (all edge arrays in dst-sorted space)
__global__ __launch_bounds__(256) void k_msg_mfma(const u16* __restrict__ ns,
                                                  const u8* __restrict__ h,
                                                  const u8* __restrict__ h0g,
                                                  const u16* __restrict__ WT2,
                                                  const float* __restrict__ b2,
                                                  const int* __restrict__ src_d,
                                                  const int* __restrict__ rev_d,
                                                  u8* __restrict__ hn) {
    __shared__ u16 A[MT * K2_STRIDE];
    __shared__ float b2s[HID];
    const int e0 = blockIdx.x * MT;
    const int t = threadIdx.x;
    if (t < HID) b2s[t] = b2[t];
    {   // builder: 4 threads/row, 32 channels each (vector loads; random rows)
        const int le = t >> 2, j = t & 3;
        const int e = e0 + le;
        const int s = clampi(src_d[e], N_NODES);
        const int r = clampi(rev_d[e], N_EDGES);
        const u16* nsr = ns + (size_t)s * HID + j * 32;
        const u8* hr = h + (size_t)r * HID + j * 32;
        u16* dstr = &A[le * K2_STRIDE + j * 32];
#pragma unroll
        for (int q = 0; q < 4; q++) {
            const uint4 nv = *(const uint4*)(nsr + q * 8);  // 8 bf16
            const uint2 hv = *(const uint2*)(hr + q * 8);   // 8 fp8
            union { bf16x8 v; u16 s[8]; } o;
            o.s[0] = f2bu(bu2f(nv.x & 0xFFFFu) - FP8_DEC(hv.x, 0));
            o.s[1] = f2bu(bu2f(nv.x >> 16)     - FP8_DEC(hv.x, 1));
            o.s[2] = f2bu(bu2f(nv.y & 0xFFFFu) - FP8_DEC(hv.x, 2));
            o.s[3] = f2bu(bu2f(nv.y >> 16)     - FP8_DEC(hv.x, 3));
            o.s[4] = f2bu(bu2f(nv.z & 0xFFFFu) - FP8_DEC(hv.y, 0));
            o.s[5] = f2bu(bu2f(nv.z >> 16)     - FP8_DEC(hv.y, 1));
            o.s[6] = f2bu(bu2f(nv.w & 0xFFFFu) - FP8_DEC(hv.y, 2));
            o.s[7] = f2bu(bu2f(nv.w >> 16)     - FP8_DEC(hv.y, 3));
            *(bf16x8*)(dstr + q * 8) = o.v;
        }
    }
    __syncthreads();

    const int lane = t & 63, wid = t >> 6;
    const int wm = wid & 1, wn = wid >> 1;
    const int lr = lane & 15, lk = (lane >> 4) * 8;
    f32x4 acc[2][4];
#pragma unroll
    for (int m = 0; m < 2; m++)
#pragma unroll
        for (int n = 0; n < 4; n++) acc[m][n] = (f32x4){0.f, 0.f, 0.f, 0.f};

    const int ar0 = (wm * 32 + lr) * K2_STRIDE + lk;
#pragma unroll
    for (int ks = 0; ks < K2_PAD / 32; ks++) {
        const int kk = ks * 32;
        const bf16x8 a0 = *(const bf16x8*)&A[ar0 + kk];
        const bf16x8 a1 = *(const bf16x8*)&A[ar0 + 16 * K2_STRIDE + kk];
#pragma unroll
        for (int n = 0; n < 4; n++) {
            const bf16x8 b = *(const bf16x8*)&WT2[(size_t)(wn * 64 + n * 16 + lr) * K2_STRIDE + kk + lk];
            acc[0][n] = __builtin_amdgcn_mfma_f32_16x16x32_bf16(a0, b, acc[0][n], 0, 0, 0);
            acc[1][n] = __builtin_amdgcn_mfma_f32_16x16x32_bf16(a1, b, acc[1][n], 0, 0, 0);
        }
    }

    __syncthreads();  // A's builder data fully consumed; safe to overwrite
    // stage product (bf16) into A at [row][col], stride K2_STRIDE
    const int lr4 = lane >> 4;
#pragma unroll
    for (int n = 0; n < 4; n++) {
        const int col = wn * 64 + n * 16 + lr;
#pragma unroll
        for (int m = 0; m < 2; m++)
#pragma unroll
            for (int j = 0; j < 4; j++) {
                const int row = wm * 32 + m * 16 + lr4 * 4 + j;
                A[row * K2_STRIDE + col] = f2bu(acc[m][n][j]);
            }
    }
    __syncthreads();

    // phase 2: coalesced RMW, thread = (row, 32-ch chunk), uint2 (8 fp8) IO
    const int prow = t >> 2, pj = t & 3;
    const long long e = e0 + prow;
#pragma unroll
    for (int q = 0; q < 4; q++) {
        const int c8 = pj * 32 + q * 8;
        const uint4 sv = *(const uint4*)&A[prow * K2_STRIDE + c8];  // 8 bf16
        const uint2 hv = *(const uint2*)(h0g + e * HID + c8);       // 8 fp8
        const float4 ba = *(const float4*)&b2s[c8];
        const float4 bbv = *(const float4*)&b2s[c8 + 4];
        const float v0 = bu2f(sv.x & 0xFFFFu) + FP8_DEC(hv.x, 0) + ba.x;
        const float v1 = bu2f(sv.x >> 16)     + FP8_DEC(hv.x, 1) + ba.y;
        const float v2 = bu2f(sv.y & 0xFFFFu) + FP8_DEC(hv.x, 2) + ba.z;
        const float v3 = bu2f(sv.y >> 16)     + FP8_DEC(hv.x, 3) + ba.w;
        const float v4 = bu2f(sv.z & 0xFFFFu) + FP8_DEC(hv.y, 0) + bbv.x;
        const float v5 = bu2f(sv.z >> 16)     + FP8_DEC(hv.y, 1) + bbv.y;
        const float v6 = bu2f(sv.w & 0xFFFFu) + FP8_DEC(hv.y, 2) + bbv.z;
        const float v7 = bu2f(sv.w >> 16)     + FP8_DEC(hv.y, 3) + bbv.w;
        uint2 o;
        o.x = fp8_pk(v0, v1) | (fp8_pk(v2, v3) << 16);
        o.y = fp8_pk(v4, v5) | (fp8_pk(v6, v7) << 16);
        *(uint2*)(hn + e * HID + c8) = o;
    }
}

// K5: node_attr[n] = relu(concat(x[n], vmsg[n]) @ W3 + b3)  (fp32 out)
__global__ __launch_bounds__(256) void k_node_mfma(const float* __restrict__ x,
                                                   const u16* __restrict__ vmsg,
                                                   const u16* __restrict__ WT3,
                                                   const float* __restrict__ b3,
                                                   float* __restrict__ node_attr) {
    __shared__ u16 A[MT * K3_STRIDE];
    const int n0 = blockIdx.x * MT;
    const int t = threadIdx.x;
    const int lane = t & 63, wv = t >> 6;
    {   // coalesced builder: wave wv handles rows wv*16 .. wv*16+15
        for (int rr = 0; rr < 16; rr++) {
            const int row = wv * 16 + rr;
            const int n = n0 + row;
            const float* xr = x + (size_t)n * NODE_IN;
            const unsigned* vr = (const unsigned*)(vmsg + (size_t)n * HID);
            u16* dstr = &A[row * K3_STRIDE];
            dstr[lane] = f2bu(xr[lane]);                 // k 0..63
            dstr[64 + lane] = f2bu(xr[64 + lane]);       // k 64..127
            if (lane < 5) dstr[128 + lane] = f2bu(xr[128 + lane]);  // 128..132
            const unsigned v = vr[lane];                 // 2 bf16
            dstr[NODE_IN + 2 * lane] = (u16)(v & 0xFFFFu);
            dstr[NODE_IN + 2 * lane + 1] = (u16)(v >> 16);
            if (lane < K3_PAD - (NODE_IN + HID))         // 261..287
                dstr[NODE_IN + HID + lane] = 0;
        }
    }
    __syncthreads();

    const int wm = wv & 1, wn = wv >> 1;
    const int lr = lane & 15, lk = (lane >> 4) * 8;
    f32x4 acc[2][4];
#pragma unroll
    for (int m = 0; m < 2; m++)
#pragma unroll
        for (int n = 0; n < 4; n++) acc[m][n] = (f32x4){0.f, 0.f, 0.f, 0.f};

    const int ar0 = (wm * 32 + lr) * K3_STRIDE + lk;
#pragma unroll
    for (int ks = 0; ks < K3_PAD / 32; ks++) {
        const int kk = ks * 32;
        const bf16x8 a0 = *(const bf16x8*)&A[ar0 + kk];
        const bf16x8 a1 = *(const bf16x8*)&A[ar0 + 16 * K3_STRIDE + kk];
#pragma unroll
        for (int n = 0; n < 4; n++) {
            const bf16x8 b = *(const bf16x8*)&WT3[(size_t)(wn * 64 + n * 16 + lr) * K3_STRIDE + kk + lk];
            acc[0][n] = __builtin_amdgcn_mfma_f32_16x16x32_bf16(a0, b, acc[0][n], 0, 0, 0);
            acc[1][n] = __builtin_amdgcn_mfma_f32_16x16x32_bf16(a1, b, acc[1][n], 0, 0, 0);
        }
    }

    const int lr4 = lane >> 4;
#pragma unroll
    for (int n = 0; n < 4; n++) {
        const int col = wn * 64 + n * 16 + lr;
        const float bias = b3[col];
#pragma unroll
        for (int m = 0; m < 2; m++)
#pragma unroll
            for (int j = 0; j < 4; j++) {
                const int nd = n0 + wm * 32 + m * 16 + lr4 * 4 + j;
                float v = acc[m][n][j] + bias;
                node_attr[(size_t)nd * HID + col] = v > 0.f ? v : 0.f;
            }
    }
}

// ---------------------------------------------------------------------------
// K6: out[g] = mean over the graph's (sorted, contiguous) node range.
// ---------------------------------------------------------------------------
__global__ __launch_bounds__(128) void k_pool2(const float* __restrict__ node_attr,
                                               const int* __restrict__ batch,
                                               float* __restrict__ out) {
    const int g = blockIdx.x;
    __shared__ int lo_s, hi_s;
    if (threadIdx.x == 0) {
        int lo = 0, hi = N_NODES;
        while (lo < hi) { int mid = (lo + hi) >> 1; if (batch[mid] < g) lo = mid + 1; else hi = mid; }
        lo_s = lo;
        int lo2 = lo, hi2 = N_NODES;
        while (lo2 < hi2) { int mid = (lo2 + hi2) >> 1; if (batch[mid] <= g) lo2 = mid + 1; else hi2 = mid; }
        hi_s = lo2;
    }
    __syncthreads();
    const int lo = lo_s, hi = hi_s;
    float acc = 0.f;
    for (int n = lo; n < hi; n++) acc += node_attr[(size_t)n * HID + threadIdx.x];
    const float cnt = (hi > lo) ? (float)(hi - lo) : 1.f;
    out[(size_t)g * HID + threadIdx.x] = acc / cnt;
}

// ---------------------------------------------------------------------------
extern "C" void kernel_launch(void* const* d_in, const int* in_sizes, int n_in,
                              void* d_out, int out_size, void* d_ws, size_t ws_size,
                              hipStream_t stream) {
    const float* x   = (const float*)d_in[0];
    const float* ea  = (const float*)d_in[1];
    const float* W1  = (const float*)d_in[2];
    const float* b1  = (const float*)d_in[3];
    const float* W2  = (const float*)d_in[4];
    const float* b2  = (const float*)d_in[5];
    const float* W3  = (const float*)d_in[6];
    const float* b3  = (const float*)d_in[7];
    const int*   ei  = (const int*)d_in[8];
    const int*   src = ei;
    const int*   dst = ei + N_EDGES;
    const int*   rev = (const int*)d_in[9];
    const int*   bat = (const int*)d_in[10];

    char* ws = (char*)d_ws;
    size_t off = 0;
    auto alloc = [&](size_t bytes) -> void* {
        void* p = ws + off;
        off += (bytes + 255) & ~(size_t)255;
        return p;
    };
    const size_t hbytes = (size_t)N_EDGES * HID;                 // 102.4 MB fp8
    u8* h0 = (u8*)alloc(hbytes);
    u8* hA = (u8*)alloc(hbytes);
    u8* hB = (u8*)alloc(hbytes);
    u16* node_sum = (u16*)alloc((size_t)N_NODES * HID * sizeof(u16));  // 51.2 MB
    int* row_ptr = (int*)alloc((size_t)(N_NODES + 1) * sizeof(int));
    int* eidx = (int*)alloc((size_t)N_EDGES * sizeof(int));
    int* src_d = (int*)alloc((size_t)N_EDGES * sizeof(int));
    int* rev_d = (int*)alloc((size_t)N_EDGES * sizeof(int));
    u16* ea_d = (u16*)alloc((size_t)N_EDGES * 16 * sizeof(u16));  // 25.6 MB
    u16* WT1 = (u16*)alloc((size_t)HID * K1_STRIDE * sizeof(u16));
    u16* WT2 = (u16*)alloc((size_t)HID * K2_STRIDE * sizeof(u16));
    u16* WT3 = (u16*)alloc((size_t)HID * K3_STRIDE * sizeof(u16));
    // Aliases:
    //  - xw (bf16, 51.2 MB) lives in hA: dead before the first k_msg writes hA.
    //  - node_attr (fp32, 102.4 MB) lives in h0: dead after last k_msg read.
    u16* xw = (u16*)hA;
    float* node_attr = (float*)h0;
    // total ~395 MB < proven ws floor of ~415.7 MB (round-3 fp8_csr tier ran)

    if (ws_size < off) return;  // diagnostic: leave d_out untouched

    // weight transpose+pad to bf16
    k_prep<<<(HID * K1_STRIDE + 255) / 256, 256, 0, stream>>>(W1, WT1, NODE_IN + EDGE_IN, K1_STRIDE);
    k_prep<<<(HID * K2_STRIDE + 255) / 256, 256, 0, stream>>>(W2, WT2, HID, K2_STRIDE);
    k_prep<<<(HID * K3_STRIDE + 255) / 256, 256, 0, stream>>>(W3, WT3, NODE_IN + HID, K3_STRIDE);

    // CSR build + dst-sorted relabeling (transients overlay node_sum)
    {
        int* cnt = (int*)node_sum;
        int* local = cnt + N_NODES;
        int* cursor = local + N_NODES;
        int* partial = cursor + N_NODES;
        int* inv = partial + 4096;  // 3.2 MB, still well inside node_sum's 51.2 MB
        hipMemsetAsync(cnt, 0, (size_t)N_NODES * sizeof(int), stream);
        k_hist<<<(N_EDGES + 255) / 256, 256, 0, stream>>>(dst, cnt);
        k_scan1<<<SCAN_NBLK, 256, 0, stream>>>(cnt, local, partial);
        k_scan2<<<1, 256, 0, stream>>>(partial);
        k_scan3<<<(N_NODES + 256) / 256, 256, 0, stream>>>(local, partial, row_ptr, cursor);
        k_place<<<(N_EDGES + 255) / 256, 256, 0, stream>>>(dst, cursor, eidx);
        k_inv<<<(N_EDGES + 255) / 256, 256, 0, stream>>>(eidx, inv);
        k_remap<<<(N_EDGES + 255) / 256, 256, 0, stream>>>(eidx, src, rev, inv, src_d, rev_d);
        k_ea<<<(N_EDGES + 255) / 256, 256, 0, stream>>>(eidx, ea, ea_d);
    }

    // h0 = relu(x[src]@W1x + ea@W1e + b1), split per-node GEMM + fused epilogue
    k_xw<<<N_NODES / MT, 256, 0, stream>>>(x, WT1, xw);
    k_init2<<<N_EDGES / 16, 256, 0, stream>>>(xw, ea_d, W1, b1, src_d, h0);

    const u8* h = h0;
    u8* bufs[2] = {hA, hB};
    const int agg_blocks = (int)(((long long)N_NODES * 16 + 255) / 256);
    for (int it = 0; it < 3; it++) {
        k_gather<<<agg_blocks, 256, 0, stream>>>(h, row_ptr, node_sum);
        u8* hn = bufs[it & 1];   // it=0 writes hA (xw already consumed)
        k_msg_mfma<<<N_EDGES / MT, 256, 0, stream>>>(node_sum, h, h0, WT2, b2, src_d, rev_d, hn);
        h = hn;
    }
    k_gather<<<agg_blocks, 256, 0, stream>>>(h, row_ptr, node_sum);

    // h0 is dead from here; node_attr reuses its storage.
    k_node_mfma<<<N_NODES / MT, 256, 0, stream>>>(x, node_sum, WT3, b3, node_attr);
    k_pool2<<<NUM_GRAPHS, 128, 0, stream>>>(node_attr, bat, (float*)d_out);
}

// Round 14
// 977.782 us; speedup vs baseline: 1.7675x; 1.0629x over previous
//
#include <hip/hip_runtime.h>

#define N_NODES 200000
#define N_EDGES 800000
#define NODE_IN 133
#define EDGE_IN 14
#define HID 128
#define NUM_GRAPHS 4096

#define SCAN_CHUNK 2048
#define SCAN_NBLK ((N_NODES + SCAN_CHUNK - 1) / SCAN_CHUNK)  // 98

#define MT 64  // M tile rows per block for MFMA GEMMs

// K geometry per GEMM (padded K, LDS/WT row stride in elements)
#define K1_PAD 160
#define K1_STRIDE 168
#define K2_PAD 128
#define K2_STRIDE 136
#define K3_PAD 288
#define K3_STRIDE 296    // WT3 global row stride
#define K3H_STRIDE 168   // k_node per-half LDS staging stride (160 used)
#define KE_PAD 32        // k_init3 ea K (14 used, zero-padded)
#define KE_STRIDE 40

typedef unsigned short u16;
typedef unsigned char u8;
typedef short bf16x8 __attribute__((ext_vector_type(8)));
typedef float f32x4 __attribute__((ext_vector_type(4)));

__device__ __forceinline__ float bu2f(unsigned s) {
    return __uint_as_float(s << 16);
}
__device__ __forceinline__ u16 f2bu(float f) {
    unsigned u = __float_as_uint(f);
    return (u16)((u + 0x7FFFu + ((u >> 16) & 1u)) >> 16);  // RNE
}
// ---------------- fp8 e4m3 (OCP), non-negative post-ReLU values -----------
__device__ __forceinline__ float e42f(unsigned b) {
    unsigned E = (b >> 4) & 0xF, M = b & 7u;
    if (E == 0) return (float)M * 0.001953125f;  // M * 2^-9
    return __uint_as_float(((E - 7u + 127u) << 23) | (M << 20));
}
__device__ __forceinline__ u8 f2e4(float f) {
    if (!(f > 0.f)) return 0;
    if (f >= 448.f) return 0x7E;
    unsigned u = __float_as_uint(f);
    int e = (int)((u >> 23) & 0xFF) - 127;
    if (e < -6) {
        int q = (int)rintf(f * 512.f);
        return (u8)q;
    }
    unsigned m = u & 0x7FFFFF;
    unsigned keep = m >> 20, rem = m & 0xFFFFF;
    keep += (rem > 0x80000u || (rem == 0x80000u && (keep & 1u))) ? 1u : 0u;
    unsigned E = (unsigned)(e + 7);
    if (keep == 8u) { keep = 0u; E++; }
    return (u8)((E << 4) | keep);
}

// ---------------- HW fp8 convert (gfx950 OCP) with software fallback -------
#if defined(__has_builtin)
#if __has_builtin(__builtin_amdgcn_cvt_f32_fp8) && __has_builtin(__builtin_amdgcn_cvt_pk_fp8_f32)
#define HW_FP8 1
#endif
#endif

#if defined(HW_FP8)
// sel must be a compile-time constant
#define FP8_DEC(dw, s) __builtin_amdgcn_cvt_f32_fp8((int)(dw), (s))
__device__ __forceinline__ unsigned fp8_pk(float a, float b) {
    a = fminf(fmaxf(a, 0.f), 448.f);  // ReLU + sat (matches sw path)
    b = fminf(fmaxf(b, 0.f), 448.f);
    return (unsigned)__builtin_amdgcn_cvt_pk_fp8_f32(a, b, 0, false) & 0xFFFFu;
}
#else
#define FP8_DEC(dw, s) e42f(((dw) >> (8 * (s))) & 0xFFu)
__device__ __forceinline__ unsigned fp8_pk(float a, float b) {
    return (unsigned)f2e4(a) | ((unsigned)f2e4(b) << 8);
}
#endif

__device__ __forceinline__ int clampi(int v, int hi) {
    return v < 0 ? 0 : (v >= hi ? hi - 1 : v);
}

// ---------------------------------------------------------------------------
// Weight prep: WT[n][k] = bf16(W[k][n]), k < K else 0.
// ---------------------------------------------------------------------------
__global__ __launch_bounds__(256) void k_prep(const float* __restrict__ W,
                                              u16* __restrict__ WT, int K,
                                              int stride) {
    const int idx = blockIdx.x * 256 + threadIdx.x;
    if (idx >= HID * stride) return;
    const int n = idx / stride, k = idx % stride;
    WT[idx] = (k < K) ? f2bu(W[k * HID + n]) : (u16)0;
}

// ---------------------------------------------------------------------------
// CSR build: histogram -> exclusive scan -> atomic-cursor placement.
// Edge state space is RELABELED into dst-sorted order: j <-> eidx[j].
// ---------------------------------------------------------------------------
__global__ __launch_bounds__(256) void k_hist(const int* __restrict__ dst,
                                              int* __restrict__ cnt) {
    const int e = blockIdx.x * 256 + threadIdx.x;
    if (e < N_EDGES) atomicAdd(&cnt[clampi(dst[e], N_NODES)], 1);
}

__global__ __launch_bounds__(256) void k_scan1(const int* __restrict__ cnt,
                                               int* __restrict__ local,
                                               int* __restrict__ partial) {
    __shared__ int tsum[256];
    const int b = blockIdx.x, t = threadIdx.x;
    const int base = b * SCAN_CHUNK + t * 8;
    int v[8];
    int s = 0;
#pragma unroll
    for (int i = 0; i < 8; i++) {
        const int idx = base + i;
        v[i] = (idx < N_NODES) ? cnt[idx] : 0;
        s += v[i];
    }
    tsum[t] = s;
    __syncthreads();
    for (int ofs = 1; ofs < 256; ofs <<= 1) {
        const int add = (t >= ofs) ? tsum[t - ofs] : 0;
        __syncthreads();
        tsum[t] += add;
        __syncthreads();
    }
    int excl = (t == 0) ? 0 : tsum[t - 1];
    if (t == 255) partial[b] = tsum[255];
#pragma unroll
    for (int i = 0; i < 8; i++) {
        const int idx = base + i;
        if (idx < N_NODES) local[idx] = excl;
        excl += v[i];
    }
}

__global__ __launch_bounds__(256) void k_scan2(int* __restrict__ partial) {
    __shared__ int s[256];
    const int t = threadIdx.x;
    s[t] = (t < SCAN_NBLK) ? partial[t] : 0;
    __syncthreads();
    for (int ofs = 1; ofs < 256; ofs <<= 1) {
        const int add = (t >= ofs) ? s[t - ofs] : 0;
        __syncthreads();
        s[t] += add;
        __syncthreads();
    }
    if (t < SCAN_NBLK) partial[t] = (t == 0) ? 0 : s[t - 1];
}

__global__ __launch_bounds__(256) void k_scan3(const int* __restrict__ local,
                                               const int* __restrict__ partial,
                                               int* __restrict__ row_ptr,
                                               int* __restrict__ cursor) {
    const int idx = blockIdx.x * 256 + threadIdx.x;
    if (idx <= N_NODES) {
        const int v = (idx == N_NODES) ? N_EDGES
                                       : local[idx] + partial[idx / SCAN_CHUNK];
        row_ptr[idx] = v;
        if (idx < N_NODES) cursor[idx] = v;
    }
}

__global__ __launch_bounds__(256) void k_place(const int* __restrict__ dst,
                                               int* __restrict__ cursor,
                                               int* __restrict__ eidx) {
    const int e = blockIdx.x * 256 + threadIdx.x;
    if (e < N_EDGES) {
        const int slot = atomicAdd(&cursor[clampi(dst[e], N_NODES)], 1);
        eidx[slot] = e;
    }
}

// inv[eidx[j]] = j
__global__ __launch_bounds__(256) void k_inv(const int* __restrict__ eidx,
                                             int* __restrict__ inv) {
    const int j = blockIdx.x * 256 + threadIdx.x;
    if (j < N_EDGES) inv[clampi(eidx[j], N_EDGES)] = j;
}

// src_d[j] = src[eidx[j]];  rev_d[j] = inv[rev[eidx[j]]]
__global__ __launch_bounds__(256) void k_remap(const int* __restrict__ eidx,
                                               const int* __restrict__ src,
                                               const int* __restrict__ rev,
                                               const int* __restrict__ inv,
                                               int* __restrict__ src_d,
                                               int* __restrict__ rev_d) {
    const int j = blockIdx.x * 256 + threadIdx.x;
    if (j < N_EDGES) {
        const int e = clampi(eidx[j], N_EDGES);
        src_d[j] = src[e];
        rev_d[j] = inv[clampi(rev[e], N_EDGES)];
    }
}

// ea_d[j] = bf16-packed ea[eidx[j]] (16 u16 = 32 B rows; last 2 zero)
__global__ __launch_bounds__(256) void k_ea(const int* __restrict__ eidx,
                                            const float* __restrict__ ea,
                                            u16* __restrict__ ea_d) {
    const int j = blockIdx.x * 256 + threadIdx.x;
    if (j >= N_EDGES) return;
    const int e = clampi(eidx[j], N_EDGES);
    const float2* er = (const float2*)(ea + (size_t)e * EDGE_IN);
    u16 v[16];
#pragma unroll
    for (int k = 0; k < 7; k++) {
        const float2 u = er[k];
        v[2 * k] = f2bu(u.x);
        v[2 * k + 1] = f2bu(u.y);
    }
    v[14] = 0; v[15] = 0;
    uint4 o1, o2;
    o1.x = (unsigned)v[0] | ((unsigned)v[1] << 16);
    o1.y = (unsigned)v[2] | ((unsigned)v[3] << 16);
    o1.z = (unsigned)v[4] | ((unsigned)v[5] << 16);
    o1.w = (unsigned)v[6] | ((unsigned)v[7] << 16);
    o2.x = (unsigned)v[8] | ((unsigned)v[9] << 16);
    o2.y = (unsigned)v[10] | ((unsigned)v[11] << 16);
    o2.z = (unsigned)v[12] | ((unsigned)v[13] << 16);
    o2.w = 0;
    uint4* dstp = (uint4*)(ea_d + (size_t)j * 16);
    dstp[0] = o1;
    dstp[1] = o2;
}

// ---------------------------------------------------------------------------
// K2 (streaming gather): node_sum[n] = sum over contiguous sorted rows.
// ---------------------------------------------------------------------------
__global__ __launch_bounds__(256) void k_gather(const u8* __restrict__ h,
                                                const int* __restrict__ row_ptr,
                                                u16* __restrict__ node_sum) {
    const long long idx = (long long)blockIdx.x * 256 + threadIdx.x;
    const int n = (int)(idx >> 4);
    if (n >= N_NODES) return;
    const int c8 = (int)(idx & 15) << 3;
    const int beg = row_ptr[n], end = row_ptr[n + 1];
    float a0 = 0.f, a1 = 0.f, a2 = 0.f, a3 = 0.f;
    float a4 = 0.f, a5 = 0.f, a6 = 0.f, a7 = 0.f;
    for (int j = beg; j < end; j++) {
        const uint2 v = *reinterpret_cast<const uint2*>(h + (long long)j * HID + c8);
        a0 += FP8_DEC(v.x, 0); a1 += FP8_DEC(v.x, 1);
        a2 += FP8_DEC(v.x, 2); a3 += FP8_DEC(v.x, 3);
        a4 += FP8_DEC(v.y, 0); a5 += FP8_DEC(v.y, 1);
        a6 += FP8_DEC(v.y, 2); a7 += FP8_DEC(v.y, 3);
    }
    ushort4 o1, o2;
    o1.x = f2bu(a0); o1.y = f2bu(a1); o1.z = f2bu(a2); o1.w = f2bu(a3);
    o2.x = f2bu(a4); o2.y = f2bu(a5); o2.z = f2bu(a6); o2.w = f2bu(a7);
    *reinterpret_cast<ushort4*>(node_sum + (long long)n * HID + c8) = o1;
    *reinterpret_cast<ushort4*>(node_sum + (long long)n * HID + c8 + 4) = o2;
}

// ---------------------------------------------------------------------------
// MFMA geometry (64x128 tile, 4 waves: 2 in M x 2 in N)
// a-frag: lane holds A[lane&15][(lane>>4)*8 + i]; b-frag from [n][k] layout.
// C/D: col = lane&15, row = (lane>>4)*4 + reg.
// ---------------------------------------------------------------------------

// K1a: xw[n] = x[n] @ W1x  (per-NODE GEMM; A cols 133..159 zeroed)
__global__ __launch_bounds__(256) void k_xw(const float* __restrict__ x,
                                            const u16* __restrict__ WT1,
                                            u16* __restrict__ xw) {
    __shared__ u16 A[MT * K1_STRIDE];
    const int n0 = blockIdx.x * MT;
    const int t = threadIdx.x;
    const int lane = t & 63, wv = t >> 6;
    for (int rr = 0; rr < 16; rr++) {
        const int row = wv * 16 + rr;
        const int n = n0 + row;
        const float* xr = x + (size_t)n * NODE_IN;
        u16* dstr = &A[row * K1_STRIDE];
        dstr[lane] = f2bu(xr[lane]);                 // k 0..63
        dstr[64 + lane] = f2bu(xr[64 + lane]);       // k 64..127
        if (lane < 5) dstr[128 + lane] = f2bu(xr[128 + lane]);  // 128..132
        if (lane < K1_PAD - NODE_IN) dstr[NODE_IN + lane] = 0;  // 133..159
    }
    __syncthreads();

    const int wm = wv & 1, wn = wv >> 1;
    const int lr = lane & 15, lk = (lane >> 4) * 8;
    f32x4 acc[2][4];
#pragma unroll
    for (int m = 0; m < 2; m++)
#pragma unroll
        for (int n = 0; n < 4; n++) acc[m][n] = (f32x4){0.f, 0.f, 0.f, 0.f};

    const int ar0 = (wm * 32 + lr) * K1_STRIDE + lk;
#pragma unroll
    for (int ks = 0; ks < K1_PAD / 32; ks++) {
        const int kk = ks * 32;
        const bf16x8 a0 = *(const bf16x8*)&A[ar0 + kk];
        const bf16x8 a1 = *(const bf16x8*)&A[ar0 + 16 * K1_STRIDE + kk];
#pragma unroll
        for (int n = 0; n < 4; n++) {
            const bf16x8 b = *(const bf16x8*)&WT1[(size_t)(wn * 64 + n * 16 + lr) * K1_STRIDE + kk + lk];
            acc[0][n] = __builtin_amdgcn_mfma_f32_16x16x32_bf16(a0, b, acc[0][n], 0, 0, 0);
            acc[1][n] = __builtin_amdgcn_mfma_f32_16x16x32_bf16(a1, b, acc[1][n], 0, 0, 0);
        }
    }

    const int lr4 = lane >> 4;
#pragma unroll
    for (int n = 0; n < 4; n++) {
        const int col = wn * 64 + n * 16 + lr;
#pragma unroll
        for (int m = 0; m < 2; m++)
#pragma unroll
            for (int j = 0; j < 4; j++) {
                const int nd = n0 + wm * 32 + m * 16 + lr4 * 4 + j;
                xw[(size_t)nd * HID + col] = f2bu(acc[m][n][j]);
            }
    }
}

// K1b (MFMA): h0[j] = relu(xw[src_d[j]] + ea_d[j]@W1e + b1) -> fp8.
// ea matvec on the matrix pipe (one k-step); k_msg-style staged epilogue.
__global__ __launch_bounds__(256) void k_init3(const u16* __restrict__ xw,
                                               const u16* __restrict__ ea_d,
                                               const float* __restrict__ W1,
                                               const float* __restrict__ b1,
                                               const int* __restrict__ src_d,
                                               u8* __restrict__ h0) {
    __shared__ u16 Aea[MT * KE_STRIDE];       // 5120 B
    __shared__ u16 W1e[HID * KE_PAD];         // [n][k], 8192 B
    __shared__ u16 Sacc[MT * K2_STRIDE];      // 17408 B staging
    __shared__ float b1s[HID];
    const int e0 = blockIdx.x * MT;
    const int t = threadIdx.x;

    for (int i = t; i < HID * KE_PAD; i += 256) {
        const int n = i >> 5, k = i & 31;
        W1e[i] = (k < EDGE_IN) ? f2bu(W1[(NODE_IN + k) * HID + n]) : (u16)0;
    }
    if (t < HID) b1s[t] = b1[t];
    {   // ea tile: 4 threads/row, 8B each; pad 16..31 zeroed
        const int row = t >> 2, q = t & 3;
        const uint2 v = *(const uint2*)(ea_d + (size_t)(e0 + row) * 16 + q * 4);
        *(uint2*)&Aea[row * KE_STRIDE + q * 4] = v;
        uint2 z; z.x = 0; z.y = 0;
        *(uint2*)&Aea[row * KE_STRIDE + 16 + q * 4] = z;
    }
    __syncthreads();

    const int lane = t & 63, wid = t >> 6;
    const int wm = wid & 1, wn = wid >> 1;
    const int lr = lane & 15, lk = (lane >> 4) * 8;
    f32x4 acc[2][4];
#pragma unroll
    for (int m = 0; m < 2; m++)
#pragma unroll
        for (int n = 0; n < 4; n++) acc[m][n] = (f32x4){0.f, 0.f, 0.f, 0.f};

    {
        const bf16x8 a0 = *(const bf16x8*)&Aea[(wm * 32 + lr) * KE_STRIDE + lk];
        const bf16x8 a1 = *(const bf16x8*)&Aea[(wm * 32 + 16 + lr) * KE_STRIDE + lk];
#pragma unroll
        for (int n = 0; n < 4; n++) {
            const bf16x8 b = *(const bf16x8*)&W1e[(wn * 64 + n * 16 + lr) * KE_PAD + lk];
            acc[0][n] = __builtin_amdgcn_mfma_f32_16x16x32_bf16(a0, b, acc[0][n], 0, 0, 0);
            acc[1][n] = __builtin_amdgcn_mfma_f32_16x16x32_bf16(a1, b, acc[1][n], 0, 0, 0);
        }
    }

    // stage product bf16 -> Sacc[row][col]
    const int lr4 = lane >> 4;
#pragma unroll
    for (int n = 0; n < 4; n++) {
        const int col = wn * 64 + n * 16 + lr;
#pragma unroll
        for (int m = 0; m < 2; m++)
#pragma unroll
            for (int j = 0; j < 4; j++) {
                const int row = wm * 32 + m * 16 + lr4 * 4 + j;
                Sacc[row * K2_STRIDE + col] = f2bu(acc[m][n][j]);
            }
    }
    __syncthreads();

    // phase 2: coalesced, thread = (row, 32-ch chunk)
    const int prow = t >> 2, pj = t & 3;
    const long long e = e0 + prow;
    const int s = clampi(src_d[e], N_NODES);
#pragma unroll
    for (int q = 0; q < 4; q++) {
        const int c8 = pj * 32 + q * 8;
        const uint4 sv = *(const uint4*)&Sacc[prow * K2_STRIDE + c8];  // 8 bf16
        const uint4 xv = *(const uint4*)(xw + (size_t)s * HID + c8);   // 8 bf16
        const float4 ba = *(const float4*)&b1s[c8];
        const float4 bbv = *(const float4*)&b1s[c8 + 4];
        const float v0 = bu2f(sv.x & 0xFFFFu) + bu2f(xv.x & 0xFFFFu) + ba.x;
        const float v1 = bu2f(sv.x >> 16)     + bu2f(xv.x >> 16)     + ba.y;
        const float v2 = bu2f(sv.y & 0xFFFFu) + bu2f(xv.y & 0xFFFFu) + ba.z;
        const float v3 = bu2f(sv.y >> 16)     + bu2f(xv.y >> 16)     + ba.w;
        const float v4 = bu2f(sv.z & 0xFFFFu) + bu2f(xv.z & 0xFFFFu) + bbv.x;
        const float v5 = bu2f(sv.z >> 16)     + bu2f(xv.z >> 16)     + bbv.y;
        const float v6 = bu2f(sv.w & 0xFFFFu) + bu2f(xv.w & 0xFFFFu) + bbv.z;
        const float v7 = bu2f(sv.w >> 16)     + bu2f(xv.w >> 16)     + bbv.w;
        uint2 o;
        o.x = fp8_pk(v0, v1) | (fp8_pk(v2, v3) << 16);
        o.y = fp8_pk(v4, v5) | (fp8_pk(v6, v7) << 16);
        *(uint2*)(h0 + e * HID + c8) = o;
    }
}

// K3: hn[j] = relu(h0[j] + (node_sum[src_d[j]] - h[rev_d[j]]) @ W2 + b2)
__global__ __launch_bounds__(256) void k_msg_mfma(const u16* __restrict__ ns,
                                                  const u8* __restrict__ h,
                                                  const u8* __restrict__ h0g,
                                                  const u16* __restrict__ WT2,
                                                  const float* __restrict__ b2,
                                                  const int* __restrict__ src_d,
                                                  const int* __restrict__ rev_d,
                                                  u8* __restrict__ hn) {
    __shared__ u16 A[MT * K2_STRIDE];
    __shared__ float b2s[HID];
    const int e0 = blockIdx.x * MT;
    const int t = threadIdx.x;
    if (t < HID) b2s[t] = b2[t];
    {   // builder: 4 threads/row, 32 channels each
        const int le = t >> 2, j = t & 3;
        const int e = e0 + le;
        const int s = clampi(src_d[e], N_NODES);
        const int r = clampi(rev_d[e], N_EDGES);
        const u16* nsr = ns + (size_t)s * HID + j * 32;
        const u8* hr = h + (size_t)r * HID + j * 32;
        u16* dstr = &A[le * K2_STRIDE + j * 32];
#pragma unroll
        for (int q = 0; q < 4; q++) {
            const uint4 nv = *(const uint4*)(nsr + q * 8);  // 8 bf16
            const uint2 hv = *(const uint2*)(hr + q * 8);   // 8 fp8
            union { bf16x8 v; u16 s[8]; } o;
            o.s[0] = f2bu(bu2f(nv.x & 0xFFFFu) - FP8_DEC(hv.x, 0));
            o.s[1] = f2bu(bu2f(nv.x >> 16)     - FP8_DEC(hv.x, 1));
            o.s[2] = f2bu(bu2f(nv.y & 0xFFFFu) - FP8_DEC(hv.x, 2));
            o.s[3] = f2bu(bu2f(nv.y >> 16)     - FP8_DEC(hv.x, 3));
            o.s[4] = f2bu(bu2f(nv.z & 0xFFFFu) - FP8_DEC(hv.y, 0));
            o.s[5] = f2bu(bu2f(nv.z >> 16)     - FP8_DEC(hv.y, 1));
            o.s[6] = f2bu(bu2f(nv.w & 0xFFFFu) - FP8_DEC(hv.y, 2));
            o.s[7] = f2bu(bu2f(nv.w >> 16)     - FP8_DEC(hv.y, 3));
            *(bf16x8*)(dstr + q * 8) = o.v;
        }
    }
    __syncthreads();

    const int lane = t & 63, wid = t >> 6;
    const int wm = wid & 1, wn = wid >> 1;
    const int lr = lane & 15, lk = (lane >> 4) * 8;
    f32x4 acc[2][4];
#pragma unroll
    for (int m = 0; m < 2; m++)
#pragma unroll
        for (int n = 0; n < 4; n++) acc[m][n] = (f32x4){0.f, 0.f, 0.f, 0.f};

    const int ar0 = (wm * 32 + lr) * K2_STRIDE + lk;
#pragma unroll
    for (int ks = 0; ks < K2_PAD / 32; ks++) {
        const int kk = ks * 32;
        const bf16x8 a0 = *(const bf16x8*)&A[ar0 + kk];
        const bf16x8 a1 = *(const bf16x8*)&A[ar0 + 16 * K2_STRIDE + kk];
#pragma unroll
        for (int n = 0; n < 4; n++) {
            const bf16x8 b = *(const bf16x8*)&WT2[(size_t)(wn * 64 + n * 16 + lr) * K2_STRIDE + kk + lk];
            acc[0][n] = __builtin_amdgcn_mfma_f32_16x16x32_bf16(a0, b, acc[0][n], 0, 0, 0);
            acc[1][n] = __builtin_amdgcn_mfma_f32_16x16x32_bf16(a1, b, acc[1][n], 0, 0, 0);
        }
    }

    __syncthreads();  // A's builder data fully consumed
    const int lr4 = lane >> 4;
#pragma unroll
    for (int n = 0; n < 4; n++) {
        const int col = wn * 64 + n * 16 + lr;
#pragma unroll
        for (int m = 0; m < 2; m++)
#pragma unroll
            for (int j = 0; j < 4; j++) {
                const int row = wm * 32 + m * 16 + lr4 * 4 + j;
                A[row * K2_STRIDE + col] = f2bu(acc[m][n][j]);
            }
    }
    __syncthreads();

    const int prow = t >> 2, pj = t & 3;
    const long long e = e0 + prow;
#pragma unroll
    for (int q = 0; q < 4; q++) {
        const int c8 = pj * 32 + q * 8;
        const uint4 sv = *(const uint4*)&A[prow * K2_STRIDE + c8];  // 8 bf16
        const uint2 hv = *(const uint2*)(h0g + e * HID + c8);       // 8 fp8
        const float4 ba = *(const float4*)&b2s[c8];
        const float4 bbv = *(const float4*)&b2s[c8 + 4];
        const float v0 = bu2f(sv.x & 0xFFFFu) + FP8_DEC(hv.x, 0) + ba.x;
        const float v1 = bu2f(sv.x >> 16)     + FP8_DEC(hv.x, 1) + ba.y;
        const float v2 = bu2f(sv.y & 0xFFFFu) + FP8_DEC(hv.x, 2) + ba.z;
        const float v3 = bu2f(sv.y >> 16)     + FP8_DEC(hv.x, 3) + ba.w;
        const float v4 = bu2f(sv.z & 0xFFFFu) + FP8_DEC(hv.y, 0) + bbv.x;
        const float v5 = bu2f(sv.z >> 16)     + FP8_DEC(hv.y, 1) + bbv.y;
        const float v6 = bu2f(sv.w & 0xFFFFu) + FP8_DEC(hv.y, 2) + bbv.z;
        const float v7 = bu2f(sv.w >> 16)     + FP8_DEC(hv.y, 3) + bbv.w;
        uint2 o;
        o.x = fp8_pk(v0, v1) | (fp8_pk(v2, v3) << 16);
        o.y = fp8_pk(v4, v5) | (fp8_pk(v6, v7) << 16);
        *(uint2*)(hn + e * HID + c8) = o;
    }
}

// K5: node_attr[n] = relu(concat(x[n], vmsg[n]) @ W3 + b3)  (bf16 out)
// K staged in two halves (160 + 128) through a 64x168 LDS buffer.
__global__ __launch_bounds__(256) void k_node_mfma(const float* __restrict__ x,
                                                   const u16* __restrict__ vmsg,
                                                   const u16* __restrict__ WT3,
                                                   const float* __restrict__ b3,
                                                   u16* __restrict__ node_attr) {
    __shared__ u16 A[MT * K3H_STRIDE];  // 21504 B
    const int n0 = blockIdx.x * MT;
    const int t = threadIdx.x;
    const int lane = t & 63, wv = t >> 6;
    const int wm = wv & 1, wn = wv >> 1;
    const int lr = lane & 15, lk = (lane >> 4) * 8;
    f32x4 acc[2][4];
#pragma unroll
    for (int m = 0; m < 2; m++)
#pragma unroll
        for (int n = 0; n < 4; n++) acc[m][n] = (f32x4){0.f, 0.f, 0.f, 0.f};
    const int ar0 = (wm * 32 + lr) * K3H_STRIDE + lk;

#pragma unroll
    for (int half = 0; half < 2; half++) {
        // build this half's 160(/128)-wide K slice
        for (int rr = 0; rr < 16; rr++) {
            const int row = wv * 16 + rr;
            const int n = n0 + row;
            u16* dstr = &A[row * K3H_STRIDE];
            if (half == 0) {
                const float* xr = x + (size_t)n * NODE_IN;
                const u16* vr = vmsg + (size_t)n * HID;
                dstr[lane] = f2bu(xr[lane]);             // k 0..63
                dstr[64 + lane] = f2bu(xr[64 + lane]);   // k 64..127
                if (lane < 32) {                         // k 128..159
                    const int kg = 128 + lane;
                    dstr[128 + lane] = (kg < NODE_IN) ? f2bu(xr[kg])
                                                      : vr[kg - NODE_IN];
                }
            } else {
                const u16* vr = vmsg + (size_t)n * HID;
                dstr[lane] = vr[27 + lane];              // k 160..223 -> vmsg 27..90
                dstr[64 + lane] = (91 + lane < HID) ? vr[91 + lane] : (u16)0;
            }
        }
        __syncthreads();
        const int steps = half ? (K3_PAD - K1_PAD) / 32 : K1_PAD / 32;  // 4 : 5
        for (int ks = 0; ks < steps; ks++) {
            const int kk = ks * 32;
            const bf16x8 a0 = *(const bf16x8*)&A[ar0 + kk];
            const bf16x8 a1 = *(const bf16x8*)&A[ar0 + 16 * K3H_STRIDE + kk];
            const int kwt = half * K1_PAD + kk;
#pragma unroll
            for (int n = 0; n < 4; n++) {
                const bf16x8 b = *(const bf16x8*)&WT3[(size_t)(wn * 64 + n * 16 + lr) * K3_STRIDE + kwt + lk];
                acc[0][n] = __builtin_amdgcn_mfma_f32_16x16x32_bf16(a0, b, acc[0][n], 0, 0, 0);
                acc[1][n] = __builtin_amdgcn_mfma_f32_16x16x32_bf16(a1, b, acc[1][n], 0, 0, 0);
            }
        }
        __syncthreads();
    }

    const int lr4 = lane >> 4;
#pragma unroll
    for (int n = 0; n < 4; n++) {
        const int col = wn * 64 + n * 16 + lr;
        const float bias = b3[col];
#pragma unroll
        for (int m = 0; m < 2; m++)
#pragma unroll
            for (int j = 0; j < 4; j++) {
                const int nd = n0 + wm * 32 + m * 16 + lr4 * 4 + j;
                float v = acc[m][n][j] + bias;
                node_attr[(size_t)nd * HID + col] = f2bu(v > 0.f ? v : 0.f);
            }
    }
}

// ---------------------------------------------------------------------------
// K6: out[g] = mean over the graph's contiguous node range (bf16 node_attr).
// ---------------------------------------------------------------------------
__global__ __launch_bounds__(128) void k_pool2(const u16* __restrict__ node_attr,
                                               const int* __restrict__ batch,
                                               float* __restrict__ out) {
    const int g = blockIdx.x;
    __shared__ int lo_s, hi_s;
    if (threadIdx.x == 0) {
        int lo = 0, hi = N_NODES;
        while (lo < hi) { int mid = (lo + hi) >> 1; if (batch[mid] < g) lo = mid + 1; else hi = mid; }
        lo_s = lo;
        int lo2 = lo, hi2 = N_NODES;
        while (lo2 < hi2) { int mid = (lo2 + hi2) >> 1; if (batch[mid] <= g) lo2 = mid + 1; else hi2 = mid; }
        hi_s = lo2;
    }
    __syncthreads();
    const int lo = lo_s, hi = hi_s;
    float acc = 0.f;
    for (int n = lo; n < hi; n++)
        acc += bu2f(node_attr[(size_t)n * HID + threadIdx.x]);
    const float cnt = (hi > lo) ? (float)(hi - lo) : 1.f;
    out[(size_t)g * HID + threadIdx.x] = acc / cnt;
}

// ---------------------------------------------------------------------------
extern "C" void kernel_launch(void* const* d_in, const int* in_sizes, int n_in,
                              void* d_out, int out_size, void* d_ws, size_t ws_size,
                              hipStream_t stream) {
    const float* x   = (const float*)d_in[0];
    const float* ea  = (const float*)d_in[1];
    const float* W1  = (const float*)d_in[2];
    const float* b1  = (const float*)d_in[3];
    const float* W2  = (const float*)d_in[4];
    const float* b2  = (const float*)d_in[5];
    const float* W3  = (const float*)d_in[6];
    const float* b3  = (const float*)d_in[7];
    const int*   ei  = (const int*)d_in[8];
    const int*   src = ei;
    const int*   dst = ei + N_EDGES;
    const int*   rev = (const int*)d_in[9];
    const int*   bat = (const int*)d_in[10];

    char* ws = (char*)d_ws;
    size_t off = 0;
    auto alloc = [&](size_t bytes) -> void* {
        void* p = ws + off;
        off += (bytes + 255) & ~(size_t)255;
        return p;
    };
    const size_t hbytes = (size_t)N_EDGES * HID;                 // 102.4 MB fp8
    u8* h0 = (u8*)alloc(hbytes);
    u8* hA = (u8*)alloc(hbytes);
    u8* hB = (u8*)alloc(hbytes);
    u16* node_sum = (u16*)alloc((size_t)N_NODES * HID * sizeof(u16));  // 51.2 MB
    int* row_ptr = (int*)alloc((size_t)(N_NODES + 1) * sizeof(int));
    int* eidx = (int*)alloc((size_t)N_EDGES * sizeof(int));
    int* src_d = (int*)alloc((size_t)N_EDGES * sizeof(int));
    int* rev_d = (int*)alloc((size_t)N_EDGES * sizeof(int));
    u16* ea_d = (u16*)alloc((size_t)N_EDGES * 16 * sizeof(u16));  // 25.6 MB
    u16* WT1 = (u16*)alloc((size_t)HID * K1_STRIDE * sizeof(u16));
    u16* WT2 = (u16*)alloc((size_t)HID * K2_STRIDE * sizeof(u16));
    u16* WT3 = (u16*)alloc((size_t)HID * K3_STRIDE * sizeof(u16));
    // Aliases:
    //  - xw (bf16, 51.2 MB) lives in hA: dead before the first k_msg writes hA.
    //  - node_attr (bf16, 51.2 MB) lives in h0: dead after last k_msg read.
    u16* xw = (u16*)hA;
    u16* node_attr = (u16*)h0;
    // total ~395 MB < proven ws floor of ~415.7 MB (round-3 fp8_csr tier ran)

    if (ws_size < off) return;  // diagnostic: leave d_out untouched

    // weight transpose+pad to bf16
    k_prep<<<(HID * K1_STRIDE + 255) / 256, 256, 0, stream>>>(W1, WT1, NODE_IN + EDGE_IN, K1_STRIDE);
    k_prep<<<(HID * K2_STRIDE + 255) / 256, 256, 0, stream>>>(W2, WT2, HID, K2_STRIDE);
    k_prep<<<(HID * K3_STRIDE + 255) / 256, 256, 0, stream>>>(W3, WT3, NODE_IN + HID, K3_STRIDE);

    // CSR build + dst-sorted relabeling (transients overlay node_sum)
    {
        int* cnt = (int*)node_sum;
        int* local = cnt + N_NODES;
        int* cursor = local + N_NODES;
        int* partial = cursor + N_NODES;
        int* inv = partial + 4096;
        hipMemsetAsync(cnt, 0, (size_t)N_NODES * sizeof(int), stream);
        k_hist<<<(N_EDGES + 255) / 256, 256, 0, stream>>>(dst, cnt);
        k_scan1<<<SCAN_NBLK, 256, 0, stream>>>(cnt, local, partial);
        k_scan2<<<1, 256, 0, stream>>>(partial);
        k_scan3<<<(N_NODES + 256) / 256, 256, 0, stream>>>(local, partial, row_ptr, cursor);
        k_place<<<(N_EDGES + 255) / 256, 256, 0, stream>>>(dst, cursor, eidx);
        k_inv<<<(N_EDGES + 255) / 256, 256, 0, stream>>>(eidx, inv);
        k_remap<<<(N_EDGES + 255) / 256, 256, 0, stream>>>(eidx, src, rev, inv, src_d, rev_d);
        k_ea<<<(N_EDGES + 255) / 256, 256, 0, stream>>>(eidx, ea, ea_d);
    }

    // h0 = relu(x[src]@W1x + ea@W1e + b1)
    k_xw<<<N_NODES / MT, 256, 0, stream>>>(x, WT1, xw);
    k_init3<<<N_EDGES / MT, 256, 0, stream>>>(xw, ea_d, W1, b1, src_d, h0);

    const u8* h = h0;
    u8* bufs[2] = {hA, hB};
    const int agg_blocks = (int)(((long long)N_NODES * 16 + 255) / 256);
    for (int it = 0; it < 3; it++) {
        k_gather<<<agg_blocks, 256, 0, stream>>>(h, row_ptr, node_sum);
        u8* hn = bufs[it & 1];   // it=0 writes hA (xw already consumed)
        k_msg_mfma<<<N_EDGES / MT, 256, 0, stream>>>(node_sum, h, h0, WT2, b2, src_d, rev_d, hn);
        h = hn;
    }
    k_gather<<<agg_blocks, 256, 0, stream>>>(h, row_ptr, node_sum);

    // h0 is dead from here; node_attr (bf16) reuses its storage.
    k_node_mfma<<<N_NODES / MT, 256, 0, stream>>>(x, node_sum, WT3, b3, node_attr);
    k_pool2<<<NUM_GRAPHS, 128, 0, stream>>>(node_attr, bat, (float*)d_out);
}

// Round 15
// 957.169 us; speedup vs baseline: 1.8055x; 1.0215x over previous
//
#include <hip/hip_runtime.h>

#define N_NODES 200000
#define N_EDGES 800000
#define NODE_IN 133
#define EDGE_IN 14
#define HID 128
#define NUM_GRAPHS 4096

#define SCAN_CHUNK 2048
#define SCAN_NBLK ((N_NODES + SCAN_CHUNK - 1) / SCAN_CHUNK)  // 98

#define MT 64  // M tile rows per block for MFMA GEMMs

// K geometry per GEMM (padded K, LDS/WT row stride in elements)
#define K1_PAD 160
#define K1_STRIDE 168
#define K2_PAD 128
#define K2_STRIDE 136
#define K3_PAD 288
#define K3_STRIDE 296    // WT3 global row stride
#define K3H_STRIDE 168   // k_node per-half LDS staging stride (160 used)
#define KE_PAD 32        // k_init3 ea K (14 used, zero-padded)
#define KE_STRIDE 40

typedef unsigned short u16;
typedef unsigned char u8;
typedef short bf16x8 __attribute__((ext_vector_type(8)));
typedef float f32x4 __attribute__((ext_vector_type(4)));

__device__ __forceinline__ float bu2f(unsigned s) {
    return __uint_as_float(s << 16);
}
__device__ __forceinline__ u16 f2bu(float f) {
    unsigned u = __float_as_uint(f);
    return (u16)((u + 0x7FFFu + ((u >> 16) & 1u)) >> 16);  // RNE
}
// ---------------- fp8 e4m3 (OCP), non-negative post-ReLU values -----------
__device__ __forceinline__ float e42f(unsigned b) {
    unsigned E = (b >> 4) & 0xF, M = b & 7u;
    if (E == 0) return (float)M * 0.001953125f;  // M * 2^-9
    return __uint_as_float(((E - 7u + 127u) << 23) | (M << 20));
}
__device__ __forceinline__ u8 f2e4(float f) {
    if (!(f > 0.f)) return 0;
    if (f >= 448.f) return 0x7E;
    unsigned u = __float_as_uint(f);
    int e = (int)((u >> 23) & 0xFF) - 127;
    if (e < -6) {
        int q = (int)rintf(f * 512.f);
        return (u8)q;
    }
    unsigned m = u & 0x7FFFFF;
    unsigned keep = m >> 20, rem = m & 0xFFFFF;
    keep += (rem > 0x80000u || (rem == 0x80000u && (keep & 1u))) ? 1u : 0u;
    unsigned E = (unsigned)(e + 7);
    if (keep == 8u) { keep = 0u; E++; }
    return (u8)((E << 4) | keep);
}

// ---------------- HW fp8 convert (gfx950 OCP) with software fallback -------
#if defined(__has_builtin)
#if __has_builtin(__builtin_amdgcn_cvt_f32_fp8) && __has_builtin(__builtin_amdgcn_cvt_pk_fp8_f32)
#define HW_FP8 1
#endif
#endif

#if defined(HW_FP8)
// sel must be a compile-time constant
#define FP8_DEC(dw, s) __builtin_amdgcn_cvt_f32_fp8((int)(dw), (s))
__device__ __forceinline__ unsigned fp8_pk(float a, float b) {
    a = fminf(fmaxf(a, 0.f), 448.f);  // ReLU + sat (matches sw path)
    b = fminf(fmaxf(b, 0.f), 448.f);
    return (unsigned)__builtin_amdgcn_cvt_pk_fp8_f32(a, b, 0, false) & 0xFFFFu;
}
#else
#define FP8_DEC(dw, s) e42f(((dw) >> (8 * (s))) & 0xFFu)
__device__ __forceinline__ unsigned fp8_pk(float a, float b) {
    return (unsigned)f2e4(a) | ((unsigned)f2e4(b) << 8);
}
#endif

__device__ __forceinline__ int clampi(int v, int hi) {
    return v < 0 ? 0 : (v >= hi ? hi - 1 : v);
}

__device__ __forceinline__ void acc16(float* a, const uint4 v) {
    a[0]  += FP8_DEC(v.x, 0); a[1]  += FP8_DEC(v.x, 1);
    a[2]  += FP8_DEC(v.x, 2); a[3]  += FP8_DEC(v.x, 3);
    a[4]  += FP8_DEC(v.y, 0); a[5]  += FP8_DEC(v.y, 1);
    a[6]  += FP8_DEC(v.y, 2); a[7]  += FP8_DEC(v.y, 3);
    a[8]  += FP8_DEC(v.z, 0); a[9]  += FP8_DEC(v.z, 1);
    a[10] += FP8_DEC(v.z, 2); a[11] += FP8_DEC(v.z, 3);
    a[12] += FP8_DEC(v.w, 0); a[13] += FP8_DEC(v.w, 1);
    a[14] += FP8_DEC(v.w, 2); a[15] += FP8_DEC(v.w, 3);
}

// ---------------------------------------------------------------------------
// Weight prep: WT[n][k] = bf16(W[k][n]), k < K else 0.
// ---------------------------------------------------------------------------
__global__ __launch_bounds__(256) void k_prep(const float* __restrict__ W,
                                              u16* __restrict__ WT, int K,
                                              int stride) {
    const int idx = blockIdx.x * 256 + threadIdx.x;
    if (idx >= HID * stride) return;
    const int n = idx / stride, k = idx % stride;
    WT[idx] = (k < K) ? f2bu(W[k * HID + n]) : (u16)0;
}

// ---------------------------------------------------------------------------
// CSR build: histogram -> exclusive scan -> atomic-cursor placement.
// Edge state space is RELABELED into dst-sorted order: j <-> eidx[j].
// ---------------------------------------------------------------------------
__global__ __launch_bounds__(256) void k_hist(const int* __restrict__ dst,
                                              int* __restrict__ cnt) {
    const int e = blockIdx.x * 256 + threadIdx.x;
    if (e < N_EDGES) atomicAdd(&cnt[clampi(dst[e], N_NODES)], 1);
}

__global__ __launch_bounds__(256) void k_scan1(const int* __restrict__ cnt,
                                               int* __restrict__ local,
                                               int* __restrict__ partial) {
    __shared__ int tsum[256];
    const int b = blockIdx.x, t = threadIdx.x;
    const int base = b * SCAN_CHUNK + t * 8;
    int v[8];
    int s = 0;
#pragma unroll
    for (int i = 0; i < 8; i++) {
        const int idx = base + i;
        v[i] = (idx < N_NODES) ? cnt[idx] : 0;
        s += v[i];
    }
    tsum[t] = s;
    __syncthreads();
    for (int ofs = 1; ofs < 256; ofs <<= 1) {
        const int add = (t >= ofs) ? tsum[t - ofs] : 0;
        __syncthreads();
        tsum[t] += add;
        __syncthreads();
    }
    int excl = (t == 0) ? 0 : tsum[t - 1];
    if (t == 255) partial[b] = tsum[255];
#pragma unroll
    for (int i = 0; i < 8; i++) {
        const int idx = base + i;
        if (idx < N_NODES) local[idx] = excl;
        excl += v[i];
    }
}

__global__ __launch_bounds__(256) void k_scan2(int* __restrict__ partial) {
    __shared__ int s[256];
    const int t = threadIdx.x;
    s[t] = (t < SCAN_NBLK) ? partial[t] : 0;
    __syncthreads();
    for (int ofs = 1; ofs < 256; ofs <<= 1) {
        const int add = (t >= ofs) ? s[t - ofs] : 0;
        __syncthreads();
        s[t] += add;
        __syncthreads();
    }
    if (t < SCAN_NBLK) partial[t] = (t == 0) ? 0 : s[t - 1];
}

__global__ __launch_bounds__(256) void k_scan3(const int* __restrict__ local,
                                               const int* __restrict__ partial,
                                               int* __restrict__ row_ptr,
                                               int* __restrict__ cursor) {
    const int idx = blockIdx.x * 256 + threadIdx.x;
    if (idx <= N_NODES) {
        const int v = (idx == N_NODES) ? N_EDGES
                                       : local[idx] + partial[idx / SCAN_CHUNK];
        row_ptr[idx] = v;
        if (idx < N_NODES) cursor[idx] = v;
    }
}

// placement + inverse permutation in one pass
__global__ __launch_bounds__(256) void k_place(const int* __restrict__ dst,
                                               int* __restrict__ cursor,
                                               int* __restrict__ eidx,
                                               int* __restrict__ inv) {
    const int e = blockIdx.x * 256 + threadIdx.x;
    if (e < N_EDGES) {
        const int slot = atomicAdd(&cursor[clampi(dst[e], N_NODES)], 1);
        eidx[slot] = e;
        inv[e] = slot;
    }
}

// merged remap + ea pack: one eidx read per sorted edge
__global__ __launch_bounds__(256) void k_setup(const int* __restrict__ eidx,
                                               const int* __restrict__ src,
                                               const int* __restrict__ rev,
                                               const int* __restrict__ inv,
                                               const float* __restrict__ ea,
                                               int* __restrict__ src_d,
                                               int* __restrict__ rev_d,
                                               u16* __restrict__ ea_d) {
    const int j = blockIdx.x * 256 + threadIdx.x;
    if (j >= N_EDGES) return;
    const int e = clampi(eidx[j], N_EDGES);
    src_d[j] = src[e];
    rev_d[j] = inv[clampi(rev[e], N_EDGES)];
    const float2* er = (const float2*)(ea + (size_t)e * EDGE_IN);
    u16 v[16];
#pragma unroll
    for (int k = 0; k < 7; k++) {
        const float2 u = er[k];
        v[2 * k] = f2bu(u.x);
        v[2 * k + 1] = f2bu(u.y);
    }
    v[14] = 0; v[15] = 0;
    uint4 o1, o2;
    o1.x = (unsigned)v[0] | ((unsigned)v[1] << 16);
    o1.y = (unsigned)v[2] | ((unsigned)v[3] << 16);
    o1.z = (unsigned)v[4] | ((unsigned)v[5] << 16);
    o1.w = (unsigned)v[6] | ((unsigned)v[7] << 16);
    o2.x = (unsigned)v[8] | ((unsigned)v[9] << 16);
    o2.y = (unsigned)v[10] | ((unsigned)v[11] << 16);
    o2.z = (unsigned)v[12] | ((unsigned)v[13] << 16);
    o2.w = 0;
    uint4* dstp = (uint4*)(ea_d + (size_t)j * 16);
    dstp[0] = o1;
    dstp[1] = o2;
}

// ---------------------------------------------------------------------------
// K2 (streaming gather): node_sum[n] = sum over contiguous sorted rows.
// 8 threads/node, 16 channels each (uint4 loads), 4-deep unrolled deg loop.
// ---------------------------------------------------------------------------
__global__ __launch_bounds__(256) void k_gather(const u8* __restrict__ h,
                                                const int* __restrict__ row_ptr,
                                                u16* __restrict__ node_sum) {
    const long long idx = (long long)blockIdx.x * 256 + threadIdx.x;
    const int n = (int)(idx >> 3);
    if (n >= N_NODES) return;
    const int c16 = (int)(idx & 7) << 4;
    const int beg = row_ptr[n], end = row_ptr[n + 1];
    float a[16];
#pragma unroll
    for (int i = 0; i < 16; i++) a[i] = 0.f;
    int j = beg;
    for (; j + 4 <= end; j += 4) {
        const uint4 v0 = *(const uint4*)(h + (long long)j * HID + c16);
        const uint4 v1 = *(const uint4*)(h + (long long)(j + 1) * HID + c16);
        const uint4 v2 = *(const uint4*)(h + (long long)(j + 2) * HID + c16);
        const uint4 v3 = *(const uint4*)(h + (long long)(j + 3) * HID + c16);
        acc16(a, v0); acc16(a, v1); acc16(a, v2); acc16(a, v3);
    }
    for (; j < end; j++) {
        const uint4 v = *(const uint4*)(h + (long long)j * HID + c16);
        acc16(a, v);
    }
    uint4 o1, o2;
    o1.x = (unsigned)f2bu(a[0])  | ((unsigned)f2bu(a[1])  << 16);
    o1.y = (unsigned)f2bu(a[2])  | ((unsigned)f2bu(a[3])  << 16);
    o1.z = (unsigned)f2bu(a[4])  | ((unsigned)f2bu(a[5])  << 16);
    o1.w = (unsigned)f2bu(a[6])  | ((unsigned)f2bu(a[7])  << 16);
    o2.x = (unsigned)f2bu(a[8])  | ((unsigned)f2bu(a[9])  << 16);
    o2.y = (unsigned)f2bu(a[10]) | ((unsigned)f2bu(a[11]) << 16);
    o2.z = (unsigned)f2bu(a[12]) | ((unsigned)f2bu(a[13]) << 16);
    o2.w = (unsigned)f2bu(a[14]) | ((unsigned)f2bu(a[15]) << 16);
    uint4* outp = (uint4*)(node_sum + (long long)n * HID + c16);
    outp[0] = o1;
    outp[1] = o2;
}

// ---------------------------------------------------------------------------
// MFMA geometry (64x128 tile, 4 waves: 2 in M x 2 in N)
// a-frag: lane holds A[lane&15][(lane>>4)*8 + i]; b-frag from [n][k] layout.
// C/D: col = lane&15, row = (lane>>4)*4 + reg.
// ---------------------------------------------------------------------------

// K1a: xw[n] = x[n] @ W1x  (per-NODE GEMM; A cols 133..159 zeroed)
__global__ __launch_bounds__(256) void k_xw(const float* __restrict__ x,
                                            const u16* __restrict__ WT1,
                                            u16* __restrict__ xw) {
    __shared__ u16 A[MT * K1_STRIDE];
    const int n0 = blockIdx.x * MT;
    const int t = threadIdx.x;
    const int lane = t & 63, wv = t >> 6;
    for (int rr = 0; rr < 16; rr++) {
        const int row = wv * 16 + rr;
        const int n = n0 + row;
        const float* xr = x + (size_t)n * NODE_IN;
        u16* dstr = &A[row * K1_STRIDE];
        dstr[lane] = f2bu(xr[lane]);                 // k 0..63
        dstr[64 + lane] = f2bu(xr[64 + lane]);       // k 64..127
        if (lane < 5) dstr[128 + lane] = f2bu(xr[128 + lane]);  // 128..132
        if (lane < K1_PAD - NODE_IN) dstr[NODE_IN + lane] = 0;  // 133..159
    }
    __syncthreads();

    const int wm = wv & 1, wn = wv >> 1;
    const int lr = lane & 15, lk = (lane >> 4) * 8;
    f32x4 acc[2][4];
#pragma unroll
    for (int m = 0; m < 2; m++)
#pragma unroll
        for (int n = 0; n < 4; n++) acc[m][n] = (f32x4){0.f, 0.f, 0.f, 0.f};

    const int ar0 = (wm * 32 + lr) * K1_STRIDE + lk;
#pragma unroll
    for (int ks = 0; ks < K1_PAD / 32; ks++) {
        const int kk = ks * 32;
        const bf16x8 a0 = *(const bf16x8*)&A[ar0 + kk];
        const bf16x8 a1 = *(const bf16x8*)&A[ar0 + 16 * K1_STRIDE + kk];
#pragma unroll
        for (int n = 0; n < 4; n++) {
            const bf16x8 b = *(const bf16x8*)&WT1[(size_t)(wn * 64 + n * 16 + lr) * K1_STRIDE + kk + lk];
            acc[0][n] = __builtin_amdgcn_mfma_f32_16x16x32_bf16(a0, b, acc[0][n], 0, 0, 0);
            acc[1][n] = __builtin_amdgcn_mfma_f32_16x16x32_bf16(a1, b, acc[1][n], 0, 0, 0);
        }
    }

    const int lr4 = lane >> 4;
#pragma unroll
    for (int n = 0; n < 4; n++) {
        const int col = wn * 64 + n * 16 + lr;
#pragma unroll
        for (int m = 0; m < 2; m++)
#pragma unroll
            for (int j = 0; j < 4; j++) {
                const int nd = n0 + wm * 32 + m * 16 + lr4 * 4 + j;
                xw[(size_t)nd * HID + col] = f2bu(acc[m][n][j]);
            }
    }
}

// K1b (MFMA): h0[j] = relu(xw[src_d[j]] + ea_d[j]@W1e + b1) -> fp8.
// ea matvec on the matrix pipe; xw row PREFETCHED into registers at start.
__global__ __launch_bounds__(256) void k_init3(const u16* __restrict__ xw,
                                               const u16* __restrict__ ea_d,
                                               const float* __restrict__ W1,
                                               const float* __restrict__ b1,
                                               const int* __restrict__ src_d,
                                               u8* __restrict__ h0) {
    __shared__ u16 Aea[MT * KE_STRIDE];       // 5120 B
    __shared__ u16 W1e[HID * KE_PAD];         // [n][k], 8192 B
    __shared__ u16 Sacc[MT * K2_STRIDE];      // 17408 B staging
    __shared__ float b1s[HID];
    const int e0 = blockIdx.x * MT;
    const int t = threadIdx.x;

    // prefetch phase-2 operands (consumed after 2 barriers)
    const int prow = t >> 2, pj = t & 3;
    const int ps = clampi(src_d[e0 + prow], N_NODES);
    uint4 xv[4];
#pragma unroll
    for (int q = 0; q < 4; q++)
        xv[q] = *(const uint4*)(xw + (size_t)ps * HID + pj * 32 + q * 8);

    for (int i = t; i < HID * KE_PAD; i += 256) {
        const int n = i >> 5, k = i & 31;
        W1e[i] = (k < EDGE_IN) ? f2bu(W1[(NODE_IN + k) * HID + n]) : (u16)0;
    }
    if (t < HID) b1s[t] = b1[t];
    {   // ea tile: 4 threads/row, 8B each; pad 16..31 zeroed
        const int row = t >> 2, q = t & 3;
        const uint2 v = *(const uint2*)(ea_d + (size_t)(e0 + row) * 16 + q * 4);
        *(uint2*)&Aea[row * KE_STRIDE + q * 4] = v;
        uint2 z; z.x = 0; z.y = 0;
        *(uint2*)&Aea[row * KE_STRIDE + 16 + q * 4] = z;
    }
    __syncthreads();

    const int lane = t & 63, wid = t >> 6;
    const int wm = wid & 1, wn = wid >> 1;
    const int lr = lane & 15, lk = (lane >> 4) * 8;
    f32x4 acc[2][4];
#pragma unroll
    for (int m = 0; m < 2; m++)
#pragma unroll
        for (int n = 0; n < 4; n++) acc[m][n] = (f32x4){0.f, 0.f, 0.f, 0.f};

    {
        const bf16x8 a0 = *(const bf16x8*)&Aea[(wm * 32 + lr) * KE_STRIDE + lk];
        const bf16x8 a1 = *(const bf16x8*)&Aea[(wm * 32 + 16 + lr) * KE_STRIDE + lk];
#pragma unroll
        for (int n = 0; n < 4; n++) {
            const bf16x8 b = *(const bf16x8*)&W1e[(wn * 64 + n * 16 + lr) * KE_PAD + lk];
            acc[0][n] = __builtin_amdgcn_mfma_f32_16x16x32_bf16(a0, b, acc[0][n], 0, 0, 0);
            acc[1][n] = __builtin_amdgcn_mfma_f32_16x16x32_bf16(a1, b, acc[1][n], 0, 0, 0);
        }
    }

    // stage product bf16 -> Sacc[row][col]
    const int lr4 = lane >> 4;
#pragma unroll
    for (int n = 0; n < 4; n++) {
        const int col = wn * 64 + n * 16 + lr;
#pragma unroll
        for (int m = 0; m < 2; m++)
#pragma unroll
            for (int j = 0; j < 4; j++) {
                const int row = wm * 32 + m * 16 + lr4 * 4 + j;
                Sacc[row * K2_STRIDE + col] = f2bu(acc[m][n][j]);
            }
    }
    __syncthreads();

    // phase 2: coalesced, thread = (row, 32-ch chunk)
    const long long e = e0 + prow;
#pragma unroll
    for (int q = 0; q < 4; q++) {
        const int c8 = pj * 32 + q * 8;
        const uint4 sv = *(const uint4*)&Sacc[prow * K2_STRIDE + c8];  // 8 bf16
        const float4 ba = *(const float4*)&b1s[c8];
        const float4 bbv = *(const float4*)&b1s[c8 + 4];
        const float v0 = bu2f(sv.x & 0xFFFFu) + bu2f(xv[q].x & 0xFFFFu) + ba.x;
        const float v1 = bu2f(sv.x >> 16)     + bu2f(xv[q].x >> 16)     + ba.y;
        const float v2 = bu2f(sv.y & 0xFFFFu) + bu2f(xv[q].y & 0xFFFFu) + ba.z;
        const float v3 = bu2f(sv.y >> 16)     + bu2f(xv[q].y >> 16)     + ba.w;
        const float v4 = bu2f(sv.z & 0xFFFFu) + bu2f(xv[q].z & 0xFFFFu) + bbv.x;
        const float v5 = bu2f(sv.z >> 16)     + bu2f(xv[q].z >> 16)     + bbv.y;
        const float v6 = bu2f(sv.w & 0xFFFFu) + bu2f(xv[q].w & 0xFFFFu) + bbv.z;
        const float v7 = bu2f(sv.w >> 16)     + bu2f(xv[q].w >> 16)     + bbv.w;
        uint2 o;
        o.x = fp8_pk(v0, v1) | (fp8_pk(v2, v3) << 16);
        o.y = fp8_pk(v4, v5) | (fp8_pk(v6, v7) << 16);
        *(uint2*)(h0 + e * HID + c8) = o;
    }
}

// K3: hn[j] = relu(h0[j] + (node_sum[src_d[j]] - h[rev_d[j]]) @ W2 + b2)
// h0 row PREFETCHED into registers at kernel start.
__global__ __launch_bounds__(256) void k_msg_mfma(const u16* __restrict__ ns,
                                                  const u8* __restrict__ h,
                                                  const u8* __restrict__ h0g,
                                                  const u16* __restrict__ WT2,
                                                  const float* __restrict__ b2,
                                                  const int* __restrict__ src_d,
                                                  const int* __restrict__ rev_d,
                                                  u8* __restrict__ hn) {
    __shared__ u16 A[MT * K2_STRIDE];
    __shared__ float b2s[HID];
    const int e0 = blockIdx.x * MT;
    const int t = threadIdx.x;

    // prefetch phase-2 h0 row chunks (stream; consumed after 2 barriers)
    const int prow = t >> 2, pj = t & 3;
    const long long pe = e0 + prow;
    uint2 h0v[4];
#pragma unroll
    for (int q = 0; q < 4; q++)
        h0v[q] = *(const uint2*)(h0g + pe * HID + pj * 32 + q * 8);

    if (t < HID) b2s[t] = b2[t];
    {   // builder: 4 threads/row, 32 channels each
        const int le = t >> 2, j = t & 3;
        const int e = e0 + le;
        const int s = clampi(src_d[e], N_NODES);
        const int r = clampi(rev_d[e], N_EDGES);
        const u16* nsr = ns + (size_t)s * HID + j * 32;
        const u8* hr = h + (size_t)r * HID + j * 32;
        u16* dstr = &A[le * K2_STRIDE + j * 32];
#pragma unroll
        for (int q = 0; q < 4; q++) {
            const uint4 nv = *(const uint4*)(nsr + q * 8);  // 8 bf16
            const uint2 hv = *(const uint2*)(hr + q * 8);   // 8 fp8
            union { bf16x8 v; u16 s[8]; } o;
            o.s[0] = f2bu(bu2f(nv.x & 0xFFFFu) - FP8_DEC(hv.x, 0));
            o.s[1] = f2bu(bu2f(nv.x >> 16)     - FP8_DEC(hv.x, 1));
            o.s[2] = f2bu(bu2f(nv.y & 0xFFFFu) - FP8_DEC(hv.x, 2));
            o.s[3] = f2bu(bu2f(nv.y >> 16)     - FP8_DEC(hv.x, 3));
            o.s[4] = f2bu(bu2f(nv.z & 0xFFFFu) - FP8_DEC(hv.y, 0));
            o.s[5] = f2bu(bu2f(nv.z >> 16)     - FP8_DEC(hv.y, 1));
            o.s[6] = f2bu(bu2f(nv.w & 0xFFFFu) - FP8_DEC(hv.y, 2));
            o.s[7] = f2bu(bu2f(nv.w >> 16)     - FP8_DEC(hv.y, 3));
            *(bf16x8*)(dstr + q * 8) = o.v;
        }
    }
    __syncthreads();

    const int lane = t & 63, wid = t >> 6;
    const int wm = wid & 1, wn = wid >> 1;
    const int lr = lane & 15, lk = (lane >> 4) * 8;
    f32x4 acc[2][4];
#pragma unroll
    for (int m = 0; m < 2; m++)
#pragma unroll
        for (int n = 0; n < 4; n++) acc[m][n] = (f32x4){0.f, 0.f, 0.f, 0.f};

    const int ar0 = (wm * 32 + lr) * K2_STRIDE + lk;
#pragma unroll
    for (int ks = 0; ks < K2_PAD / 32; ks++) {
        const int kk = ks * 32;
        const bf16x8 a0 = *(const bf16x8*)&A[ar0 + kk];
        const bf16x8 a1 = *(const bf16x8*)&A[ar0 + 16 * K2_STRIDE + kk];
#pragma unroll
        for (int n = 0; n < 4; n++) {
            const bf16x8 b = *(const bf16x8*)&WT2[(size_t)(wn * 64 + n * 16 + lr) * K2_STRIDE + kk + lk];
            acc[0][n] = __builtin_amdgcn_mfma_f32_16x16x32_bf16(a0, b, acc[0][n], 0, 0, 0);
            acc[1][n] = __builtin_amdgcn_mfma_f32_16x16x32_bf16(a1, b, acc[1][n], 0, 0, 0);
        }
    }

    __syncthreads();  // A's builder data fully consumed
    const int lr4 = lane >> 4;
#pragma unroll
    for (int n = 0; n < 4; n++) {
        const int col = wn * 64 + n * 16 + lr;
#pragma unroll
        for (int m = 0; m < 2; m++)
#pragma unroll
            for (int j = 0; j < 4; j++) {
                const int row = wm * 32 + m * 16 + lr4 * 4 + j;
                A[row * K2_STRIDE + col] = f2bu(acc[m][n][j]);
            }
    }
    __syncthreads();

#pragma unroll
    for (int q = 0; q < 4; q++) {
        const int c8 = pj * 32 + q * 8;
        const uint4 sv = *(const uint4*)&A[prow * K2_STRIDE + c8];  // 8 bf16
        const float4 ba = *(const float4*)&b2s[c8];
        const float4 bbv = *(const float4*)&b2s[c8 + 4];
        const float v0 = bu2f(sv.x & 0xFFFFu) + FP8_DEC(h0v[q].x, 0) + ba.x;
        const float v1 = bu2f(sv.x >> 16)     + FP8_DEC(h0v[q].x, 1) + ba.y;
        const float v2 = bu2f(sv.y & 0xFFFFu) + FP8_DEC(h0v[q].x, 2) + ba.z;
        const float v3 = bu2f(sv.y >> 16)     + FP8_DEC(h0v[q].x, 3) + ba.w;
        const float v4 = bu2f(sv.z & 0xFFFFu) + FP8_DEC(h0v[q].y, 0) + bbv.x;
        const float v5 = bu2f(sv.z >> 16)     + FP8_DEC(h0v[q].y, 1) + bbv.y;
        const float v6 = bu2f(sv.w & 0xFFFFu) + FP8_DEC(h0v[q].y, 2) + bbv.z;
        const float v7 = bu2f(sv.w >> 16)     + FP8_DEC(h0v[q].y, 3) + bbv.w;
        uint2 o;
        o.x = fp8_pk(v0, v1) | (fp8_pk(v2, v3) << 16);
        o.y = fp8_pk(v4, v5) | (fp8_pk(v6, v7) << 16);
        *(uint2*)(hn + pe * HID + c8) = o;
    }
}

// K5: node_attr[n] = relu(concat(x[n], vmsg[n]) @ W3 + b3)  (bf16 out)
// K staged in two halves (160 + 128) through a 64x168 LDS buffer.
__global__ __launch_bounds__(256) void k_node_mfma(const float* __restrict__ x,
                                                   const u16* __restrict__ vmsg,
                                                   const u16* __restrict__ WT3,
                                                   const float* __restrict__ b3,
                                                   u16* __restrict__ node_attr) {
    __shared__ u16 A[MT * K3H_STRIDE];  // 21504 B
    const int n0 = blockIdx.x * MT;
    const int t = threadIdx.x;
    const int lane = t & 63, wv = t >> 6;
    const int wm = wv & 1, wn = wv >> 1;
    const int lr = lane & 15, lk = (lane >> 4) * 8;
    f32x4 acc[2][4];
#pragma unroll
    for (int m = 0; m < 2; m++)
#pragma unroll
        for (int n = 0; n < 4; n++) acc[m][n] = (f32x4){0.f, 0.f, 0.f, 0.f};
    const int ar0 = (wm * 32 + lr) * K3H_STRIDE + lk;

#pragma unroll
    for (int half = 0; half < 2; half++) {
        // build this half's 160(/128)-wide K slice
        for (int rr = 0; rr < 16; rr++) {
            const int row = wv * 16 + rr;
            const int n = n0 + row;
            u16* dstr = &A[row * K3H_STRIDE];
            if (half == 0) {
                const float* xr = x + (size_t)n * NODE_IN;
                const u16* vr = vmsg + (size_t)n * HID;
                dstr[lane] = f2bu(xr[lane]);             // k 0..63
                dstr[64 + lane] = f2bu(xr[64 + lane]);   // k 64..127
                if (lane < 32) {                         // k 128..159
                    const int kg = 128 + lane;
                    dstr[128 + lane] = (kg < NODE_IN) ? f2bu(xr[kg])
                                                      : vr[kg - NODE_IN];
                }
            } else {
                const u16* vr = vmsg + (size_t)n * HID;
                dstr[lane] = vr[27 + lane];              // k 160..223 -> vmsg 27..90
                dstr[64 + lane] = (91 + lane < HID) ? vr[91 + lane] : (u16)0;
            }
        }
        __syncthreads();
        const int steps = half ? (K3_PAD - K1_PAD) / 32 : K1_PAD / 32;  // 4 : 5
        for (int ks = 0; ks < steps; ks++) {
            const int kk = ks * 32;
            const bf16x8 a0 = *(const bf16x8*)&A[ar0 + kk];
            const bf16x8 a1 = *(const bf16x8*)&A[ar0 + 16 * K3H_STRIDE + kk];
            const int kwt = half * K1_PAD + kk;
#pragma unroll
            for (int n = 0; n < 4; n++) {
                const bf16x8 b = *(const bf16x8*)&WT3[(size_t)(wn * 64 + n * 16 + lr) * K3_STRIDE + kwt + lk];
                acc[0][n] = __builtin_amdgcn_mfma_f32_16x16x32_bf16(a0, b, acc[0][n], 0, 0, 0);
                acc[1][n] = __builtin_amdgcn_mfma_f32_16x16x32_bf16(a1, b, acc[1][n], 0, 0, 0);
            }
        }
        __syncthreads();
    }

    const int lr4 = lane >> 4;
#pragma unroll
    for (int n = 0; n < 4; n++) {
        const int col = wn * 64 + n * 16 + lr;
        const float bias = b3[col];
#pragma unroll
        for (int m = 0; m < 2; m++)
#pragma unroll
            for (int j = 0; j < 4; j++) {
                const int nd = n0 + wm * 32 + m * 16 + lr4 * 4 + j;
                float v = acc[m][n][j] + bias;
                node_attr[(size_t)nd * HID + col] = f2bu(v > 0.f ? v : 0.f);
            }
    }
}

// ---------------------------------------------------------------------------
// K6: out[g] = mean over the graph's contiguous node range (bf16 node_attr).
// ---------------------------------------------------------------------------
__global__ __launch_bounds__(128) void k_pool2(const u16* __restrict__ node_attr,
                                               const int* __restrict__ batch,
                                               float* __restrict__ out) {
    const int g = blockIdx.x;
    __shared__ int lo_s, hi_s;
    if (threadIdx.x == 0) {
        int lo = 0, hi = N_NODES;
        while (lo < hi) { int mid = (lo + hi) >> 1; if (batch[mid] < g) lo = mid + 1; else hi = mid; }
        lo_s = lo;
        int lo2 = lo, hi2 = N_NODES;
        while (lo2 < hi2) { int mid = (lo2 + hi2) >> 1; if (batch[mid] <= g) lo2 = mid + 1; else hi2 = mid; }
        hi_s = lo2;
    }
    __syncthreads();
    const int lo = lo_s, hi = hi_s;
    float acc = 0.f;
    for (int n = lo; n < hi; n++)
        acc += bu2f(node_attr[(size_t)n * HID + threadIdx.x]);
    const float cnt = (hi > lo) ? (float)(hi - lo) : 1.f;
    out[(size_t)g * HID + threadIdx.x] = acc / cnt;
}

// ---------------------------------------------------------------------------
extern "C" void kernel_launch(void* const* d_in, const int* in_sizes, int n_in,
                              void* d_out, int out_size, void* d_ws, size_t ws_size,
                              hipStream_t stream) {
    const float* x   = (const float*)d_in[0];
    const float* ea  = (const float*)d_in[1];
    const float* W1  = (const float*)d_in[2];
    const float* b1  = (const float*)d_in[3];
    const float* W2  = (const float*)d_in[4];
    const float* b2  = (const float*)d_in[5];
    const float* W3  = (const float*)d_in[6];
    const float* b3  = (const float*)d_in[7];
    const int*   ei  = (const int*)d_in[8];
    const int*   src = ei;
    const int*   dst = ei + N_EDGES;
    const int*   rev = (const int*)d_in[9];
    const int*   bat = (const int*)d_in[10];

    char* ws = (char*)d_ws;
    size_t off = 0;
    auto alloc = [&](size_t bytes) -> void* {
        void* p = ws + off;
        off += (bytes + 255) & ~(size_t)255;
        return p;
    };
    const size_t hbytes = (size_t)N_EDGES * HID;                 // 102.4 MB fp8
    u8* h0 = (u8*)alloc(hbytes);
    u8* hA = (u8*)alloc(hbytes);
    u8* hB = (u8*)alloc(hbytes);
    u16* node_sum = (u16*)alloc((size_t)N_NODES * HID * sizeof(u16));  // 51.2 MB
    int* row_ptr = (int*)alloc((size_t)(N_NODES + 1) * sizeof(int));
    int* eidx = (int*)alloc((size_t)N_EDGES * sizeof(int));
    int* src_d = (int*)alloc((size_t)N_EDGES * sizeof(int));
    int* rev_d = (int*)alloc((size_t)N_EDGES * sizeof(int));
    u16* ea_d = (u16*)alloc((size_t)N_EDGES * 16 * sizeof(u16));  // 25.6 MB
    u16* WT1 = (u16*)alloc((size_t)HID * K1_STRIDE * sizeof(u16));
    u16* WT2 = (u16*)alloc((size_t)HID * K2_STRIDE * sizeof(u16));
    u16* WT3 = (u16*)alloc((size_t)HID * K3_STRIDE * sizeof(u16));
    // Aliases:
    //  - xw (bf16, 51.2 MB) lives in hA: dead before the first k_msg writes hA.
    //  - node_attr (bf16, 51.2 MB) lives in h0: dead after last k_msg read.
    u16* xw = (u16*)hA;
    u16* node_attr = (u16*)h0;
    // total ~395 MB < proven ws floor of ~415.7 MB (round-3 fp8_csr tier ran)

    if (ws_size < off) return;  // diagnostic: leave d_out untouched

    // weight transpose+pad to bf16
    k_prep<<<(HID * K1_STRIDE + 255) / 256, 256, 0, stream>>>(W1, WT1, NODE_IN + EDGE_IN, K1_STRIDE);
    k_prep<<<(HID * K2_STRIDE + 255) / 256, 256, 0, stream>>>(W2, WT2, HID, K2_STRIDE);
    k_prep<<<(HID * K3_STRIDE + 255) / 256, 256, 0, stream>>>(W3, WT3, NODE_IN + HID, K3_STRIDE);

    // CSR build + dst-sorted relabeling (transients overlay node_sum)
    {
        int* cnt = (int*)node_sum;
        int* local = cnt + N_NODES;
        int* cursor = local + N_NODES;
        int* partial = cursor + N_NODES;
        int* inv = partial + 4096;
        hipMemsetAsync(cnt, 0, (size_t)N_NODES * sizeof(int), stream);
        k_hist<<<(N_EDGES + 255) / 256, 256, 0, stream>>>(dst, cnt);
        k_scan1<<<SCAN_NBLK, 256, 0, stream>>>(cnt, local, partial);
        k_scan2<<<1, 256, 0, stream>>>(partial);
        k_scan3<<<(N_NODES + 256) / 256, 256, 0, stream>>>(local, partial, row_ptr, cursor);
        k_place<<<(N_EDGES + 255) / 256, 256, 0, stream>>>(dst, cursor, eidx, inv);
        k_setup<<<(N_EDGES + 255) / 256, 256, 0, stream>>>(eidx, src, rev, inv, ea, src_d, rev_d, ea_d);
    }

    // h0 = relu(x[src]@W1x + ea@W1e + b1)
    k_xw<<<N_NODES / MT, 256, 0, stream>>>(x, WT1, xw);
    k_init3<<<N_EDGES / MT, 256, 0, stream>>>(xw, ea_d, W1, b1, src_d, h0);

    const u8* h = h0;
    u8* bufs[2] = {hA, hB};
    const int agg_blocks = (int)(((long long)N_NODES * 8 + 255) / 256);
    for (int it = 0; it < 3; it++) {
        k_gather<<<agg_blocks, 256, 0, stream>>>(h, row_ptr, node_sum);
        u8* hn = bufs[it & 1];   // it=0 writes hA (xw already consumed)
        k_msg_mfma<<<N_EDGES / MT, 256, 0, stream>>>(node_sum, h, h0, WT2, b2, src_d, rev_d, hn);
        h = hn;
    }
    k_gather<<<agg_blocks, 256, 0, stream>>>(h, row_ptr, node_sum);

    // h0 is dead from here; node_attr (bf16) reuses its storage.
    k_node_mfma<<<N_NODES / MT, 256, 0, stream>>>(x, node_sum, WT3, b3, node_attr);
    k_pool2<<<NUM_GRAPHS, 128, 0, stream>>>(node_attr, bat, (float*)d_out);
}

// Round 16
// 902.794 us; speedup vs baseline: 1.9143x; 1.0602x over previous
//
#include <hip/hip_runtime.h>

#define N_NODES 200000
#define N_EDGES 800000
#define NODE_IN 133
#define EDGE_IN 14
#define HID 128
#define NUM_GRAPHS 4096

#define SCAN_CHUNK 2048
#define SCAN_NBLK ((N_NODES + SCAN_CHUNK - 1) / SCAN_CHUNK)  // 98

#define MT 64  // M tile rows per block for MFMA GEMMs

// K geometry per GEMM (padded K, LDS/WT row stride in elements)
#define K1_PAD 160
#define K1_STRIDE 168
#define K2_PAD 128
#define K2_STRIDE 136
#define K3_PAD 288
#define K3_STRIDE 296    // WT3 global row stride
#define K3H_STRIDE 168   // k_node per-half LDS staging stride (160 used)
#define KE_PAD 32        // k_init3 ea K (14 used, zero-padded)
#define KE_STRIDE 40

typedef unsigned short u16;
typedef unsigned char u8;
typedef short bf16x8 __attribute__((ext_vector_type(8)));
typedef float f32x4 __attribute__((ext_vector_type(4)));

__device__ __forceinline__ float bu2f(unsigned s) {
    return __uint_as_float(s << 16);
}
__device__ __forceinline__ u16 f2bu(float f) {
    unsigned u = __float_as_uint(f);
    return (u16)((u + 0x7FFFu + ((u >> 16) & 1u)) >> 16);  // RNE
}
// ---------------- fp8 e4m3 (OCP), non-negative post-ReLU values -----------
__device__ __forceinline__ float e42f(unsigned b) {
    unsigned E = (b >> 4) & 0xF, M = b & 7u;
    if (E == 0) return (float)M * 0.001953125f;  // M * 2^-9
    return __uint_as_float(((E - 7u + 127u) << 23) | (M << 20));
}
__device__ __forceinline__ u8 f2e4(float f) {
    if (!(f > 0.f)) return 0;
    if (f >= 448.f) return 0x7E;
    unsigned u = __float_as_uint(f);
    int e = (int)((u >> 23) & 0xFF) - 127;
    if (e < -6) {
        int q = (int)rintf(f * 512.f);
        return (u8)q;
    }
    unsigned m = u & 0x7FFFFF;
    unsigned keep = m >> 20, rem = m & 0xFFFFF;
    keep += (rem > 0x80000u || (rem == 0x80000u && (keep & 1u))) ? 1u : 0u;
    unsigned E = (unsigned)(e + 7);
    if (keep == 8u) { keep = 0u; E++; }
    return (u8)((E << 4) | keep);
}

// ---------------- HW fp8 convert (gfx950 OCP) with software fallback -------
#if defined(__has_builtin)
#if __has_builtin(__builtin_amdgcn_cvt_f32_fp8) && __has_builtin(__builtin_amdgcn_cvt_pk_fp8_f32)
#define HW_FP8 1
#endif
#endif

#if defined(HW_FP8)
// sel must be a compile-time constant
#define FP8_DEC(dw, s) __builtin_amdgcn_cvt_f32_fp8((int)(dw), (s))
__device__ __forceinline__ unsigned fp8_pk(float a, float b) {
    a = fminf(fmaxf(a, 0.f), 448.f);  // ReLU + sat (matches sw path)
    b = fminf(fmaxf(b, 0.f), 448.f);
    return (unsigned)__builtin_amdgcn_cvt_pk_fp8_f32(a, b, 0, false) & 0xFFFFu;
}
#else
#define FP8_DEC(dw, s) e42f(((dw) >> (8 * (s))) & 0xFFu)
__device__ __forceinline__ unsigned fp8_pk(float a, float b) {
    return (unsigned)f2e4(a) | ((unsigned)f2e4(b) << 8);
}
#endif

__device__ __forceinline__ int clampi(int v, int hi) {
    return v < 0 ? 0 : (v >= hi ? hi - 1 : v);
}

__device__ __forceinline__ void acc16(float* a, const uint4 v) {
    a[0]  += FP8_DEC(v.x, 0); a[1]  += FP8_DEC(v.x, 1);
    a[2]  += FP8_DEC(v.x, 2); a[3]  += FP8_DEC(v.x, 3);
    a[4]  += FP8_DEC(v.y, 0); a[5]  += FP8_DEC(v.y, 1);
    a[6]  += FP8_DEC(v.y, 2); a[7]  += FP8_DEC(v.y, 3);
    a[8]  += FP8_DEC(v.z, 0); a[9]  += FP8_DEC(v.z, 1);
    a[10] += FP8_DEC(v.z, 2); a[11] += FP8_DEC(v.z, 3);
    a[12] += FP8_DEC(v.w, 0); a[13] += FP8_DEC(v.w, 1);
    a[14] += FP8_DEC(v.w, 2); a[15] += FP8_DEC(v.w, 3);
}

// ---------------------------------------------------------------------------
// Weight prep (single launch): WT[n][k] = bf16(W[k][n]), k < K else 0.
// ---------------------------------------------------------------------------
__global__ __launch_bounds__(256) void k_prep3(const float* __restrict__ W1,
                                               const float* __restrict__ W2,
                                               const float* __restrict__ W3,
                                               u16* __restrict__ WT1,
                                               u16* __restrict__ WT2,
                                               u16* __restrict__ WT3) {
    int idx = blockIdx.x * 256 + threadIdx.x;
    const int n1 = HID * K1_STRIDE, n2 = HID * K2_STRIDE, n3 = HID * K3_STRIDE;
    if (idx < n1) {
        const int n = idx / K1_STRIDE, k = idx % K1_STRIDE;
        WT1[idx] = (k < NODE_IN + EDGE_IN) ? f2bu(W1[k * HID + n]) : (u16)0;
    } else if ((idx -= n1) < n2) {
        const int n = idx / K2_STRIDE, k = idx % K2_STRIDE;
        WT2[idx] = (k < HID) ? f2bu(W2[k * HID + n]) : (u16)0;
    } else if ((idx -= n2) < n3) {
        const int n = idx / K3_STRIDE, k = idx % K3_STRIDE;
        WT3[idx] = (k < NODE_IN + HID) ? f2bu(W3[k * HID + n]) : (u16)0;
    }
}

// ---------------------------------------------------------------------------
// CSR build: histogram -> exclusive scan -> atomic-cursor placement.
// Edge state space is RELABELED into dst-sorted order: j <-> eidx[j].
// ---------------------------------------------------------------------------
__global__ __launch_bounds__(256) void k_hist(const int* __restrict__ dst,
                                              int* __restrict__ cnt) {
    const int e = blockIdx.x * 256 + threadIdx.x;
    if (e < N_EDGES) atomicAdd(&cnt[clampi(dst[e], N_NODES)], 1);
}

__global__ __launch_bounds__(256) void k_scan1(const int* __restrict__ cnt,
                                               int* __restrict__ local,
                                               int* __restrict__ partial) {
    __shared__ int tsum[256];
    const int b = blockIdx.x, t = threadIdx.x;
    const int base = b * SCAN_CHUNK + t * 8;
    int v[8];
    int s = 0;
#pragma unroll
    for (int i = 0; i < 8; i++) {
        const int idx = base + i;
        v[i] = (idx < N_NODES) ? cnt[idx] : 0;
        s += v[i];
    }
    tsum[t] = s;
    __syncthreads();
    for (int ofs = 1; ofs < 256; ofs <<= 1) {
        const int add = (t >= ofs) ? tsum[t - ofs] : 0;
        __syncthreads();
        tsum[t] += add;
        __syncthreads();
    }
    int excl = (t == 0) ? 0 : tsum[t - 1];
    if (t == 255) partial[b] = tsum[255];
#pragma unroll
    for (int i = 0; i < 8; i++) {
        const int idx = base + i;
        if (idx < N_NODES) local[idx] = excl;
        excl += v[i];
    }
}

__global__ __launch_bounds__(256) void k_scan2(int* __restrict__ partial) {
    __shared__ int s[256];
    const int t = threadIdx.x;
    s[t] = (t < SCAN_NBLK) ? partial[t] : 0;
    __syncthreads();
    for (int ofs = 1; ofs < 256; ofs <<= 1) {
        const int add = (t >= ofs) ? s[t - ofs] : 0;
        __syncthreads();
        s[t] += add;
        __syncthreads();
    }
    if (t < SCAN_NBLK) partial[t] = (t == 0) ? 0 : s[t - 1];
}

__global__ __launch_bounds__(256) void k_scan3(const int* __restrict__ local,
                                               const int* __restrict__ partial,
                                               int* __restrict__ row_ptr,
                                               int* __restrict__ cursor) {
    const int idx = blockIdx.x * 256 + threadIdx.x;
    if (idx <= N_NODES) {
        const int v = (idx == N_NODES) ? N_EDGES
                                       : local[idx] + partial[idx / SCAN_CHUNK];
        row_ptr[idx] = v;
        if (idx < N_NODES) cursor[idx] = v;
    }
}

// placement + inverse permutation in one pass
__global__ __launch_bounds__(256) void k_place(const int* __restrict__ dst,
                                               int* __restrict__ cursor,
                                               int* __restrict__ eidx,
                                               int* __restrict__ inv) {
    const int e = blockIdx.x * 256 + threadIdx.x;
    if (e < N_EDGES) {
        const int slot = atomicAdd(&cursor[clampi(dst[e], N_NODES)], 1);
        eidx[slot] = e;
        inv[e] = slot;
    }
}

// merged remap + ea pack: one eidx read per sorted edge
__global__ __launch_bounds__(256) void k_setup(const int* __restrict__ eidx,
                                               const int* __restrict__ src,
                                               const int* __restrict__ rev,
                                               const int* __restrict__ inv,
                                               const float* __restrict__ ea,
                                               int* __restrict__ src_d,
                                               int* __restrict__ rev_d,
                                               u16* __restrict__ ea_d) {
    const int j = blockIdx.x * 256 + threadIdx.x;
    if (j >= N_EDGES) return;
    const int e = clampi(eidx[j], N_EDGES);
    src_d[j] = src[e];
    rev_d[j] = inv[clampi(rev[e], N_EDGES)];
    const float2* er = (const float2*)(ea + (size_t)e * EDGE_IN);
    u16 v[16];
#pragma unroll
    for (int k = 0; k < 7; k++) {
        const float2 u = er[k];
        v[2 * k] = f2bu(u.x);
        v[2 * k + 1] = f2bu(u.y);
    }
    v[14] = 0; v[15] = 0;
    uint4 o1, o2;
    o1.x = (unsigned)v[0] | ((unsigned)v[1] << 16);
    o1.y = (unsigned)v[2] | ((unsigned)v[3] << 16);
    o1.z = (unsigned)v[4] | ((unsigned)v[5] << 16);
    o1.w = (unsigned)v[6] | ((unsigned)v[7] << 16);
    o2.x = (unsigned)v[8] | ((unsigned)v[9] << 16);
    o2.y = (unsigned)v[10] | ((unsigned)v[11] << 16);
    o2.z = (unsigned)v[12] | ((unsigned)v[13] << 16);
    o2.w = 0;
    uint4* dstp = (uint4*)(ea_d + (size_t)j * 16);
    dstp[0] = o1;
    dstp[1] = o2;
}

// ---------------------------------------------------------------------------
// K2 (streaming gather): node_sum[n] = sum over contiguous sorted rows.
// fp8 OUTPUT (halves write + downstream random-read traffic).
// 8 threads/node, 16 channels each (uint4 loads), 4-deep unrolled deg loop.
// ---------------------------------------------------------------------------
__global__ __launch_bounds__(256) void k_gather(const u8* __restrict__ h,
                                                const int* __restrict__ row_ptr,
                                                u8* __restrict__ node_sum) {
    const long long idx = (long long)blockIdx.x * 256 + threadIdx.x;
    const int n = (int)(idx >> 3);
    if (n >= N_NODES) return;
    const int c16 = (int)(idx & 7) << 4;
    const int beg = row_ptr[n], end = row_ptr[n + 1];
    float a[16];
#pragma unroll
    for (int i = 0; i < 16; i++) a[i] = 0.f;
    int j = beg;
    for (; j + 4 <= end; j += 4) {
        const uint4 v0 = *(const uint4*)(h + (long long)j * HID + c16);
        const uint4 v1 = *(const uint4*)(h + (long long)(j + 1) * HID + c16);
        const uint4 v2 = *(const uint4*)(h + (long long)(j + 2) * HID + c16);
        const uint4 v3 = *(const uint4*)(h + (long long)(j + 3) * HID + c16);
        acc16(a, v0); acc16(a, v1); acc16(a, v2); acc16(a, v3);
    }
    for (; j < end; j++) {
        const uint4 v = *(const uint4*)(h + (long long)j * HID + c16);
        acc16(a, v);
    }
    uint4 o;
    o.x = fp8_pk(a[0], a[1])   | (fp8_pk(a[2], a[3])   << 16);
    o.y = fp8_pk(a[4], a[5])   | (fp8_pk(a[6], a[7])   << 16);
    o.z = fp8_pk(a[8], a[9])   | (fp8_pk(a[10], a[11]) << 16);
    o.w = fp8_pk(a[12], a[13]) | (fp8_pk(a[14], a[15]) << 16);
    *(uint4*)(node_sum + (long long)n * HID + c16) = o;
}

// ---------------------------------------------------------------------------
// MFMA geometry (64x128 tile, 4 waves: 2 in M x 2 in N)
// a-frag: lane holds A[lane&15][(lane>>4)*8 + i]; b-frag from [n][k] layout.
// C/D: col = lane&15, row = (lane>>4)*4 + reg.
// ---------------------------------------------------------------------------

// K1a: xw[n] = x[n] @ W1x  (per-NODE GEMM; A cols 133..159 zeroed)
__global__ __launch_bounds__(256) void k_xw(const float* __restrict__ x,
                                            const u16* __restrict__ WT1,
                                            u16* __restrict__ xw) {
    __shared__ u16 A[MT * K1_STRIDE];
    const int n0 = blockIdx.x * MT;
    const int t = threadIdx.x;
    const int lane = t & 63, wv = t >> 6;
    for (int rr = 0; rr < 16; rr++) {
        const int row = wv * 16 + rr;
        const int n = n0 + row;
        const float* xr = x + (size_t)n * NODE_IN;
        u16* dstr = &A[row * K1_STRIDE];
        dstr[lane] = f2bu(xr[lane]);                 // k 0..63
        dstr[64 + lane] = f2bu(xr[64 + lane]);       // k 64..127
        if (lane < 5) dstr[128 + lane] = f2bu(xr[128 + lane]);  // 128..132
        if (lane < K1_PAD - NODE_IN) dstr[NODE_IN + lane] = 0;  // 133..159
    }
    __syncthreads();

    const int wm = wv & 1, wn = wv >> 1;
    const int lr = lane & 15, lk = (lane >> 4) * 8;
    f32x4 acc[2][4];
#pragma unroll
    for (int m = 0; m < 2; m++)
#pragma unroll
        for (int n = 0; n < 4; n++) acc[m][n] = (f32x4){0.f, 0.f, 0.f, 0.f};

    const int ar0 = (wm * 32 + lr) * K1_STRIDE + lk;
#pragma unroll
    for (int ks = 0; ks < K1_PAD / 32; ks++) {
        const int kk = ks * 32;
        const bf16x8 a0 = *(const bf16x8*)&A[ar0 + kk];
        const bf16x8 a1 = *(const bf16x8*)&A[ar0 + 16 * K1_STRIDE + kk];
#pragma unroll
        for (int n = 0; n < 4; n++) {
            const bf16x8 b = *(const bf16x8*)&WT1[(size_t)(wn * 64 + n * 16 + lr) * K1_STRIDE + kk + lk];
            acc[0][n] = __builtin_amdgcn_mfma_f32_16x16x32_bf16(a0, b, acc[0][n], 0, 0, 0);
            acc[1][n] = __builtin_amdgcn_mfma_f32_16x16x32_bf16(a1, b, acc[1][n], 0, 0, 0);
        }
    }

    const int lr4 = lane >> 4;
#pragma unroll
    for (int n = 0; n < 4; n++) {
        const int col = wn * 64 + n * 16 + lr;
#pragma unroll
        for (int m = 0; m < 2; m++)
#pragma unroll
            for (int j = 0; j < 4; j++) {
                const int nd = n0 + wm * 32 + m * 16 + lr4 * 4 + j;
                xw[(size_t)nd * HID + col] = f2bu(acc[m][n][j]);
            }
    }
}

// K1b (MFMA): h0[j] = relu(xw[src_d[j]] + ea_d[j]@W1e + b1) -> fp8.
// ea matvec on the matrix pipe; xw row PREFETCHED into registers at start.
__global__ __launch_bounds__(256) void k_init3(const u16* __restrict__ xw,
                                               const u16* __restrict__ ea_d,
                                               const float* __restrict__ W1,
                                               const float* __restrict__ b1,
                                               const int* __restrict__ src_d,
                                               u8* __restrict__ h0) {
    __shared__ u16 Aea[MT * KE_STRIDE];       // 5120 B
    __shared__ u16 W1e[HID * KE_PAD];         // [n][k], 8192 B
    __shared__ u16 Sacc[MT * K2_STRIDE];      // 17408 B staging
    __shared__ float b1s[HID];
    const int e0 = blockIdx.x * MT;
    const int t = threadIdx.x;

    // prefetch phase-2 operands (consumed after 2 barriers)
    const int prow = t >> 2, pj = t & 3;
    const int ps = clampi(src_d[e0 + prow], N_NODES);
    uint4 xv[4];
#pragma unroll
    for (int q = 0; q < 4; q++)
        xv[q] = *(const uint4*)(xw + (size_t)ps * HID + pj * 32 + q * 8);

    for (int i = t; i < HID * KE_PAD; i += 256) {
        const int n = i >> 5, k = i & 31;
        W1e[i] = (k < EDGE_IN) ? f2bu(W1[(NODE_IN + k) * HID + n]) : (u16)0;
    }
    if (t < HID) b1s[t] = b1[t];
    {   // ea tile: 4 threads/row, 8B each; pad 16..31 zeroed
        const int row = t >> 2, q = t & 3;
        const uint2 v = *(const uint2*)(ea_d + (size_t)(e0 + row) * 16 + q * 4);
        *(uint2*)&Aea[row * KE_STRIDE + q * 4] = v;
        uint2 z; z.x = 0; z.y = 0;
        *(uint2*)&Aea[row * KE_STRIDE + 16 + q * 4] = z;
    }
    __syncthreads();

    const int lane = t & 63, wid = t >> 6;
    const int wm = wid & 1, wn = wid >> 1;
    const int lr = lane & 15, lk = (lane >> 4) * 8;
    f32x4 acc[2][4];
#pragma unroll
    for (int m = 0; m < 2; m++)
#pragma unroll
        for (int n = 0; n < 4; n++) acc[m][n] = (f32x4){0.f, 0.f, 0.f, 0.f};

    {
        const bf16x8 a0 = *(const bf16x8*)&Aea[(wm * 32 + lr) * KE_STRIDE + lk];
        const bf16x8 a1 = *(const bf16x8*)&Aea[(wm * 32 + 16 + lr) * KE_STRIDE + lk];
#pragma unroll
        for (int n = 0; n < 4; n++) {
            const bf16x8 b = *(const bf16x8*)&W1e[(wn * 64 + n * 16 + lr) * KE_PAD + lk];
            acc[0][n] = __builtin_amdgcn_mfma_f32_16x16x32_bf16(a0, b, acc[0][n], 0, 0, 0);
            acc[1][n] = __builtin_amdgcn_mfma_f32_16x16x32_bf16(a1, b, acc[1][n], 0, 0, 0);
        }
    }

    // stage product bf16 -> Sacc[row][col]
    const int lr4 = lane >> 4;
#pragma unroll
    for (int n = 0; n < 4; n++) {
        const int col = wn * 64 + n * 16 + lr;
#pragma unroll
        for (int m = 0; m < 2; m++)
#pragma unroll
            for (int j = 0; j < 4; j++) {
                const int row = wm * 32 + m * 16 + lr4 * 4 + j;
                Sacc[row * K2_STRIDE + col] = f2bu(acc[m][n][j]);
            }
    }
    __syncthreads();

    // phase 2: coalesced, thread = (row, 32-ch chunk)
    const long long e = e0 + prow;
#pragma unroll
    for (int q = 0; q < 4; q++) {
        const int c8 = pj * 32 + q * 8;
        const uint4 sv = *(const uint4*)&Sacc[prow * K2_STRIDE + c8];  // 8 bf16
        const float4 ba = *(const float4*)&b1s[c8];
        const float4 bbv = *(const float4*)&b1s[c8 + 4];
        const float v0 = bu2f(sv.x & 0xFFFFu) + bu2f(xv[q].x & 0xFFFFu) + ba.x;
        const float v1 = bu2f(sv.x >> 16)     + bu2f(xv[q].x >> 16)     + ba.y;
        const float v2 = bu2f(sv.y & 0xFFFFu) + bu2f(xv[q].y & 0xFFFFu) + ba.z;
        const float v3 = bu2f(sv.y >> 16)     + bu2f(xv[q].y >> 16)     + ba.w;
        const float v4 = bu2f(sv.z & 0xFFFFu) + bu2f(xv[q].z & 0xFFFFu) + bbv.x;
        const float v5 = bu2f(sv.z >> 16)     + bu2f(xv[q].z >> 16)     + bbv.y;
        const float v6 = bu2f(sv.w & 0xFFFFu) + bu2f(xv[q].w & 0xFFFFu) + bbv.z;
        const float v7 = bu2f(sv.w >> 16)     + bu2f(xv[q].w >> 16)     + bbv.w;
        uint2 o;
        o.x = fp8_pk(v0, v1) | (fp8_pk(v2, v3) << 16);
        o.y = fp8_pk(v4, v5) | (fp8_pk(v6, v7) << 16);
        *(uint2*)(h0 + e * HID + c8) = o;
    }
}

// K3: hn[j] = relu(h0[j] + (node_sum[src_d[j]] - h[rev_d[j]]) @ W2 + b2)
// ns is fp8; h0 row PREFETCHED into registers at kernel start.
__global__ __launch_bounds__(256) void k_msg_mfma(const u8* __restrict__ ns,
                                                  const u8* __restrict__ h,
                                                  const u8* __restrict__ h0g,
                                                  const u16* __restrict__ WT2,
                                                  const float* __restrict__ b2,
                                                  const int* __restrict__ src_d,
                                                  const int* __restrict__ rev_d,
                                                  u8* __restrict__ hn) {
    __shared__ u16 A[MT * K2_STRIDE];
    __shared__ float b2s[HID];
    const int e0 = blockIdx.x * MT;
    const int t = threadIdx.x;

    // prefetch phase-2 h0 row chunks (stream; consumed after 2 barriers)
    const int prow = t >> 2, pj = t & 3;
    const long long pe = e0 + prow;
    uint2 h0v[4];
#pragma unroll
    for (int q = 0; q < 4; q++)
        h0v[q] = *(const uint2*)(h0g + pe * HID + pj * 32 + q * 8);

    if (t < HID) b2s[t] = b2[t];
    {   // builder: 4 threads/row, 32 channels each (all fp8 inputs)
        const int le = t >> 2, j = t & 3;
        const int e = e0 + le;
        const int s = clampi(src_d[e], N_NODES);
        const int r = clampi(rev_d[e], N_EDGES);
        const u8* nsr = ns + (size_t)s * HID + j * 32;
        const u8* hr = h + (size_t)r * HID + j * 32;
        u16* dstr = &A[le * K2_STRIDE + j * 32];
#pragma unroll
        for (int q = 0; q < 4; q++) {
            const uint2 nv = *(const uint2*)(nsr + q * 8);  // 8 fp8
            const uint2 hv = *(const uint2*)(hr + q * 8);   // 8 fp8
            union { bf16x8 v; u16 s[8]; } o;
            o.s[0] = f2bu(FP8_DEC(nv.x, 0) - FP8_DEC(hv.x, 0));
            o.s[1] = f2bu(FP8_DEC(nv.x, 1) - FP8_DEC(hv.x, 1));
            o.s[2] = f2bu(FP8_DEC(nv.x, 2) - FP8_DEC(hv.x, 2));
            o.s[3] = f2bu(FP8_DEC(nv.x, 3) - FP8_DEC(hv.x, 3));
            o.s[4] = f2bu(FP8_DEC(nv.y, 0) - FP8_DEC(hv.y, 0));
            o.s[5] = f2bu(FP8_DEC(nv.y, 1) - FP8_DEC(hv.y, 1));
            o.s[6] = f2bu(FP8_DEC(nv.y, 2) - FP8_DEC(hv.y, 2));
            o.s[7] = f2bu(FP8_DEC(nv.y, 3) - FP8_DEC(hv.y, 3));
            *(bf16x8*)(dstr + q * 8) = o.v;
        }
    }
    __syncthreads();

    const int lane = t & 63, wid = t >> 6;
    const int wm = wid & 1, wn = wid >> 1;
    const int lr = lane & 15, lk = (lane >> 4) * 8;
    f32x4 acc[2][4];
#pragma unroll
    for (int m = 0; m < 2; m++)
#pragma unroll
        for (int n = 0; n < 4; n++) acc[m][n] = (f32x4){0.f, 0.f, 0.f, 0.f};

    const int ar0 = (wm * 32 + lr) * K2_STRIDE + lk;
#pragma unroll
    for (int ks = 0; ks < K2_PAD / 32; ks++) {
        const int kk = ks * 32;
        const bf16x8 a0 = *(const bf16x8*)&A[ar0 + kk];
        const bf16x8 a1 = *(const bf16x8*)&A[ar0 + 16 * K2_STRIDE + kk];
#pragma unroll
        for (int n = 0; n < 4; n++) {
            const bf16x8 b = *(const bf16x8*)&WT2[(size_t)(wn * 64 + n * 16 + lr) * K2_STRIDE + kk + lk];
            acc[0][n] = __builtin_amdgcn_mfma_f32_16x16x32_bf16(a0, b, acc[0][n], 0, 0, 0);
            acc[1][n] = __builtin_amdgcn_mfma_f32_16x16x32_bf16(a1, b, acc[1][n], 0, 0, 0);
        }
    }

    __syncthreads();  // A's builder data fully consumed
    const int lr4 = lane >> 4;
#pragma unroll
    for (int n = 0; n < 4; n++) {
        const int col = wn * 64 + n * 16 + lr;
#pragma unroll
        for (int m = 0; m < 2; m++)
#pragma unroll
            for (int j = 0; j < 4; j++) {
                const int row = wm * 32 + m * 16 + lr4 * 4 + j;
                A[row * K2_STRIDE + col] = f2bu(acc[m][n][j]);
            }
    }
    __syncthreads();

#pragma unroll
    for (int q = 0; q < 4; q++) {
        const int c8 = pj * 32 + q * 8;
        const uint4 sv = *(const uint4*)&A[prow * K2_STRIDE + c8];  // 8 bf16
        const float4 ba = *(const float4*)&b2s[c8];
        const float4 bbv = *(const float4*)&b2s[c8 + 4];
        const float v0 = bu2f(sv.x & 0xFFFFu) + FP8_DEC(h0v[q].x, 0) + ba.x;
        const float v1 = bu2f(sv.x >> 16)     + FP8_DEC(h0v[q].x, 1) + ba.y;
        const float v2 = bu2f(sv.y & 0xFFFFu) + FP8_DEC(h0v[q].x, 2) + ba.z;
        const float v3 = bu2f(sv.y >> 16)     + FP8_DEC(h0v[q].x, 3) + ba.w;
        const float v4 = bu2f(sv.z & 0xFFFFu) + FP8_DEC(h0v[q].y, 0) + bbv.x;
        const float v5 = bu2f(sv.z >> 16)     + FP8_DEC(h0v[q].y, 1) + bbv.y;
        const float v6 = bu2f(sv.w & 0xFFFFu) + FP8_DEC(h0v[q].y, 2) + bbv.z;
        const float v7 = bu2f(sv.w >> 16)     + FP8_DEC(h0v[q].y, 3) + bbv.w;
        uint2 o;
        o.x = fp8_pk(v0, v1) | (fp8_pk(v2, v3) << 16);
        o.y = fp8_pk(v4, v5) | (fp8_pk(v6, v7) << 16);
        *(uint2*)(hn + pe * HID + c8) = o;
    }
}

// K5: node_attr[n] = relu(concat(x[n], vmsg[n]) @ W3 + b3)  (bf16 out)
// vmsg is fp8. K staged in two halves (160 + 128) through a 64x168 buffer.
__global__ __launch_bounds__(256) void k_node_mfma(const float* __restrict__ x,
                                                   const u8* __restrict__ vmsg,
                                                   const u16* __restrict__ WT3,
                                                   const float* __restrict__ b3,
                                                   u16* __restrict__ node_attr) {
    __shared__ u16 A[MT * K3H_STRIDE];  // 21504 B
    const int n0 = blockIdx.x * MT;
    const int t = threadIdx.x;
    const int lane = t & 63, wv = t >> 6;
    const int wm = wv & 1, wn = wv >> 1;
    const int lr = lane & 15, lk = (lane >> 4) * 8;
    f32x4 acc[2][4];
#pragma unroll
    for (int m = 0; m < 2; m++)
#pragma unroll
        for (int n = 0; n < 4; n++) acc[m][n] = (f32x4){0.f, 0.f, 0.f, 0.f};
    const int ar0 = (wm * 32 + lr) * K3H_STRIDE + lk;

#pragma unroll
    for (int half = 0; half < 2; half++) {
        // build this half's 160(/128)-wide K slice
        for (int rr = 0; rr < 16; rr++) {
            const int row = wv * 16 + rr;
            const int n = n0 + row;
            u16* dstr = &A[row * K3H_STRIDE];
            const u8* vp = vmsg + (size_t)n * HID;
            if (half == 0) {
                const float* xr = x + (size_t)n * NODE_IN;
                dstr[lane] = f2bu(xr[lane]);             // k 0..63
                dstr[64 + lane] = f2bu(xr[64 + lane]);   // k 64..127
                if (lane < 32) {                         // k 128..159
                    const int kg = 128 + lane;
                    dstr[128 + lane] = (kg < NODE_IN)
                        ? f2bu(xr[kg])
                        : f2bu(FP8_DEC((unsigned)vp[kg - NODE_IN], 0));
                }
            } else {
                dstr[lane] = f2bu(FP8_DEC((unsigned)vp[27 + lane], 0));  // vmsg 27..90
                dstr[64 + lane] = (91 + lane < HID)
                    ? f2bu(FP8_DEC((unsigned)vp[91 + lane], 0)) : (u16)0;
            }
        }
        __syncthreads();
        const int steps = half ? (K3_PAD - K1_PAD) / 32 : K1_PAD / 32;  // 4 : 5
        for (int ks = 0; ks < steps; ks++) {
            const int kk = ks * 32;
            const bf16x8 a0 = *(const bf16x8*)&A[ar0 + kk];
            const bf16x8 a1 = *(const bf16x8*)&A[ar0 + 16 * K3H_STRIDE + kk];
            const int kwt = half * K1_PAD + kk;
#pragma unroll
            for (int n = 0; n < 4; n++) {
                const bf16x8 b = *(const bf16x8*)&WT3[(size_t)(wn * 64 + n * 16 + lr) * K3_STRIDE + kwt + lk];
                acc[0][n] = __builtin_amdgcn_mfma_f32_16x16x32_bf16(a0, b, acc[0][n], 0, 0, 0);
                acc[1][n] = __builtin_amdgcn_mfma_f32_16x16x32_bf16(a1, b, acc[1][n], 0, 0, 0);
            }
        }
        __syncthreads();
    }

    const int lr4 = lane >> 4;
#pragma unroll
    for (int n = 0; n < 4; n++) {
        const int col = wn * 64 + n * 16 + lr;
        const float bias = b3[col];
#pragma unroll
        for (int m = 0; m < 2; m++)
#pragma unroll
            for (int j = 0; j < 4; j++) {
                const int nd = n0 + wm * 32 + m * 16 + lr4 * 4 + j;
                float v = acc[m][n][j] + bias;
                node_attr[(size_t)nd * HID + col] = f2bu(v > 0.f ? v : 0.f);
            }
    }
}

// ---------------------------------------------------------------------------
// K6: out[g] = mean over the graph's contiguous node range (bf16 node_attr).
// ---------------------------------------------------------------------------
__global__ __launch_bounds__(128) void k_pool2(const u16* __restrict__ node_attr,
                                               const int* __restrict__ batch,
                                               float* __restrict__ out) {
    const int g = blockIdx.x;
    __shared__ int lo_s, hi_s;
    if (threadIdx.x == 0) {
        int lo = 0, hi = N_NODES;
        while (lo < hi) { int mid = (lo + hi) >> 1; if (batch[mid] < g) lo = mid + 1; else hi = mid; }
        lo_s = lo;
        int lo2 = lo, hi2 = N_NODES;
        while (lo2 < hi2) { int mid = (lo2 + hi2) >> 1; if (batch[mid] <= g) lo2 = mid + 1; else hi2 = mid; }
        hi_s = lo2;
    }
    __syncthreads();
    const int lo = lo_s, hi = hi_s;
    float acc = 0.f;
    for (int n = lo; n < hi; n++)
        acc += bu2f(node_attr[(size_t)n * HID + threadIdx.x]);
    const float cnt = (hi > lo) ? (float)(hi - lo) : 1.f;
    out[(size_t)g * HID + threadIdx.x] = acc / cnt;
}

// ---------------------------------------------------------------------------
extern "C" void kernel_launch(void* const* d_in, const int* in_sizes, int n_in,
                              void* d_out, int out_size, void* d_ws, size_t ws_size,
                              hipStream_t stream) {
    const float* x   = (const float*)d_in[0];
    const float* ea  = (const float*)d_in[1];
    const float* W1  = (const float*)d_in[2];
    const float* b1  = (const float*)d_in[3];
    const float* W2  = (const float*)d_in[4];
    const float* b2  = (const float*)d_in[5];
    const float* W3  = (const float*)d_in[6];
    const float* b3  = (const float*)d_in[7];
    const int*   ei  = (const int*)d_in[8];
    const int*   src = ei;
    const int*   dst = ei + N_EDGES;
    const int*   rev = (const int*)d_in[9];
    const int*   bat = (const int*)d_in[10];

    char* ws = (char*)d_ws;
    size_t off = 0;
    auto alloc = [&](size_t bytes) -> void* {
        void* p = ws + off;
        off += (bytes + 255) & ~(size_t)255;
        return p;
    };
    const size_t hbytes = (size_t)N_EDGES * HID;                 // 102.4 MB fp8
    u8* h0 = (u8*)alloc(hbytes);
    u8* hA = (u8*)alloc(hbytes);
    u8* hB = (u8*)alloc(hbytes);
    u8* node_sum = (u8*)alloc((size_t)N_NODES * HID);            // 25.6 MB fp8
    int* row_ptr = (int*)alloc((size_t)(N_NODES + 1) * sizeof(int));
    int* eidx = (int*)alloc((size_t)N_EDGES * sizeof(int));
    int* src_d = (int*)alloc((size_t)N_EDGES * sizeof(int));
    int* rev_d = (int*)alloc((size_t)N_EDGES * sizeof(int));
    u16* ea_d = (u16*)alloc((size_t)N_EDGES * 16 * sizeof(u16));  // 25.6 MB
    u16* WT1 = (u16*)alloc((size_t)HID * K1_STRIDE * sizeof(u16));
    u16* WT2 = (u16*)alloc((size_t)HID * K2_STRIDE * sizeof(u16));
    u16* WT3 = (u16*)alloc((size_t)HID * K3_STRIDE * sizeof(u16));
    // Aliases:
    //  - xw (bf16, 51.2 MB) lives in hA: dead before the first k_msg writes hA.
    //  - node_attr (bf16, 51.2 MB) lives in h0: dead after last k_msg read.
    u16* xw = (u16*)hA;
    u16* node_attr = (u16*)h0;
    // total ~370 MB < proven ws floor of ~415.7 MB (round-3 fp8_csr tier ran)

    if (ws_size < off) return;  // diagnostic: leave d_out untouched

    // weight transpose+pad to bf16 (single launch)
    k_prep3<<<(HID * (K1_STRIDE + K2_STRIDE + K3_STRIDE) + 255) / 256, 256, 0,
              stream>>>(W1, W2, W3, WT1, WT2, WT3);

    // CSR build + dst-sorted relabeling (transients overlay node_sum, 6.4MB < 25.6MB)
    {
        int* cnt = (int*)node_sum;
        int* local = cnt + N_NODES;
        int* cursor = local + N_NODES;
        int* partial = cursor + N_NODES;
        int* inv = partial + 4096;
        hipMemsetAsync(cnt, 0, (size_t)N_NODES * sizeof(int), stream);
        k_hist<<<(N_EDGES + 255) / 256, 256, 0, stream>>>(dst, cnt);
        k_scan1<<<SCAN_NBLK, 256, 0, stream>>>(cnt, local, partial);
        k_scan2<<<1, 256, 0, stream>>>(partial);
        k_scan3<<<(N_NODES + 256) / 256, 256, 0, stream>>>(local, partial, row_ptr, cursor);
        k_place<<<(N_EDGES + 255) / 256, 256, 0, stream>>>(dst, cursor, eidx, inv);
        k_setup<<<(N_EDGES + 255) / 256, 256, 0, stream>>>(eidx, src, rev, inv, ea, src_d, rev_d, ea_d);
    }

    // h0 = relu(x[src]@W1x + ea@W1e + b1)
    k_xw<<<N_NODES / MT, 256, 0, stream>>>(x, WT1, xw);
    k_init3<<<N_EDGES / MT, 256, 0, stream>>>(xw, ea_d, W1, b1, src_d, h0);

    const u8* h = h0;
    u8* bufs[2] = {hA, hB};
    const int agg_blocks = (int)(((long long)N_NODES * 8 + 255) / 256);
    for (int it = 0; it < 3; it++) {
        k_gather<<<agg_blocks, 256, 0, stream>>>(h, row_ptr, node_sum);
        u8* hn = bufs[it & 1];   // it=0 writes hA (xw already consumed)
        k_msg_mfma<<<N_EDGES / MT, 256, 0, stream>>>(node_sum, h, h0, WT2, b2, src_d, rev_d, hn);
        h = hn;
    }
    k_gather<<<agg_blocks, 256, 0, stream>>>(h, row_ptr, node_sum);

    // h0 is dead from here; node_attr (bf16) reuses its storage.
    k_node_mfma<<<N_NODES / MT, 256, 0, stream>>>(x, node_sum, WT3, b3, node_attr);
    k_pool2<<<NUM_GRAPHS, 128, 0, stream>>>(node_attr, bat, (float*)d_out);
}